// Round 3
// baseline (10385.139 us; speedup 1.0000x reference)
//
#include <hip/hip_runtime.h>
#include <hip/hip_bf16.h>
#include <math.h>

// ---------------------------------------------------------------------------
// GIN model (GINEConv x5 + virtual node + readout).
// fp32 compute; persistent node activations stored bf16 to cut workspace.
// Strictly respects ws_size; if insufficient, writes ws_MB sentinel to d_out.
// ---------------------------------------------------------------------------

typedef __hip_bfloat16 bf16;

__device__ __forceinline__ float silu_f(float v) { return v / (1.0f + __expf(-v)); }

__global__ void k_fill(float* __restrict__ p, float v, int n) {
    int stride = gridDim.x * blockDim.x;
    for (int i = blockIdx.x * blockDim.x + threadIdx.x; i < n; i += stride) p[i] = v;
}

__global__ void k_zero(float* __restrict__ p, size_t n) {
    size_t stride = (size_t)gridDim.x * blockDim.x;
    for (size_t i = (size_t)blockIdx.x * blockDim.x + threadIdx.x; i < n; i += stride)
        p[i] = 0.0f;
}

// tbl[l][a][j] = bond_emb[a] . We[l][j] + be[l][j]
__global__ void k_eptable(const float* __restrict__ bond_emb,
                          const float* __restrict__ We,
                          const float* __restrict__ be,
                          float* __restrict__ tbl, int BV, int H, int ED) {
    int l = blockIdx.x / BV;
    int a = blockIdx.x % BV;
    int j = threadIdx.x;
    if (j >= H) return;
    const float* w = We + ((size_t)l * H + j) * ED;
    const float* bb = bond_emb + (size_t)a * ED;
    float s = be[(size_t)l * H + j];
    for (int k = 0; k < ED; k++) s += bb[k] * w[k];
    tbl[((size_t)l * BV + a) * H + j] = s;
}

// h_bf[n*H+j] = atom_emb[x[n]*H+j]
__global__ void k_encode(const int* __restrict__ x, const float* __restrict__ emb,
                         bf16* __restrict__ h, int H, int total) {
    int stride = gridDim.x * blockDim.x;
    for (int i = blockIdx.x * blockDim.x + threadIdx.x; i < total; i += stride) {
        int n = i / H, j = i - n * H;
        h[i] = __float2bfloat16(emb[(size_t)x[n] * H + j]);
    }
}

// agg[dst] += relu(h[src] + tbl[ea])
__global__ void k_message(const int* __restrict__ src, const int* __restrict__ dst,
                          const int* __restrict__ ea,
                          const bf16* __restrict__ h, const float* __restrict__ tbl,
                          float* __restrict__ agg, int H, int E) {
    int j = threadIdx.x;
    if (j >= H) return;
    for (int e = blockIdx.x; e < E; e += gridDim.x) {
        int s = src[e], d = dst[e], a = ea[e];
        float v = __bfloat162float(h[(size_t)s * H + j]) + tbl[(size_t)a * H + j];
        if (v > 0.0f) atomicAdd(&agg[(size_t)d * H + j], v);
    }
}

// z = (1+eps[l]) * h + z
__global__ void k_zmix(const bf16* __restrict__ h, float* __restrict__ z,
                       const float* __restrict__ epsp, int l, int n) {
    float e = 1.0f + epsp[l];
    int stride = gridDim.x * blockDim.x;
    for (int i = blockIdx.x * blockDim.x + threadIdx.x; i < n; i += stride)
        z[i] = e * __bfloat162float(h[i]) + z[i];
}

__global__ void k_add(const float* __restrict__ a, const float* __restrict__ b,
                      float* __restrict__ c, int n) {
    int stride = gridDim.x * blockDim.x;
    for (int i = blockIdx.x * blockDim.x + threadIdx.x; i < n; i += stride)
        c[i] = a[i] + b[i];
}

// h[i] += vn[batch[i/H]*H + i%H]
__global__ void k_addvn(bf16* __restrict__ h, const float* __restrict__ vn,
                        const int* __restrict__ batch, int H, int total) {
    int stride = gridDim.x * blockDim.x;
    for (int i = blockIdx.x * blockDim.x + threadIdx.x; i < total; i += stride) {
        int n = i / H, j = i - n * H;
        h[i] = __float2bfloat16(__bfloat162float(h[i]) + vn[(size_t)batch[n] * H + j]);
    }
}

// hp[batch[n]] += h[n]
__global__ void k_pool(const bf16* __restrict__ h, const int* __restrict__ batch,
                       float* __restrict__ hp, int H, int N) {
    int j = threadIdx.x;
    if (j >= H) return;
    for (int n = blockIdx.x; n < N; n += gridDim.x) {
        atomicAdd(&hp[(size_t)batch[n] * H + j], __bfloat162float(h[(size_t)n * H + j]));
    }
}

// C[m,n] = sum_k A[m,k]*B[n,k]; epilogue: +bias, BN, SiLU, residual, accumulate.
// If Cb != null: output bf16 (residual from resb if non-null). Else fp32 path.
#define GBM 64
#define GBN 64
#define GBK 16
__global__ __launch_bounds__(256)
void k_gemm(const float* __restrict__ A, const float* __restrict__ B,
            const float* __restrict__ bias, const float* __restrict__ bn,
            const float* __restrict__ res, const bf16* __restrict__ resb,
            float* __restrict__ C, bf16* __restrict__ Cb,
            int M, int Nc, int K, int flags) {  // flags: 1=silu, 2=accumulate(fp32)
    __shared__ float As[GBK][GBM + 4];
    __shared__ float Bs[GBK][GBN + 4];
    const int bm = blockIdx.x * GBM;
    const int bnc = blockIdx.y * GBN;
    const int tid = threadIdx.x;
    const int tx = tid & 15, ty = tid >> 4;
    const int ar = tid >> 2;
    const int ak = (tid & 3) << 2;

    float acc[4][4] = {{0.f}};

    for (int k0 = 0; k0 < K; k0 += GBK) {
        {
            int gr = bm + ar, gk = k0 + ak;
            float4 v = make_float4(0.f, 0.f, 0.f, 0.f);
            if (gr < M && gk < K) {
                const float* p = A + (size_t)gr * K;
                if (gk + 3 < K) v = *(const float4*)(p + gk);
                else {
                    v.x = p[gk];
                    if (gk + 1 < K) v.y = p[gk + 1];
                    if (gk + 2 < K) v.z = p[gk + 2];
                }
            }
            As[ak][ar] = v.x; As[ak + 1][ar] = v.y; As[ak + 2][ar] = v.z; As[ak + 3][ar] = v.w;
        }
        {
            int gr = bnc + ar, gk = k0 + ak;
            float4 v = make_float4(0.f, 0.f, 0.f, 0.f);
            if (gr < Nc && gk < K) {
                const float* p = B + (size_t)gr * K;
                if (gk + 3 < K) v = *(const float4*)(p + gk);
                else {
                    v.x = p[gk];
                    if (gk + 1 < K) v.y = p[gk + 1];
                    if (gk + 2 < K) v.z = p[gk + 2];
                }
            }
            Bs[ak][ar] = v.x; Bs[ak + 1][ar] = v.y; Bs[ak + 2][ar] = v.z; Bs[ak + 3][ar] = v.w;
        }
        __syncthreads();
        #pragma unroll
        for (int kk = 0; kk < GBK; kk++) {
            float4 a = *(const float4*)&As[kk][ty * 4];
            float4 b = *(const float4*)&Bs[kk][tx * 4];
            acc[0][0] += a.x * b.x; acc[0][1] += a.x * b.y; acc[0][2] += a.x * b.z; acc[0][3] += a.x * b.w;
            acc[1][0] += a.y * b.x; acc[1][1] += a.y * b.y; acc[1][2] += a.y * b.z; acc[1][3] += a.y * b.w;
            acc[2][0] += a.z * b.x; acc[2][1] += a.z * b.y; acc[2][2] += a.z * b.z; acc[2][3] += a.z * b.w;
            acc[3][0] += a.w * b.x; acc[3][1] += a.w * b.y; acc[3][2] += a.w * b.z; acc[3][3] += a.w * b.w;
        }
        __syncthreads();
    }

    #pragma unroll
    for (int i = 0; i < 4; i++) {
        int row = bm + ty * 4 + i;
        if (row >= M) continue;
        #pragma unroll
        for (int j = 0; j < 4; j++) {
            int col = bnc + tx * 4 + j;
            if (col >= Nc) continue;
            float v = acc[i][j];
            if (bias) v += bias[col];
            if (bn) {
                float g = bn[col], bb = bn[Nc + col], mm = bn[2 * Nc + col], vv = bn[3 * Nc + col];
                v = (v - mm) * (g * rsqrtf(vv + 1e-5f)) + bb;
            }
            if (flags & 1) v = silu_f(v);
            size_t idx = (size_t)row * Nc + col;
            if (Cb) {
                if (resb) v += __bfloat162float(resb[idx]);
                Cb[idx] = __float2bfloat16(v);
            } else {
                if (res) v += res[idx];
                if (flags & 2) C[idx] += v;
                else           C[idx] = v;
            }
        }
    }
}

// per-row LayerNorm + SiLU
__global__ __launch_bounds__(256)
void k_ln_silu(const float* __restrict__ hg, const float* __restrict__ g,
               const float* __restrict__ b, float* __restrict__ r, int H) {
    int gi = blockIdx.x;
    const float* row = hg + (size_t)gi * H;
    float s = 0.f, s2 = 0.f;
    for (int j = threadIdx.x; j < H; j += blockDim.x) {
        float v = row[j];
        s += v; s2 += v * v;
    }
    for (int off = 32; off; off >>= 1) {
        s += __shfl_down(s, off);
        s2 += __shfl_down(s2, off);
    }
    __shared__ float rs[4], rs2[4];
    int wid = threadIdx.x >> 6, lane = threadIdx.x & 63;
    if (lane == 0) { rs[wid] = s; rs2[wid] = s2; }
    __syncthreads();
    if (threadIdx.x == 0) {
        float S = 0.f, S2 = 0.f;
        for (int w = 0; w < 4; w++) { S += rs[w]; S2 += rs2[w]; }
        rs[0] = S; rs2[0] = S2;
    }
    __syncthreads();
    float mu = rs[0] / H;
    float var = rs2[0] / H - mu * mu;
    float inv = rsqrtf(var + 1e-5f);
    for (int j = threadIdx.x; j < H; j += blockDim.x) {
        float v = (row[j] - mu) * inv * g[j] + b[j];
        r[(size_t)gi * H + j] = silu_f(v);
    }
}

__global__ void k_head2(const float* __restrict__ r2, const float* __restrict__ w,
                        const float* __restrict__ b, float* __restrict__ out, int Kh) {
    int gi = blockIdx.x;
    int t = threadIdx.x;
    float s = 0.f;
    for (int k = t; k < Kh; k += 64) s += r2[(size_t)gi * Kh + k] * w[k];
    for (int off = 32; off; off >>= 1) s += __shfl_down(s, off);
    if (t == 0) out[gi] = s + b[0];
}

extern "C" void kernel_launch(void* const* d_in, const int* in_sizes, int n_in,
                              void* d_out, int out_size, void* d_ws, size_t ws_size,
                              hipStream_t stream) {
    const int*   x         = (const int*)d_in[0];
    const int*   edge_attr = (const int*)d_in[1];
    const int*   eidx      = (const int*)d_in[2];
    const int*   batch     = (const int*)d_in[3];
    const float* atom_emb  = (const float*)d_in[5];
    const float* bond_emb  = (const float*)d_in[6];
    const float* We  = (const float*)d_in[7];
    const float* be  = (const float*)d_in[8];
    const float* W1  = (const float*)d_in[9];
    const float* b1  = (const float*)d_in[10];
    const float* bn1 = (const float*)d_in[11];
    const float* W2  = (const float*)d_in[12];
    const float* b2  = (const float*)d_in[13];
    const float* bn2 = (const float*)d_in[14];
    const float* epsp= (const float*)d_in[15];
    const float* Wp  = (const float*)d_in[16];
    const float* bp  = (const float*)d_in[17];
    const float* vnW1= (const float*)d_in[18];
    const float* vnb1= (const float*)d_in[19];
    const float* vnbn= (const float*)d_in[20];
    const float* vnW2= (const float*)d_in[21];
    const float* vnb2= (const float*)d_in[22];
    const float* ln_g= (const float*)d_in[23];
    const float* ln_b= (const float*)d_in[24];
    const float* hW1 = (const float*)d_in[25];
    const float* hb1 = (const float*)d_in[26];
    const float* hW2 = (const float*)d_in[27];
    const float* hb2 = (const float*)d_in[28];
    float* out = (float*)d_out;

    const int N  = in_sizes[0];
    const int E  = in_sizes[1];
    const int G  = out_size;
    const int L  = in_sizes[15];
    const int H  = in_sizes[19];
    const int H2 = 2 * H;
    const int ED = in_sizes[7] / (L * H);
    const int BV = in_sizes[6] / ED;
    const int HH = in_sizes[26];
    (void)n_in;

    const int* src = eidx;
    const int* dst = eidx + E;

    // ---- workspace carve-up (in floats), strictly bounded by ws_size ----
    float* wsf = (float*)d_ws;
    const size_t ws_floats = ws_size / sizeof(float);
    const size_t fN = (size_t)N * H;
    const size_t fG = (size_t)G * H;
    size_t off = 0;
    float* agg   = wsf + off; off += fN;                 // fp32 agg / z
    float* hp    = wsf + off; off += fG;
    float* hg    = wsf + off; off += fG;
    float* vn    = wsf + off; off += fG;
    float* vn_in = wsf + off; off += fG;
    float* vn_t  = wsf + off; off += fG;
    float* rbuf  = wsf + off; off += fG;
    float* r2    = wsf + off; off += (size_t)G * HH;
    float* tbl   = wsf + off; off += (size_t)L * BV * H;
    bf16*  hbf   = (bf16*)(wsf + off); off += (fN + 1) / 2;  // bf16 node activations
    float* t1    = wsf + off;                            // chunked N x 2H hidden

    size_t left = (ws_floats > off) ? (ws_floats - off) : 0;
    long long chl = (long long)(left / (size_t)H2);
    int CH = (int)((chl > N) ? N : chl);
    CH = (CH / 64) * 64;
    if (CH < 64) {
        // Workspace too small: fail fast and leak ws_size (in MB) via absmax.
        k_fill<<<64, 256, 0, stream>>>(out, (float)(ws_size >> 20), G);
        return;
    }

    auto gemm_f = [&](const float* A, const float* B, const float* bias, const float* bn,
                      const float* res, float* C, int M, int Nc, int K, int flags) {
        dim3 grid((M + GBM - 1) / GBM, (Nc + GBN - 1) / GBN);
        k_gemm<<<grid, dim3(256), 0, stream>>>(A, B, bias, bn, res, nullptr, C, nullptr,
                                               M, Nc, K, flags);
    };
    auto gemm_b = [&](const float* A, const float* B, const float* bias, const float* bn,
                      const bf16* resb, bf16* Cb, int M, int Nc, int K, int flags) {
        dim3 grid((M + GBM - 1) / GBM, (Nc + GBN - 1) / GBN);
        k_gemm<<<grid, dim3(256), 0, stream>>>(A, B, bias, bn, nullptr, resb, nullptr, Cb,
                                               M, Nc, K, flags);
    };
    auto zero = [&](float* p, size_t n) { k_zero<<<2048, 256, 0, stream>>>(p, n); };

    const int NH = N * H;

    zero(hg, fG);
    zero(vn, fG);

    k_eptable<<<L * BV, 320, 0, stream>>>(bond_emb, We, be, tbl, BV, H, ED);
    k_encode<<<2048, 256, 0, stream>>>(x, atom_emb, hbf, H, NH);

    for (int i = 0; i < L; i++) {
        if (i > 0) {
            k_add<<<1024, 256, 0, stream>>>(hp, vn, vn_in, G * H);
            gemm_f(vn_in, vnW1, vnb1, vnbn, nullptr, vn_t, G, H, H, 1);
            gemm_f(vn_t, vnW2, vnb2, nullptr, nullptr, vn, G, H, H, 0);
            k_addvn<<<2048, 256, 0, stream>>>(hbf, vn, batch, H, NH);
        }
        // GINEConv aggregation: agg = scatter-add relu(h_src + ep); z = (1+eps)h + agg
        zero(agg, fN);
        k_message<<<8192, 320, 0, stream>>>(src, dst, edge_attr, hbf,
                                            tbl + (size_t)i * BV * H, agg, H, E);
        k_zmix<<<4096, 256, 0, stream>>>(hbf, agg, epsp, i, NH);
        // node MLP, row-chunked through t1; h_new written bf16 in place
        for (int r0 = 0; r0 < N; r0 += CH) {
            int m = (N - r0 < CH) ? (N - r0) : CH;
            gemm_f(agg + (size_t)r0 * H, W1 + (size_t)i * H2 * H, b1 + (size_t)i * H2,
                   bn1 + (size_t)i * 4 * H2, nullptr, t1, m, H2, H, 1);
            gemm_b(t1, W2 + (size_t)i * H * H2, b2 + (size_t)i * H, bn2 + (size_t)i * 4 * H,
                   (i > 0) ? (hbf + (size_t)r0 * H) : nullptr, hbf + (size_t)r0 * H,
                   m, H, H2, 1);
        }
        // pooling + graph accumulation
        zero(hp, fG);
        k_pool<<<8192, 320, 0, stream>>>(hbf, batch, hp, H, N);
        gemm_f(hp, Wp + (size_t)i * H * H, bp + (size_t)i * H, nullptr, nullptr, hg,
               G, H, H, 2);
    }

    // readout
    k_ln_silu<<<G, 256, 0, stream>>>(hg, ln_g, ln_b, rbuf, H);
    gemm_f(rbuf, hW1, hb1, nullptr, nullptr, r2, G, HH, H, 1);
    k_head2<<<G, 64, 0, stream>>>(r2, hW2, hb2, out, HH);
}

// Round 5
// 5270.844 us; speedup vs baseline: 1.9703x; 1.9703x over previous
//
#include <hip/hip_runtime.h>
#include <hip/hip_bf16.h>
#include <math.h>

// ---------------------------------------------------------------------------
// GIN model (GINEConv x5 + virtual node + readout).
// Node-MLP GEMMs on bf16 MFMA (16x16x32), row-chunked to fit 256 MiB ws.
// Everything else fp32. Sentinel fail-fast leaks 10000+ws_MB via absmax.
// ---------------------------------------------------------------------------

typedef __hip_bfloat16 bf16;
typedef __attribute__((ext_vector_type(8))) __bf16 bf16x8;
typedef __attribute__((ext_vector_type(8))) short short8;
typedef __attribute__((ext_vector_type(4))) float f32x4;

#define LDSW 40   // padded LDS row stride (shorts) to break bank conflicts

__device__ __forceinline__ float silu_f(float v) { return v / (1.0f + __expf(-v)); }

__global__ void k_fill(float* __restrict__ p, float v, int n) {
    int stride = gridDim.x * blockDim.x;
    for (int i = blockIdx.x * blockDim.x + threadIdx.x; i < n; i += stride) p[i] = v;
}

__global__ void k_zero(float* __restrict__ p, size_t n) {
    size_t stride = (size_t)gridDim.x * blockDim.x;
    for (size_t i = (size_t)blockIdx.x * blockDim.x + threadIdx.x; i < n; i += stride)
        p[i] = 0.0f;
}

// tbl[l][a][j] = bond_emb[a] . We[l][j] + be[l][j]
__global__ void k_eptable(const float* __restrict__ bond_emb,
                          const float* __restrict__ We,
                          const float* __restrict__ be,
                          float* __restrict__ tbl, int BV, int H, int ED) {
    int l = blockIdx.x / BV;
    int a = blockIdx.x % BV;
    int j = threadIdx.x;
    if (j >= H) return;
    const float* w = We + ((size_t)l * H + j) * ED;
    const float* bb = bond_emb + (size_t)a * ED;
    float s = be[(size_t)l * H + j];
    for (int k = 0; k < ED; k++) s += bb[k] * w[k];
    tbl[((size_t)l * BV + a) * H + j] = s;
}

// h_bf[n*H+j] = atom_emb[x[n]*H+j]
__global__ void k_encode(const int* __restrict__ x, const float* __restrict__ emb,
                         bf16* __restrict__ h, int H, int total) {
    int stride = gridDim.x * blockDim.x;
    for (int i = blockIdx.x * blockDim.x + threadIdx.x; i < total; i += stride) {
        int n = i / H, j = i - n * H;
        h[i] = __float2bfloat16(emb[(size_t)x[n] * H + j]);
    }
}

// agg[dst] += relu(h[src] + tbl[ea])
__global__ void k_message(const int* __restrict__ src, const int* __restrict__ dst,
                          const int* __restrict__ ea,
                          const bf16* __restrict__ h, const float* __restrict__ tbl,
                          float* __restrict__ agg, int H, int E) {
    int j = threadIdx.x;
    if (j >= H) return;
    for (int e = blockIdx.x; e < E; e += gridDim.x) {
        int s = src[e], d = dst[e], a = ea[e];
        float v = __bfloat162float(h[(size_t)s * H + j]) + tbl[(size_t)a * H + j];
        if (v > 0.0f) atomicAdd(&agg[(size_t)d * H + j], v);
    }
}

// zb[n][c] = (c < H) ? (1+eps)*h[n][c] + agg[n][c] : 0   (bf16, stride KP1)
__global__ void k_zmix_pad(const bf16* __restrict__ h, const float* __restrict__ agg,
                           bf16* __restrict__ zb, const float* __restrict__ epsp,
                           int l, int H, int KP1, int total) {
    float e = 1.0f + epsp[l];
    int stride = gridDim.x * blockDim.x;
    for (int i = blockIdx.x * blockDim.x + threadIdx.x; i < total; i += stride) {
        int n = i / KP1, c = i - n * KP1;
        float v = 0.0f;
        if (c < H) {
            size_t idx = (size_t)n * H + c;
            v = e * __bfloat162float(h[idx]) + agg[idx];
        }
        zb[i] = __float2bfloat16(v);
    }
}

__global__ void k_add(const float* __restrict__ a, const float* __restrict__ b,
                      float* __restrict__ c, int n) {
    int stride = gridDim.x * blockDim.x;
    for (int i = blockIdx.x * blockDim.x + threadIdx.x; i < n; i += stride)
        c[i] = a[i] + b[i];
}

// h[i] += vn[batch[i/H]*H + i%H]
__global__ void k_addvn(bf16* __restrict__ h, const float* __restrict__ vn,
                        const int* __restrict__ batch, int H, int total) {
    int stride = gridDim.x * blockDim.x;
    for (int i = blockIdx.x * blockDim.x + threadIdx.x; i < total; i += stride) {
        int n = i / H, j = i - n * H;
        h[i] = __float2bfloat16(__bfloat162float(h[i]) + vn[(size_t)batch[n] * H + j]);
    }
}

// hp[batch[n]] += h[n]
__global__ void k_pool(const bf16* __restrict__ h, const int* __restrict__ batch,
                       float* __restrict__ hp, int H, int N) {
    int j = threadIdx.x;
    if (j >= H) return;
    for (int n = blockIdx.x; n < N; n += gridDim.x) {
        atomicAdd(&hp[(size_t)batch[n] * H + j], __bfloat162float(h[(size_t)n * H + j]));
    }
}

// weight cast + zero-pad: Wb[r][c] (Rp x Kp) = (r<R && c<K) ? W[r*K+c] : 0
__global__ void k_castw(const float* __restrict__ W, bf16* __restrict__ Wb,
                        int R, int K, int Kp, int total) {
    int stride = gridDim.x * blockDim.x;
    for (int i = blockIdx.x * blockDim.x + threadIdx.x; i < total; i += stride) {
        int r = i / Kp, c = i - r * Kp;
        float v = (r < R && c < K) ? W[(size_t)r * K + c] : 0.0f;
        Wb[i] = __float2bfloat16(v);
    }
}

// --- MFMA GEMM: out[m,n] = epi( sum_k A[m,k]*B[n,k] ), A,B bf16 k-contig.
//     Kp multiple of 32. Rows >= M in A may be stale (discarded by row guard).
//     epi: +bias, BN(4xNc fp32), SiLU, +resb(bf16), store bf16 at ldOut.
//     Cols in [Nc, ldPad) are written as 0 (K-pad cleaning for chained GEMMs).
__global__ __launch_bounds__(256)
void k_mfma_gemm(const bf16* __restrict__ A, const bf16* __restrict__ B,
                 const float* __restrict__ bias, const float* __restrict__ bn,
                 const bf16* __restrict__ resb, bf16* __restrict__ out,
                 int M, int Nc, int Kp, int ldA, int ldOut, int ldPad, int dosilu) {
    __shared__ short As[128 * LDSW];
    __shared__ short Bs[128 * LDSW];
    const int tid = threadIdx.x;
    const int wave = tid >> 6, lane = tid & 63;
    const int wr = wave >> 1, wc = wave & 1;
    const int bm = blockIdx.x * 128, bn0 = blockIdx.y * 128;
    const int l15 = lane & 15, l4 = lane >> 4;

    f32x4 acc[4][4];
    #pragma unroll
    for (int mi = 0; mi < 4; mi++)
        #pragma unroll
        for (int ni = 0; ni < 4; ni++)
            acc[mi][ni] = (f32x4){0.f, 0.f, 0.f, 0.f};

    for (int k0 = 0; k0 < Kp; k0 += 32) {
        #pragma unroll
        for (int cc = 0; cc < 2; cc++) {
            int c = tid * 2 + cc;
            int row = c >> 2, kc = (c & 3) << 3;
            short8 va = *(const short8*)(A + (size_t)(bm + row) * ldA + k0 + kc);
            *(short8*)&As[row * LDSW + kc] = va;
            short8 vb = *(const short8*)(B + (size_t)(bn0 + row) * Kp + k0 + kc);
            *(short8*)&Bs[row * LDSW + kc] = vb;
        }
        __syncthreads();
        bf16x8 a[4], b[4];
        #pragma unroll
        for (int mi = 0; mi < 4; mi++)
            a[mi] = *(const bf16x8*)&As[(wr * 64 + mi * 16 + l15) * LDSW + l4 * 8];
        #pragma unroll
        for (int ni = 0; ni < 4; ni++)
            b[ni] = *(const bf16x8*)&Bs[(wc * 64 + ni * 16 + l15) * LDSW + l4 * 8];
        #pragma unroll
        for (int mi = 0; mi < 4; mi++)
            #pragma unroll
            for (int ni = 0; ni < 4; ni++)
                acc[mi][ni] = __builtin_amdgcn_mfma_f32_16x16x32_bf16(
                    a[mi], b[ni], acc[mi][ni], 0, 0, 0);
        __syncthreads();
    }

    #pragma unroll
    for (int ni = 0; ni < 4; ni++) {
        int col = bn0 + wc * 64 + ni * 16 + l15;
        if (col >= ldPad) continue;
        bool pad = (col >= Nc);
        float bi = (!pad && bias) ? bias[col] : 0.f;
        float sc = 1.f, mm = 0.f, bb = 0.f;
        if (!pad && bn) {
            sc = bn[col] * rsqrtf(bn[3 * Nc + col] + 1e-5f);
            mm = bn[2 * Nc + col];
            bb = bn[Nc + col];
        }
        #pragma unroll
        for (int mi = 0; mi < 4; mi++) {
            #pragma unroll
            for (int r = 0; r < 4; r++) {
                int row = bm + wr * 64 + mi * 16 + l4 * 4 + r;
                if (row >= M) continue;
                size_t idx = (size_t)row * ldOut + col;
                if (pad) { out[idx] = __float2bfloat16(0.f); continue; }
                float v = acc[mi][ni][r] + bi;
                if (bn) v = (v - mm) * sc + bb;
                if (dosilu) v = silu_f(v);
                if (resb) v += __bfloat162float(resb[idx]);
                out[idx] = __float2bfloat16(v);
            }
        }
    }
}

// --- small fp32 GEMM (vn / pool / readout): C[m,n] = sum_k A[m,k]*B[n,k]
#define GBM 64
#define GBN 64
#define GBK 16
__global__ __launch_bounds__(256)
void k_gemm(const float* __restrict__ A, const float* __restrict__ B,
            const float* __restrict__ bias, const float* __restrict__ bn,
            float* __restrict__ C, int M, int Nc, int K, int flags) { // 1=silu 2=accum
    __shared__ float As[GBK][GBM + 4];
    __shared__ float Bs[GBK][GBN + 4];
    const int bm = blockIdx.x * GBM;
    const int bnc = blockIdx.y * GBN;
    const int tid = threadIdx.x;
    const int tx = tid & 15, ty = tid >> 4;
    const int ar = tid >> 2;
    const int ak = (tid & 3) << 2;

    float acc[4][4] = {{0.f}};

    for (int k0 = 0; k0 < K; k0 += GBK) {
        {
            int gr = bm + ar, gk = k0 + ak;
            float4 v = make_float4(0.f, 0.f, 0.f, 0.f);
            if (gr < M && gk < K) {
                const float* p = A + (size_t)gr * K;
                if (gk + 3 < K) v = *(const float4*)(p + gk);
                else {
                    v.x = p[gk];
                    if (gk + 1 < K) v.y = p[gk + 1];
                    if (gk + 2 < K) v.z = p[gk + 2];
                }
            }
            As[ak][ar] = v.x; As[ak + 1][ar] = v.y; As[ak + 2][ar] = v.z; As[ak + 3][ar] = v.w;
        }
        {
            int gr = bnc + ar, gk = k0 + ak;
            float4 v = make_float4(0.f, 0.f, 0.f, 0.f);
            if (gr < Nc && gk < K) {
                const float* p = B + (size_t)gr * K;
                if (gk + 3 < K) v = *(const float4*)(p + gk);
                else {
                    v.x = p[gk];
                    if (gk + 1 < K) v.y = p[gk + 1];
                    if (gk + 2 < K) v.z = p[gk + 2];
                }
            }
            Bs[ak][ar] = v.x; Bs[ak + 1][ar] = v.y; Bs[ak + 2][ar] = v.z; Bs[ak + 3][ar] = v.w;
        }
        __syncthreads();
        #pragma unroll
        for (int kk = 0; kk < GBK; kk++) {
            float4 a = *(const float4*)&As[kk][ty * 4];
            float4 b = *(const float4*)&Bs[kk][tx * 4];
            acc[0][0] += a.x * b.x; acc[0][1] += a.x * b.y; acc[0][2] += a.x * b.z; acc[0][3] += a.x * b.w;
            acc[1][0] += a.y * b.x; acc[1][1] += a.y * b.y; acc[1][2] += a.y * b.z; acc[1][3] += a.y * b.w;
            acc[2][0] += a.z * b.x; acc[2][1] += a.z * b.y; acc[2][2] += a.z * b.z; acc[2][3] += a.z * b.w;
            acc[3][0] += a.w * b.x; acc[3][1] += a.w * b.y; acc[3][2] += a.w * b.z; acc[3][3] += a.w * b.w;
        }
        __syncthreads();
    }

    #pragma unroll
    for (int i = 0; i < 4; i++) {
        int row = bm + ty * 4 + i;
        if (row >= M) continue;
        #pragma unroll
        for (int j = 0; j < 4; j++) {
            int col = bnc + tx * 4 + j;
            if (col >= Nc) continue;
            float v = acc[i][j];
            if (bias) v += bias[col];
            if (bn) {
                float g = bn[col], bb = bn[Nc + col], mm = bn[2 * Nc + col], vv = bn[3 * Nc + col];
                v = (v - mm) * (g * rsqrtf(vv + 1e-5f)) + bb;
            }
            if (flags & 1) v = silu_f(v);
            size_t idx = (size_t)row * Nc + col;
            if (flags & 2) C[idx] += v;
            else           C[idx] = v;
        }
    }
}

// per-row LayerNorm + SiLU
__global__ __launch_bounds__(256)
void k_ln_silu(const float* __restrict__ hg, const float* __restrict__ g,
               const float* __restrict__ b, float* __restrict__ r, int H) {
    int gi = blockIdx.x;
    const float* row = hg + (size_t)gi * H;
    float s = 0.f, s2 = 0.f;
    for (int j = threadIdx.x; j < H; j += blockDim.x) {
        float v = row[j];
        s += v; s2 += v * v;
    }
    for (int off = 32; off; off >>= 1) {
        s += __shfl_down(s, off);
        s2 += __shfl_down(s2, off);
    }
    __shared__ float rs[4], rs2[4];
    int wid = threadIdx.x >> 6, lane = threadIdx.x & 63;
    if (lane == 0) { rs[wid] = s; rs2[wid] = s2; }
    __syncthreads();
    if (threadIdx.x == 0) {
        float S = 0.f, S2 = 0.f;
        for (int w = 0; w < 4; w++) { S += rs[w]; S2 += rs2[w]; }
        rs[0] = S; rs2[0] = S2;
    }
    __syncthreads();
    float mu = rs[0] / H;
    float var = rs2[0] / H - mu * mu;
    float inv = rsqrtf(var + 1e-5f);
    for (int j = threadIdx.x; j < H; j += blockDim.x) {
        float v = (row[j] - mu) * inv * g[j] + b[j];
        r[(size_t)gi * H + j] = silu_f(v);
    }
}

__global__ void k_head2(const float* __restrict__ r2, const float* __restrict__ w,
                        const float* __restrict__ b, float* __restrict__ out, int Kh) {
    int gi = blockIdx.x;
    int t = threadIdx.x;
    float s = 0.f;
    for (int k = t; k < Kh; k += 64) s += r2[(size_t)gi * Kh + k] * w[k];
    for (int off = 32; off; off >>= 1) s += __shfl_down(s, off);
    if (t == 0) out[gi] = s + b[0];
}

extern "C" void kernel_launch(void* const* d_in, const int* in_sizes, int n_in,
                              void* d_out, int out_size, void* d_ws, size_t ws_size,
                              hipStream_t stream) {
    const int*   x         = (const int*)d_in[0];
    const int*   edge_attr = (const int*)d_in[1];
    const int*   eidx      = (const int*)d_in[2];
    const int*   batch     = (const int*)d_in[3];
    const float* atom_emb  = (const float*)d_in[5];
    const float* bond_emb  = (const float*)d_in[6];
    const float* We  = (const float*)d_in[7];
    const float* be  = (const float*)d_in[8];
    const float* W1  = (const float*)d_in[9];
    const float* b1  = (const float*)d_in[10];
    const float* bn1 = (const float*)d_in[11];
    const float* W2  = (const float*)d_in[12];
    const float* b2  = (const float*)d_in[13];
    const float* bn2 = (const float*)d_in[14];
    const float* epsp= (const float*)d_in[15];
    const float* Wp  = (const float*)d_in[16];
    const float* bp  = (const float*)d_in[17];
    const float* vnW1= (const float*)d_in[18];
    const float* vnb1= (const float*)d_in[19];
    const float* vnbn= (const float*)d_in[20];
    const float* vnW2= (const float*)d_in[21];
    const float* vnb2= (const float*)d_in[22];
    const float* ln_g= (const float*)d_in[23];
    const float* ln_b= (const float*)d_in[24];
    const float* hW1 = (const float*)d_in[25];
    const float* hb1 = (const float*)d_in[26];
    const float* hW2 = (const float*)d_in[27];
    const float* hb2 = (const float*)d_in[28];
    float* out = (float*)d_out;

    const int N  = in_sizes[0];
    const int E  = in_sizes[1];
    const int G  = out_size;
    const int L  = in_sizes[15];
    const int H  = in_sizes[19];
    const int H2 = 2 * H;
    const int ED = in_sizes[7] / (L * H);
    const int BV = in_sizes[6] / ED;
    const int HH = in_sizes[26];
    (void)n_in;

    const int* src = eidx;
    const int* dst = eidx + E;

    // padded dims for MFMA path
    const int KP1 = ((H  + 31) / 32) * 32;            // 320
    const int KP2 = ((H2 + 31) / 32) * 32;            // 608
    const int RP1 = ((H2 + 127) / 128) * 128;         // 640
    const int RP2 = ((H  + 127) / 128) * 128;         // 384

    // ---- workspace carve-up (bytes, 256B aligned), strictly within ws_size ----
    char* wsb = (char*)d_ws;
    auto alb = [](size_t v) { return (v + 255) & ~(size_t)255; };
    const size_t fN = (size_t)N * H;
    const size_t fG = (size_t)G * H;

    size_t off = 0;
    float* agg   = (float*)(wsb + off); off += alb(fN * 4);
    bf16*  hbf   = (bf16*) (wsb + off); off += alb(fN * 2);
    float* hp    = (float*)(wsb + off); off += alb(fG * 4);
    float* hg    = (float*)(wsb + off); off += alb(fG * 4);
    float* vn    = (float*)(wsb + off); off += alb(fG * 4);
    float* vn_in = (float*)(wsb + off); off += alb(fG * 4);
    float* vn_t  = (float*)(wsb + off); off += alb(fG * 4);
    float* rbuf  = (float*)(wsb + off); off += alb(fG * 4);
    float* r2    = (float*)(wsb + off); off += alb((size_t)G * HH * 4);
    float* tbl   = (float*)(wsb + off); off += alb((size_t)L * BV * H * 4);
    bf16*  W1b   = (bf16*) (wsb + off); off += alb((size_t)RP1 * KP1 * 2);
    bf16*  W2b   = (bf16*) (wsb + off); off += alb((size_t)RP2 * KP2 * 2);

    // chunk region: zb (CH x KP1 bf16) + t1 (CH x KP2 bf16)
    size_t left = (ws_size > off) ? (ws_size - off - 256) : 0;
    const size_t per_row = (size_t)(KP1 + KP2) * 2;
    long long chl = (long long)(left / per_row);
    const int Npad = ((N + 127) / 128) * 128;
    int CH = (int)((chl > Npad) ? Npad : chl);
    CH = (CH / 128) * 128;
    if (CH < 128) {
        // Workspace too small: unambiguous sentinel 10000 + ws_MB.
        k_fill<<<64, 256, 0, stream>>>(out, 10000.0f + (float)(ws_size >> 20), G);
        return;
    }
    bf16* zb = (bf16*)(wsb + off);
    bf16* t1 = zb + (size_t)CH * KP1;

    auto gemm_f = [&](const float* A, const float* B, const float* bias, const float* bn,
                      float* C, int M, int Nc, int K, int flags) {
        dim3 grid((M + GBM - 1) / GBM, (Nc + GBN - 1) / GBN);
        k_gemm<<<grid, dim3(256), 0, stream>>>(A, B, bias, bn, C, M, Nc, K, flags);
    };
    auto zero = [&](float* p, size_t n) { k_zero<<<2048, 256, 0, stream>>>(p, n); };

    const int NH = N * H;

    zero(hg, fG);
    zero(vn, fG);

    k_eptable<<<L * BV, 320, 0, stream>>>(bond_emb, We, be, tbl, BV, H, ED);
    k_encode<<<2048, 256, 0, stream>>>(x, atom_emb, hbf, H, NH);

    for (int i = 0; i < L; i++) {
        if (i > 0) {
            k_add<<<1024, 256, 0, stream>>>(hp, vn, vn_in, G * H);
            gemm_f(vn_in, vnW1, vnb1, vnbn, vn_t, G, H, H, 1);
            gemm_f(vn_t, vnW2, vnb2, nullptr, vn, G, H, H, 0);
            k_addvn<<<2048, 256, 0, stream>>>(hbf, vn, batch, H, NH);
        }
        // aggregation: agg = scatter-add relu(h_src + ep)
        zero(agg, fN);
        k_message<<<8192, 320, 0, stream>>>(src, dst, edge_attr, hbf,
                                            tbl + (size_t)i * BV * H, agg, H, E);
        // weights -> bf16 padded
        k_castw<<<512, 256, 0, stream>>>(W1 + (size_t)i * H2 * H, W1b, H2, H, KP1, RP1 * KP1);
        k_castw<<<512, 256, 0, stream>>>(W2 + (size_t)i * H * H2, W2b, H, H2, KP2, RP2 * KP2);
        // node MLP, row-chunked
        for (int r0 = 0; r0 < N; r0 += CH) {
            int m = (N - r0 < CH) ? (N - r0) : CH;
            int mt = (m + 127) / 128;
            // zb = (1+eps)h + agg  (bf16, K-padded)
            k_zmix_pad<<<4096, 256, 0, stream>>>(hbf + (size_t)r0 * H, agg + (size_t)r0 * H,
                                                 zb, epsp, i, H, KP1, m * KP1);
            dim3 g1(mt, RP1 / 128);
            k_mfma_gemm<<<g1, dim3(256), 0, stream>>>(
                zb, W1b, b1 + (size_t)i * H2, bn1 + (size_t)i * 4 * H2,
                nullptr, t1, m, H2, KP1, KP1, KP2, KP2, 1);
            dim3 g2(mt, RP2 / 128);
            k_mfma_gemm<<<g2, dim3(256), 0, stream>>>(
                t1, W2b, b2 + (size_t)i * H, bn2 + (size_t)i * 4 * H,
                (i > 0) ? (hbf + (size_t)r0 * H) : nullptr, hbf + (size_t)r0 * H,
                m, H, KP2, KP2, H, H, 1);
        }
        // pooling + graph accumulation
        zero(hp, fG);
        k_pool<<<8192, 320, 0, stream>>>(hbf, batch, hp, H, N);
        gemm_f(hp, Wp + (size_t)i * H * H, bp + (size_t)i * H, nullptr, hg, G, H, H, 2);
    }

    // readout
    k_ln_silu<<<G, 256, 0, stream>>>(hg, ln_g, ln_b, rbuf, H);
    gemm_f(rbuf, hW1, hb1, nullptr, r2, G, HH, H, 1);
    k_head2<<<G, 64, 0, stream>>>(r2, hW2, hb2, out, HH);
}

// Round 6
// 3561.858 us; speedup vs baseline: 2.9157x; 1.4798x over previous
//
#include <hip/hip_runtime.h>
#include <hip/hip_bf16.h>
#include <math.h>

// ---------------------------------------------------------------------------
// GIN model (GINEConv x5 + virtual node + readout).
// CSR-based message passing + pooling (no atomics in the hot path).
// Node-MLP GEMMs on bf16 MFMA (16x16x32), t1 row-chunked to fit 256 MiB ws.
// ---------------------------------------------------------------------------

typedef __hip_bfloat16 bf16;
typedef __attribute__((ext_vector_type(8))) __bf16 bf16x8;
typedef __attribute__((ext_vector_type(8))) short short8;
typedef __attribute__((ext_vector_type(4))) float f32x4;

#define LDSW 40   // padded LDS row stride (shorts) to break bank conflicts

__device__ __forceinline__ float silu_f(float v) { return v / (1.0f + __expf(-v)); }

__global__ void k_fill(float* __restrict__ p, float v, int n) {
    int stride = gridDim.x * blockDim.x;
    for (int i = blockIdx.x * blockDim.x + threadIdx.x; i < n; i += stride) p[i] = v;
}

__global__ void k_zero(float* __restrict__ p, size_t n) {
    size_t stride = (size_t)gridDim.x * blockDim.x;
    for (size_t i = (size_t)blockIdx.x * blockDim.x + threadIdx.x; i < n; i += stride)
        p[i] = 0.0f;
}

// ---------------- CSR build helpers ----------------
__global__ void k_hist(const int* __restrict__ key, int* __restrict__ cnt, int n) {
    int stride = gridDim.x * blockDim.x;
    for (int i = blockIdx.x * blockDim.x + threadIdx.x; i < n; i += stride)
        atomicAdd(&cnt[key[i]], 1);
}

// per-1024-block exclusive scan; bsum[b] = block total (if bsum != null).
// Safe in-place (out==in) for a single-block launch.
__global__ __launch_bounds__(256)
void k_scan1(const int* __restrict__ in, int* __restrict__ out,
             int* __restrict__ bsum, int n) {
    __shared__ int wsum[4];
    int base = blockIdx.x << 10;
    int t = threadIdx.x;
    int i0 = base + t * 4;
    int v0 = (i0 + 0 < n) ? in[i0 + 0] : 0;
    int v1 = (i0 + 1 < n) ? in[i0 + 1] : 0;
    int v2 = (i0 + 2 < n) ? in[i0 + 2] : 0;
    int v3 = (i0 + 3 < n) ? in[i0 + 3] : 0;
    int s = v0 + v1 + v2 + v3;
    int lane = t & 63, wid = t >> 6;
    int x = s;
    for (int d = 1; d < 64; d <<= 1) {
        int y = __shfl_up(x, d);
        if (lane >= d) x += y;
    }
    if (lane == 63) wsum[wid] = x;
    __syncthreads();
    int wadd = 0;
    for (int w = 0; w < wid; w++) wadd += wsum[w];
    x += wadd;               // inclusive over block
    int run = x - s;         // exclusive start for this thread
    if (i0 + 0 < n) out[i0 + 0] = run; run += v0;
    if (i0 + 1 < n) out[i0 + 1] = run; run += v1;
    if (i0 + 2 < n) out[i0 + 2] = run; run += v2;
    if (i0 + 3 < n) out[i0 + 3] = run; run += v3;
    if (bsum && t == 255) bsum[blockIdx.x] = x;
}

__global__ void k_scan_add(int* __restrict__ out, const int* __restrict__ bsum,
                           int* __restrict__ cur, int n, int total) {
    int stride = gridDim.x * blockDim.x;
    for (int i = blockIdx.x * blockDim.x + threadIdx.x; i < n; i += stride) {
        int v = out[i] + bsum[i >> 10];
        out[i] = v;
        if (cur) cur[i] = v;
    }
    if (blockIdx.x == 0 && threadIdx.x == 0) out[n] = total;
}

__global__ void k_escatter(const int* __restrict__ dst, const int* __restrict__ src,
                           const int* __restrict__ ea, int* __restrict__ cur,
                           int* __restrict__ esrc, int* __restrict__ eea, int E) {
    int stride = gridDim.x * blockDim.x;
    for (int e = blockIdx.x * blockDim.x + threadIdx.x; e < E; e += stride) {
        int p = atomicAdd(&cur[dst[e]], 1);
        esrc[p] = src[e];
        eea[p]  = ea[e];
    }
}

// ---------------- model kernels ----------------
// tbl[l][a][j] = bond_emb[a] . We[l][j] + be[l][j]
__global__ void k_eptable(const float* __restrict__ bond_emb,
                          const float* __restrict__ We,
                          const float* __restrict__ be,
                          float* __restrict__ tbl, int BV, int H, int ED) {
    int l = blockIdx.x / BV;
    int a = blockIdx.x % BV;
    int j = threadIdx.x;
    if (j >= H) return;
    const float* w = We + ((size_t)l * H + j) * ED;
    const float* bb = bond_emb + (size_t)a * ED;
    float s = be[(size_t)l * H + j];
    for (int k = 0; k < ED; k++) s += bb[k] * w[k];
    tbl[((size_t)l * BV + a) * H + j] = s;
}

__global__ void k_encode(const int* __restrict__ x, const float* __restrict__ emb,
                         bf16* __restrict__ h, int H, int total) {
    int stride = gridDim.x * blockDim.x;
    for (int i = blockIdx.x * blockDim.x + threadIdx.x; i < total; i += stride) {
        int n = i / H, j = i - n * H;
        h[i] = __float2bfloat16(emb[(size_t)x[n] * H + j]);
    }
}

// CSR message + zmix fused:
// zb[n][j] = (j<H) ? (1+eps)*h[n][j] + sum_{e in CSR[n]} relu(h[esrc[e]][j]+tbl[eea[e]][j]) : 0
__global__ __launch_bounds__(320)
void k_msg_csr(const int* __restrict__ eoff, const int* __restrict__ esrc,
               const int* __restrict__ eea, const bf16* __restrict__ h,
               const float* __restrict__ tbl, const float* __restrict__ epsp, int l,
               bf16* __restrict__ zb, int H, int KP1, int N) {
    int j = threadIdx.x;                       // 0..KP1-1 (KP1 == blockDim.x)
    float epl = 1.0f + epsp[l];
    for (int n = blockIdx.x; n < N; n += gridDim.x) {
        float z = 0.0f;
        if (j < H) {
            float s = 0.0f;
            int e0 = eoff[n], e1 = eoff[n + 1];
            for (int e = e0; e < e1; e++) {
                float v = __bfloat162float(h[(size_t)esrc[e] * H + j])
                        + tbl[(size_t)eea[e] * H + j];
                if (v > 0.0f) s += v;
            }
            z = epl * __bfloat162float(h[(size_t)n * H + j]) + s;
        }
        zb[(size_t)n * KP1 + j] = __float2bfloat16(z);
    }
}

// CSR pooling (batch sorted): hp[g][j] = sum_{n in [goff[g],goff[g+1])} h[n][j]
__global__ __launch_bounds__(320)
void k_pool_csr(const int* __restrict__ goff, const bf16* __restrict__ h,
                float* __restrict__ hp, int H, int G) {
    int j = threadIdx.x;
    if (j >= H) return;
    for (int g = blockIdx.x; g < G; g += gridDim.x) {
        float s = 0.0f;
        int n0 = goff[g], n1 = goff[g + 1];
        for (int n = n0; n < n1; n++)
            s += __bfloat162float(h[(size_t)n * H + j]);
        hp[(size_t)g * H + j] = s;
    }
}

__global__ void k_add(const float* __restrict__ a, const float* __restrict__ b,
                      float* __restrict__ c, int n) {
    int stride = gridDim.x * blockDim.x;
    for (int i = blockIdx.x * blockDim.x + threadIdx.x; i < n; i += stride)
        c[i] = a[i] + b[i];
}

__global__ void k_addvn(bf16* __restrict__ h, const float* __restrict__ vn,
                        const int* __restrict__ batch, int H, int total) {
    int stride = gridDim.x * blockDim.x;
    for (int i = blockIdx.x * blockDim.x + threadIdx.x; i < total; i += stride) {
        int n = i / H, j = i - n * H;
        h[i] = __float2bfloat16(__bfloat162float(h[i]) + vn[(size_t)batch[n] * H + j]);
    }
}

// weight cast + zero-pad: Wb[r][c] (Rp x Kp) = (r<R && c<K) ? W[r*K+c] : 0
__global__ void k_castw(const float* __restrict__ W, bf16* __restrict__ Wb,
                        int R, int K, int Kp, int total) {
    int stride = gridDim.x * blockDim.x;
    for (int i = blockIdx.x * blockDim.x + threadIdx.x; i < total; i += stride) {
        int r = i / Kp, c = i - r * Kp;
        float v = (r < R && c < K) ? W[(size_t)r * K + c] : 0.0f;
        Wb[i] = __float2bfloat16(v);
    }
}

// --- MFMA GEMM: out[m,n] = epi( sum_k A[m,k]*B[n,k] ), A,B bf16 k-contig.
__global__ __launch_bounds__(256)
void k_mfma_gemm(const bf16* __restrict__ A, const bf16* __restrict__ B,
                 const float* __restrict__ bias, const float* __restrict__ bn,
                 const bf16* __restrict__ resb, bf16* __restrict__ out,
                 int M, int Nc, int Kp, int ldA, int ldOut, int ldPad, int dosilu) {
    __shared__ short As[128 * LDSW];
    __shared__ short Bs[128 * LDSW];
    const int tid = threadIdx.x;
    const int wave = tid >> 6, lane = tid & 63;
    const int wr = wave >> 1, wc = wave & 1;
    const int bm = blockIdx.x * 128, bn0 = blockIdx.y * 128;
    const int l15 = lane & 15, l4 = lane >> 4;

    f32x4 acc[4][4];
    #pragma unroll
    for (int mi = 0; mi < 4; mi++)
        #pragma unroll
        for (int ni = 0; ni < 4; ni++)
            acc[mi][ni] = (f32x4){0.f, 0.f, 0.f, 0.f};

    for (int k0 = 0; k0 < Kp; k0 += 32) {
        #pragma unroll
        for (int cc = 0; cc < 2; cc++) {
            int c = tid * 2 + cc;
            int row = c >> 2, kc = (c & 3) << 3;
            short8 va = *(const short8*)(A + (size_t)(bm + row) * ldA + k0 + kc);
            *(short8*)&As[row * LDSW + kc] = va;
            short8 vb = *(const short8*)(B + (size_t)(bn0 + row) * Kp + k0 + kc);
            *(short8*)&Bs[row * LDSW + kc] = vb;
        }
        __syncthreads();
        bf16x8 a[4], b[4];
        #pragma unroll
        for (int mi = 0; mi < 4; mi++)
            a[mi] = *(const bf16x8*)&As[(wr * 64 + mi * 16 + l15) * LDSW + l4 * 8];
        #pragma unroll
        for (int ni = 0; ni < 4; ni++)
            b[ni] = *(const bf16x8*)&Bs[(wc * 64 + ni * 16 + l15) * LDSW + l4 * 8];
        #pragma unroll
        for (int mi = 0; mi < 4; mi++)
            #pragma unroll
            for (int ni = 0; ni < 4; ni++)
                acc[mi][ni] = __builtin_amdgcn_mfma_f32_16x16x32_bf16(
                    a[mi], b[ni], acc[mi][ni], 0, 0, 0);
        __syncthreads();
    }

    #pragma unroll
    for (int ni = 0; ni < 4; ni++) {
        int col = bn0 + wc * 64 + ni * 16 + l15;
        if (col >= ldPad) continue;
        bool pad = (col >= Nc);
        float bi = (!pad && bias) ? bias[col] : 0.f;
        float sc = 1.f, mm = 0.f, bb = 0.f;
        if (!pad && bn) {
            sc = bn[col] * rsqrtf(bn[3 * Nc + col] + 1e-5f);
            mm = bn[2 * Nc + col];
            bb = bn[Nc + col];
        }
        #pragma unroll
        for (int mi = 0; mi < 4; mi++) {
            #pragma unroll
            for (int r = 0; r < 4; r++) {
                int row = bm + wr * 64 + mi * 16 + l4 * 4 + r;
                if (row >= M) continue;
                size_t idx = (size_t)row * ldOut + col;
                if (pad) { out[idx] = __float2bfloat16(0.f); continue; }
                float v = acc[mi][ni][r] + bi;
                if (bn) v = (v - mm) * sc + bb;
                if (dosilu) v = silu_f(v);
                if (resb) v += __bfloat162float(resb[idx]);
                out[idx] = __float2bfloat16(v);
            }
        }
    }
}

// --- small fp32 GEMM (vn / pool / readout): C[m,n] = sum_k A[m,k]*B[n,k]
#define GBM 64
#define GBN 64
#define GBK 16
__global__ __launch_bounds__(256)
void k_gemm(const float* __restrict__ A, const float* __restrict__ B,
            const float* __restrict__ bias, const float* __restrict__ bn,
            float* __restrict__ C, int M, int Nc, int K, int flags) { // 1=silu 2=accum
    __shared__ float As[GBK][GBM + 4];
    __shared__ float Bs[GBK][GBN + 4];
    const int bm = blockIdx.x * GBM;
    const int bnc = blockIdx.y * GBN;
    const int tid = threadIdx.x;
    const int tx = tid & 15, ty = tid >> 4;
    const int ar = tid >> 2;
    const int ak = (tid & 3) << 2;

    float acc[4][4] = {{0.f}};

    for (int k0 = 0; k0 < K; k0 += GBK) {
        {
            int gr = bm + ar, gk = k0 + ak;
            float4 v = make_float4(0.f, 0.f, 0.f, 0.f);
            if (gr < M && gk < K) {
                const float* p = A + (size_t)gr * K;
                if (gk + 3 < K) v = *(const float4*)(p + gk);
                else {
                    v.x = p[gk];
                    if (gk + 1 < K) v.y = p[gk + 1];
                    if (gk + 2 < K) v.z = p[gk + 2];
                }
            }
            As[ak][ar] = v.x; As[ak + 1][ar] = v.y; As[ak + 2][ar] = v.z; As[ak + 3][ar] = v.w;
        }
        {
            int gr = bnc + ar, gk = k0 + ak;
            float4 v = make_float4(0.f, 0.f, 0.f, 0.f);
            if (gr < Nc && gk < K) {
                const float* p = B + (size_t)gr * K;
                if (gk + 3 < K) v = *(const float4*)(p + gk);
                else {
                    v.x = p[gk];
                    if (gk + 1 < K) v.y = p[gk + 1];
                    if (gk + 2 < K) v.z = p[gk + 2];
                }
            }
            Bs[ak][ar] = v.x; Bs[ak + 1][ar] = v.y; Bs[ak + 2][ar] = v.z; Bs[ak + 3][ar] = v.w;
        }
        __syncthreads();
        #pragma unroll
        for (int kk = 0; kk < GBK; kk++) {
            float4 a = *(const float4*)&As[kk][ty * 4];
            float4 b = *(const float4*)&Bs[kk][tx * 4];
            acc[0][0] += a.x * b.x; acc[0][1] += a.x * b.y; acc[0][2] += a.x * b.z; acc[0][3] += a.x * b.w;
            acc[1][0] += a.y * b.x; acc[1][1] += a.y * b.y; acc[1][2] += a.y * b.z; acc[1][3] += a.y * b.w;
            acc[2][0] += a.z * b.x; acc[2][1] += a.z * b.y; acc[2][2] += a.z * b.z; acc[2][3] += a.z * b.w;
            acc[3][0] += a.w * b.x; acc[3][1] += a.w * b.y; acc[3][2] += a.w * b.z; acc[3][3] += a.w * b.w;
        }
        __syncthreads();
    }

    #pragma unroll
    for (int i = 0; i < 4; i++) {
        int row = bm + ty * 4 + i;
        if (row >= M) continue;
        #pragma unroll
        for (int j = 0; j < 4; j++) {
            int col = bnc + tx * 4 + j;
            if (col >= Nc) continue;
            float v = acc[i][j];
            if (bias) v += bias[col];
            if (bn) {
                float g = bn[col], bb = bn[Nc + col], mm = bn[2 * Nc + col], vv = bn[3 * Nc + col];
                v = (v - mm) * (g * rsqrtf(vv + 1e-5f)) + bb;
            }
            if (flags & 1) v = silu_f(v);
            size_t idx = (size_t)row * Nc + col;
            if (flags & 2) C[idx] += v;
            else           C[idx] = v;
        }
    }
}

// per-row LayerNorm + SiLU
__global__ __launch_bounds__(256)
void k_ln_silu(const float* __restrict__ hg, const float* __restrict__ g,
               const float* __restrict__ b, float* __restrict__ r, int H) {
    int gi = blockIdx.x;
    const float* row = hg + (size_t)gi * H;
    float s = 0.f, s2 = 0.f;
    for (int j = threadIdx.x; j < H; j += blockDim.x) {
        float v = row[j];
        s += v; s2 += v * v;
    }
    for (int off = 32; off; off >>= 1) {
        s += __shfl_down(s, off);
        s2 += __shfl_down(s2, off);
    }
    __shared__ float rs[4], rs2[4];
    int wid = threadIdx.x >> 6, lane = threadIdx.x & 63;
    if (lane == 0) { rs[wid] = s; rs2[wid] = s2; }
    __syncthreads();
    if (threadIdx.x == 0) {
        float S = 0.f, S2 = 0.f;
        for (int w = 0; w < 4; w++) { S += rs[w]; S2 += rs2[w]; }
        rs[0] = S; rs2[0] = S2;
    }
    __syncthreads();
    float mu = rs[0] / H;
    float var = rs2[0] / H - mu * mu;
    float inv = rsqrtf(var + 1e-5f);
    for (int j = threadIdx.x; j < H; j += blockDim.x) {
        float v = (row[j] - mu) * inv * g[j] + b[j];
        r[(size_t)gi * H + j] = silu_f(v);
    }
}

__global__ void k_head2(const float* __restrict__ r2, const float* __restrict__ w,
                        const float* __restrict__ b, float* __restrict__ out, int Kh) {
    int gi = blockIdx.x;
    int t = threadIdx.x;
    float s = 0.f;
    for (int k = t; k < Kh; k += 64) s += r2[(size_t)gi * Kh + k] * w[k];
    for (int off = 32; off; off >>= 1) s += __shfl_down(s, off);
    if (t == 0) out[gi] = s + b[0];
}

extern "C" void kernel_launch(void* const* d_in, const int* in_sizes, int n_in,
                              void* d_out, int out_size, void* d_ws, size_t ws_size,
                              hipStream_t stream) {
    const int*   x         = (const int*)d_in[0];
    const int*   edge_attr = (const int*)d_in[1];
    const int*   eidx      = (const int*)d_in[2];
    const int*   batch     = (const int*)d_in[3];
    const float* atom_emb  = (const float*)d_in[5];
    const float* bond_emb  = (const float*)d_in[6];
    const float* We  = (const float*)d_in[7];
    const float* be  = (const float*)d_in[8];
    const float* W1  = (const float*)d_in[9];
    const float* b1  = (const float*)d_in[10];
    const float* bn1 = (const float*)d_in[11];
    const float* W2  = (const float*)d_in[12];
    const float* b2  = (const float*)d_in[13];
    const float* bn2 = (const float*)d_in[14];
    const float* epsp= (const float*)d_in[15];
    const float* Wp  = (const float*)d_in[16];
    const float* bp  = (const float*)d_in[17];
    const float* vnW1= (const float*)d_in[18];
    const float* vnb1= (const float*)d_in[19];
    const float* vnbn= (const float*)d_in[20];
    const float* vnW2= (const float*)d_in[21];
    const float* vnb2= (const float*)d_in[22];
    const float* ln_g= (const float*)d_in[23];
    const float* ln_b= (const float*)d_in[24];
    const float* hW1 = (const float*)d_in[25];
    const float* hb1 = (const float*)d_in[26];
    const float* hW2 = (const float*)d_in[27];
    const float* hb2 = (const float*)d_in[28];
    float* out = (float*)d_out;

    const int N  = in_sizes[0];
    const int E  = in_sizes[1];
    const int G  = out_size;
    const int L  = in_sizes[15];
    const int H  = in_sizes[19];
    const int H2 = 2 * H;
    const int ED = in_sizes[7] / (L * H);
    const int BV = in_sizes[6] / ED;
    const int HH = in_sizes[26];
    (void)n_in;

    const int* src = eidx;
    const int* dst = eidx + E;

    // padded dims for MFMA path
    const int KP1 = ((H  + 31) / 32) * 32;            // 320
    const int KP2 = ((H2 + 31) / 32) * 32;            // 608
    const int RP1 = ((H2 + 127) / 128) * 128;         // 640
    const int RP2 = ((H  + 127) / 128) * 128;         // 384
    const int Npad = ((N + 127) / 128) * 128;

    // ---- workspace carve-up (bytes, 256B aligned), strictly within ws_size ----
    char* wsb = (char*)d_ws;
    auto alb = [](size_t v) { return (v + 255) & ~(size_t)255; };
    const size_t fN = (size_t)N * H;
    const size_t fG = (size_t)G * H;

    size_t off = 0;
    bf16*  hbf   = (bf16*) (wsb + off); off += alb(fN * 2);
    bf16*  zb    = (bf16*) (wsb + off); off += alb((size_t)Npad * KP1 * 2);
    float* hp    = (float*)(wsb + off); off += alb(fG * 4);
    float* hg    = (float*)(wsb + off); off += alb(fG * 4);
    float* vn    = (float*)(wsb + off); off += alb(fG * 4);
    float* vn_in = (float*)(wsb + off); off += alb(fG * 4);
    float* vn_t  = (float*)(wsb + off); off += alb(fG * 4);
    float* rbuf  = (float*)(wsb + off); off += alb(fG * 4);
    float* r2    = (float*)(wsb + off); off += alb((size_t)G * HH * 4);
    float* tbl   = (float*)(wsb + off); off += alb((size_t)L * BV * H * 4);
    bf16*  W1b   = (bf16*) (wsb + off); off += alb((size_t)RP1 * KP1 * 2);
    bf16*  W2b   = (bf16*) (wsb + off); off += alb((size_t)RP2 * KP2 * 2);
    // CSR arrays (ints)
    int* eoff = (int*)(wsb + off); off += alb((size_t)(N + 1) * 4);
    int* ecur = (int*)(wsb + off); off += alb((size_t)N * 4);
    int* esrc = (int*)(wsb + off); off += alb((size_t)E * 4);
    int* eea  = (int*)(wsb + off); off += alb((size_t)E * 4);
    int* goff = (int*)(wsb + off); off += alb((size_t)(G + 1) * 4);
    int* gcnt = (int*)(wsb + off); off += alb((size_t)G * 4);
    int* bsum = (int*)(wsb + off); off += alb(1024 * 4);

    // t1 chunk region gets the rest
    size_t left = (ws_size > off + 256) ? (ws_size - off - 256) : 0;
    long long chl = (long long)(left / ((size_t)KP2 * 2));
    int CH = (int)((chl > Npad) ? Npad : chl);
    CH = (CH / 128) * 128;
    if (CH < 128) {
        k_fill<<<64, 256, 0, stream>>>(out, 10000.0f + (float)(ws_size >> 20), G);
        return;
    }
    bf16* t1 = (bf16*)(wsb + off);

    auto gemm_f = [&](const float* A, const float* B, const float* bias, const float* bn,
                      float* C, int M, int Nc, int K, int flags) {
        dim3 grid((M + GBM - 1) / GBM, (Nc + GBN - 1) / GBN);
        k_gemm<<<grid, dim3(256), 0, stream>>>(A, B, bias, bn, C, M, Nc, K, flags);
    };
    auto zero = [&](void* p, size_t nfloats) { k_zero<<<1024, 256, 0, stream>>>((float*)p, nfloats); };

    const int NH = N * H;

    // ---- one-time CSR builds (dst and batch are layer-invariant) ----
    {
        int nb = (N + 1023) / 1024;
        zero(ecur, N);                                             // deg accumulator
        k_hist<<<1024, 256, 0, stream>>>(dst, ecur, E);
        k_scan1<<<nb, 256, 0, stream>>>(ecur, eoff, bsum, N);
        k_scan1<<<1, 256, 0, stream>>>(bsum, bsum, nullptr, nb);   // in-place top scan
        k_scan_add<<<512, 256, 0, stream>>>(eoff, bsum, ecur, N, E);
        k_escatter<<<1024, 256, 0, stream>>>(dst, src, edge_attr, ecur, esrc, eea, E);

        int nbg = (G + 1023) / 1024;
        zero(gcnt, G);
        k_hist<<<1024, 256, 0, stream>>>(batch, gcnt, N);
        k_scan1<<<nbg, 256, 0, stream>>>(gcnt, goff, bsum, G);
        k_scan1<<<1, 256, 0, stream>>>(bsum, bsum, nullptr, nbg);
        k_scan_add<<<64, 256, 0, stream>>>(goff, bsum, nullptr, G, N);
    }

    zero(hg, fG);
    zero(vn, fG);

    k_eptable<<<L * BV, 320, 0, stream>>>(bond_emb, We, be, tbl, BV, H, ED);
    k_encode<<<2048, 256, 0, stream>>>(x, atom_emb, hbf, H, NH);

    for (int i = 0; i < L; i++) {
        if (i > 0) {
            k_add<<<1024, 256, 0, stream>>>(hp, vn, vn_in, G * H);
            gemm_f(vn_in, vnW1, vnb1, vnbn, vn_t, G, H, H, 1);
            gemm_f(vn_t, vnW2, vnb2, nullptr, vn, G, H, H, 0);
            k_addvn<<<2048, 256, 0, stream>>>(hbf, vn, batch, H, NH);
        }
        // fused message + zmix: zb = (1+eps)h + gather-sum relu(h_src + ep)
        k_msg_csr<<<8192, KP1, 0, stream>>>(eoff, esrc, eea, hbf,
                                            tbl + (size_t)i * BV * H, epsp, i,
                                            zb, H, KP1, N);
        // weights -> bf16 padded
        k_castw<<<512, 256, 0, stream>>>(W1 + (size_t)i * H2 * H, W1b, H2, H, KP1, RP1 * KP1);
        k_castw<<<512, 256, 0, stream>>>(W2 + (size_t)i * H * H2, W2b, H, H2, KP2, RP2 * KP2);
        // node MLP, row-chunked through t1
        for (int r0 = 0; r0 < N; r0 += CH) {
            int m = (N - r0 < CH) ? (N - r0) : CH;
            int mt = (m + 127) / 128;
            dim3 g1(mt, RP1 / 128);
            k_mfma_gemm<<<g1, dim3(256), 0, stream>>>(
                zb + (size_t)r0 * KP1, W1b, b1 + (size_t)i * H2, bn1 + (size_t)i * 4 * H2,
                nullptr, t1, m, H2, KP1, KP1, KP2, KP2, 1);
            dim3 g2(mt, RP2 / 128);
            k_mfma_gemm<<<g2, dim3(256), 0, stream>>>(
                t1, W2b, b2 + (size_t)i * H, bn2 + (size_t)i * 4 * H,
                (i > 0) ? (hbf + (size_t)r0 * H) : nullptr, hbf + (size_t)r0 * H,
                m, H, KP2, KP2, H, H, 1);
        }
        // CSR pooling + graph accumulation
        k_pool_csr<<<4096, KP1, 0, stream>>>(goff, hbf, hp, H, G);
        gemm_f(hp, Wp + (size_t)i * H * H, bp + (size_t)i * H, nullptr, hg, G, H, H, 2);
    }

    // readout
    k_ln_silu<<<G, 256, 0, stream>>>(hg, ln_g, ln_b, rbuf, H);
    gemm_f(rbuf, hW1, hb1, nullptr, r2, G, HH, H, 1);
    k_head2<<<G, 64, 0, stream>>>(r2, hW2, hb2, out, HH);
}

// Round 7
// 3299.593 us; speedup vs baseline: 3.1474x; 1.0795x over previous
//
#include <hip/hip_runtime.h>
#include <hip/hip_bf16.h>
#include <math.h>

// ---------------------------------------------------------------------------
// GIN model (GINEConv x5 + virtual node + readout).
// CSR message passing + pooling (no hot-path atomics).
// Node-MLP GEMMs: bf16 MFMA 128x128 tiles, global_load_lds staging,
// XCD-chunked block swizzle for A-operand L2 reuse.
// ---------------------------------------------------------------------------

typedef __hip_bfloat16 bf16;
typedef __attribute__((ext_vector_type(8))) __bf16 bf16x8;
typedef __attribute__((ext_vector_type(4))) float f32x4;

__device__ __forceinline__ float silu_f(float v) { return v / (1.0f + __expf(-v)); }

// async global->LDS, 16B per lane; lds base must be wave-uniform.
#define GLOAD16(gp, lp) __builtin_amdgcn_global_load_lds( \
    (const __attribute__((address_space(1))) unsigned int*)(const void*)(gp), \
    (__attribute__((address_space(3))) unsigned int*)(void*)(lp), 16, 0, 0)

__global__ void k_fill(float* __restrict__ p, float v, int n) {
    int stride = gridDim.x * blockDim.x;
    for (int i = blockIdx.x * blockDim.x + threadIdx.x; i < n; i += stride) p[i] = v;
}

__global__ void k_zero(float* __restrict__ p, size_t n) {
    size_t stride = (size_t)gridDim.x * blockDim.x;
    for (size_t i = (size_t)blockIdx.x * blockDim.x + threadIdx.x; i < n; i += stride)
        p[i] = 0.0f;
}

// ---------------- CSR build helpers ----------------
__global__ void k_hist(const int* __restrict__ key, int* __restrict__ cnt, int n) {
    int stride = gridDim.x * blockDim.x;
    for (int i = blockIdx.x * blockDim.x + threadIdx.x; i < n; i += stride)
        atomicAdd(&cnt[key[i]], 1);
}

__global__ __launch_bounds__(256)
void k_scan1(const int* __restrict__ in, int* __restrict__ out,
             int* __restrict__ bsum, int n) {
    __shared__ int wsum[4];
    int base = blockIdx.x << 10;
    int t = threadIdx.x;
    int i0 = base + t * 4;
    int v0 = (i0 + 0 < n) ? in[i0 + 0] : 0;
    int v1 = (i0 + 1 < n) ? in[i0 + 1] : 0;
    int v2 = (i0 + 2 < n) ? in[i0 + 2] : 0;
    int v3 = (i0 + 3 < n) ? in[i0 + 3] : 0;
    int s = v0 + v1 + v2 + v3;
    int lane = t & 63, wid = t >> 6;
    int x = s;
    for (int d = 1; d < 64; d <<= 1) {
        int y = __shfl_up(x, d);
        if (lane >= d) x += y;
    }
    if (lane == 63) wsum[wid] = x;
    __syncthreads();
    int wadd = 0;
    for (int w = 0; w < wid; w++) wadd += wsum[w];
    x += wadd;
    int run = x - s;
    if (i0 + 0 < n) out[i0 + 0] = run; run += v0;
    if (i0 + 1 < n) out[i0 + 1] = run; run += v1;
    if (i0 + 2 < n) out[i0 + 2] = run; run += v2;
    if (i0 + 3 < n) out[i0 + 3] = run; run += v3;
    if (bsum && t == 255) bsum[blockIdx.x] = x;
}

__global__ void k_scan_add(int* __restrict__ out, const int* __restrict__ bsum,
                           int* __restrict__ cur, int n, int total) {
    int stride = gridDim.x * blockDim.x;
    for (int i = blockIdx.x * blockDim.x + threadIdx.x; i < n; i += stride) {
        int v = out[i] + bsum[i >> 10];
        out[i] = v;
        if (cur) cur[i] = v;
    }
    if (blockIdx.x == 0 && threadIdx.x == 0) out[n] = total;
}

__global__ void k_escatter(const int* __restrict__ dst, const int* __restrict__ src,
                           const int* __restrict__ ea, int* __restrict__ cur,
                           int* __restrict__ esrc, int* __restrict__ eea, int E) {
    int stride = gridDim.x * blockDim.x;
    for (int e = blockIdx.x * blockDim.x + threadIdx.x; e < E; e += stride) {
        int p = atomicAdd(&cur[dst[e]], 1);
        esrc[p] = src[e];
        eea[p]  = ea[e];
    }
}

// ---------------- model kernels ----------------
__global__ void k_eptable(const float* __restrict__ bond_emb,
                          const float* __restrict__ We,
                          const float* __restrict__ be,
                          float* __restrict__ tbl, int BV, int H, int ED) {
    int l = blockIdx.x / BV;
    int a = blockIdx.x % BV;
    int j = threadIdx.x;
    if (j >= H) return;
    const float* w = We + ((size_t)l * H + j) * ED;
    const float* bb = bond_emb + (size_t)a * ED;
    float s = be[(size_t)l * H + j];
    for (int k = 0; k < ED; k++) s += bb[k] * w[k];
    tbl[((size_t)l * BV + a) * H + j] = s;
}

__global__ void k_encode(const int* __restrict__ x, const float* __restrict__ emb,
                         bf16* __restrict__ h, int H, int total) {
    int stride = gridDim.x * blockDim.x;
    for (int i = blockIdx.x * blockDim.x + threadIdx.x; i < total; i += stride) {
        int n = i / H, j = i - n * H;
        h[i] = __float2bfloat16(emb[(size_t)x[n] * H + j]);
    }
}

// CSR message + zmix fused
__global__ __launch_bounds__(320)
void k_msg_csr(const int* __restrict__ eoff, const int* __restrict__ esrc,
               const int* __restrict__ eea, const bf16* __restrict__ h,
               const float* __restrict__ tbl, const float* __restrict__ epsp, int l,
               bf16* __restrict__ zb, int H, int KP1, int N) {
    int j = threadIdx.x;
    float epl = 1.0f + epsp[l];
    for (int n = blockIdx.x; n < N; n += gridDim.x) {
        float z = 0.0f;
        if (j < H) {
            float s = 0.0f;
            int e0 = eoff[n], e1 = eoff[n + 1];
            for (int e = e0; e < e1; e++) {
                float v = __bfloat162float(h[(size_t)esrc[e] * H + j])
                        + tbl[(size_t)eea[e] * H + j];
                if (v > 0.0f) s += v;
            }
            z = epl * __bfloat162float(h[(size_t)n * H + j]) + s;
        }
        zb[(size_t)n * KP1 + j] = __float2bfloat16(z);
    }
}

// CSR pooling (batch sorted)
__global__ __launch_bounds__(320)
void k_pool_csr(const int* __restrict__ goff, const bf16* __restrict__ h,
                float* __restrict__ hp, int H, int G) {
    int j = threadIdx.x;
    if (j >= H) return;
    for (int g = blockIdx.x; g < G; g += gridDim.x) {
        float s = 0.0f;
        int n0 = goff[g], n1 = goff[g + 1];
        for (int n = n0; n < n1; n++)
            s += __bfloat162float(h[(size_t)n * H + j]);
        hp[(size_t)g * H + j] = s;
    }
}

__global__ void k_add(const float* __restrict__ a, const float* __restrict__ b,
                      float* __restrict__ c, int n) {
    int stride = gridDim.x * blockDim.x;
    for (int i = blockIdx.x * blockDim.x + threadIdx.x; i < n; i += stride)
        c[i] = a[i] + b[i];
}

__global__ void k_addvn(bf16* __restrict__ h, const float* __restrict__ vn,
                        const int* __restrict__ batch, int H, int total) {
    int stride = gridDim.x * blockDim.x;
    for (int i = blockIdx.x * blockDim.x + threadIdx.x; i < total; i += stride) {
        int n = i / H, j = i - n * H;
        h[i] = __float2bfloat16(__bfloat162float(h[i]) + vn[(size_t)batch[n] * H + j]);
    }
}

__global__ void k_castw(const float* __restrict__ W, bf16* __restrict__ Wb,
                        int R, int K, int Kp, int total) {
    int stride = gridDim.x * blockDim.x;
    for (int i = blockIdx.x * blockDim.x + threadIdx.x; i < total; i += stride) {
        int r = i / Kp, c = i - r * Kp;
        float v = (r < R && c < K) ? W[(size_t)r * K + c] : 0.0f;
        Wb[i] = __float2bfloat16(v);
    }
}

// --- MFMA GEMM: out[m,n] = epi( sum_k A[m,k]*B[n,k] ), A,B bf16 k-contig.
// 1D grid (mt*ncol), column-fastest with bijective XCD-chunked swizzle so
// sibling column tiles of one A row-band run on the same XCD (L2 reuse).
// Staging via global_load_lds width-16, linear LDS layout.
__global__ __launch_bounds__(256)
void k_mfma_gemm(const bf16* __restrict__ A, const bf16* __restrict__ B,
                 const float* __restrict__ bias, const float* __restrict__ bn,
                 const bf16* __restrict__ resb, bf16* __restrict__ out,
                 int M, int Nc, int Kp, int ldA, int ldOut, int ldPad,
                 int dosilu, int ncol) {
    __shared__ short As[128 * 32];
    __shared__ short Bs[128 * 32];
    // XCD-chunked bijective swizzle (m204)
    const int nwg = gridDim.x;
    const int bid = blockIdx.x;
    const int q = nwg >> 3, r = nwg & 7;
    const int xcd = bid & 7, ii = bid >> 3;
    const int wgid = (xcd < r ? xcd * (q + 1) : r * (q + 1) + (xcd - r) * q) + ii;
    const int rb = wgid / ncol, cb = wgid - rb * ncol;
    const int bm = rb * 128, bn0 = cb * 128;

    const int tid = threadIdx.x;
    const int wave = tid >> 6, lane = tid & 63;
    const int wr = wave >> 1, wc = wave & 1;
    const int l15 = lane & 15, l4 = lane >> 4;
    // staging: lane's global slot (row,kc) within a 64-row half-tile
    const int sr = wave * 16 + (lane >> 2);
    const int sk = (lane & 3) << 3;

    f32x4 acc[4][4];
    #pragma unroll
    for (int mi = 0; mi < 4; mi++)
        #pragma unroll
        for (int ni = 0; ni < 4; ni++)
            acc[mi][ni] = (f32x4){0.f, 0.f, 0.f, 0.f};

    for (int k0 = 0; k0 < Kp; k0 += 32) {
        #pragma unroll
        for (int it = 0; it < 2; it++) {
            GLOAD16(A + (size_t)(bm + it * 64 + sr) * ldA + k0 + sk,
                    (short*)As + it * 2048 + wave * 512);
            GLOAD16(B + (size_t)(bn0 + it * 64 + sr) * Kp + k0 + sk,
                    (short*)Bs + it * 2048 + wave * 512);
        }
        asm volatile("s_waitcnt vmcnt(0)" ::: "memory");
        __syncthreads();
        bf16x8 a[4], b[4];
        #pragma unroll
        for (int mi = 0; mi < 4; mi++)
            a[mi] = *(const bf16x8*)&As[(wr * 64 + mi * 16 + l15) * 32 + l4 * 8];
        #pragma unroll
        for (int ni = 0; ni < 4; ni++)
            b[ni] = *(const bf16x8*)&Bs[(wc * 64 + ni * 16 + l15) * 32 + l4 * 8];
        #pragma unroll
        for (int mi = 0; mi < 4; mi++)
            #pragma unroll
            for (int ni = 0; ni < 4; ni++)
                acc[mi][ni] = __builtin_amdgcn_mfma_f32_16x16x32_bf16(
                    a[mi], b[ni], acc[mi][ni], 0, 0, 0);
        __syncthreads();
    }

    #pragma unroll
    for (int ni = 0; ni < 4; ni++) {
        int col = bn0 + wc * 64 + ni * 16 + l15;
        if (col >= ldPad) continue;
        bool pad = (col >= Nc);
        float bi = (!pad && bias) ? bias[col] : 0.f;
        float sc = 1.f, mm = 0.f, bb = 0.f;
        if (!pad && bn) {
            sc = bn[col] * rsqrtf(bn[3 * Nc + col] + 1e-5f);
            mm = bn[2 * Nc + col];
            bb = bn[Nc + col];
        }
        #pragma unroll
        for (int mi = 0; mi < 4; mi++) {
            #pragma unroll
            for (int rr = 0; rr < 4; rr++) {
                int row = bm + wr * 64 + mi * 16 + l4 * 4 + rr;
                if (row >= M) continue;
                size_t idx = (size_t)row * ldOut + col;
                if (pad) { out[idx] = __float2bfloat16(0.f); continue; }
                float v = acc[mi][ni][rr] + bi;
                if (bn) v = (v - mm) * sc + bb;
                if (dosilu) v = silu_f(v);
                if (resb) v += __bfloat162float(resb[idx]);
                out[idx] = __float2bfloat16(v);
            }
        }
    }
}

// --- small fp32 GEMM (vn / pool / readout)
#define GBM 64
#define GBN 64
#define GBK 16
__global__ __launch_bounds__(256)
void k_gemm(const float* __restrict__ A, const float* __restrict__ B,
            const float* __restrict__ bias, const float* __restrict__ bn,
            float* __restrict__ C, int M, int Nc, int K, int flags) { // 1=silu 2=accum
    __shared__ float As[GBK][GBM + 4];
    __shared__ float Bs[GBK][GBN + 4];
    const int bm = blockIdx.x * GBM;
    const int bnc = blockIdx.y * GBN;
    const int tid = threadIdx.x;
    const int tx = tid & 15, ty = tid >> 4;
    const int ar = tid >> 2;
    const int ak = (tid & 3) << 2;

    float acc[4][4] = {{0.f}};

    for (int k0 = 0; k0 < K; k0 += GBK) {
        {
            int gr = bm + ar, gk = k0 + ak;
            float4 v = make_float4(0.f, 0.f, 0.f, 0.f);
            if (gr < M && gk < K) {
                const float* p = A + (size_t)gr * K;
                if (gk + 3 < K) v = *(const float4*)(p + gk);
                else {
                    v.x = p[gk];
                    if (gk + 1 < K) v.y = p[gk + 1];
                    if (gk + 2 < K) v.z = p[gk + 2];
                }
            }
            As[ak][ar] = v.x; As[ak + 1][ar] = v.y; As[ak + 2][ar] = v.z; As[ak + 3][ar] = v.w;
        }
        {
            int gr = bnc + ar, gk = k0 + ak;
            float4 v = make_float4(0.f, 0.f, 0.f, 0.f);
            if (gr < Nc && gk < K) {
                const float* p = B + (size_t)gr * K;
                if (gk + 3 < K) v = *(const float4*)(p + gk);
                else {
                    v.x = p[gk];
                    if (gk + 1 < K) v.y = p[gk + 1];
                    if (gk + 2 < K) v.z = p[gk + 2];
                }
            }
            Bs[ak][ar] = v.x; Bs[ak + 1][ar] = v.y; Bs[ak + 2][ar] = v.z; Bs[ak + 3][ar] = v.w;
        }
        __syncthreads();
        #pragma unroll
        for (int kk = 0; kk < GBK; kk++) {
            float4 a = *(const float4*)&As[kk][ty * 4];
            float4 b = *(const float4*)&Bs[kk][tx * 4];
            acc[0][0] += a.x * b.x; acc[0][1] += a.x * b.y; acc[0][2] += a.x * b.z; acc[0][3] += a.x * b.w;
            acc[1][0] += a.y * b.x; acc[1][1] += a.y * b.y; acc[1][2] += a.y * b.z; acc[1][3] += a.y * b.w;
            acc[2][0] += a.z * b.x; acc[2][1] += a.z * b.y; acc[2][2] += a.z * b.z; acc[2][3] += a.z * b.w;
            acc[3][0] += a.w * b.x; acc[3][1] += a.w * b.y; acc[3][2] += a.w * b.z; acc[3][3] += a.w * b.w;
        }
        __syncthreads();
    }

    #pragma unroll
    for (int i = 0; i < 4; i++) {
        int row = bm + ty * 4 + i;
        if (row >= M) continue;
        #pragma unroll
        for (int j = 0; j < 4; j++) {
            int col = bnc + tx * 4 + j;
            if (col >= Nc) continue;
            float v = acc[i][j];
            if (bias) v += bias[col];
            if (bn) {
                float g = bn[col], bb = bn[Nc + col], mm = bn[2 * Nc + col], vv = bn[3 * Nc + col];
                v = (v - mm) * (g * rsqrtf(vv + 1e-5f)) + bb;
            }
            if (flags & 1) v = silu_f(v);
            size_t idx = (size_t)row * Nc + col;
            if (flags & 2) C[idx] += v;
            else           C[idx] = v;
        }
    }
}

// per-row LayerNorm + SiLU
__global__ __launch_bounds__(256)
void k_ln_silu(const float* __restrict__ hg, const float* __restrict__ g,
               const float* __restrict__ b, float* __restrict__ r, int H) {
    int gi = blockIdx.x;
    const float* row = hg + (size_t)gi * H;
    float s = 0.f, s2 = 0.f;
    for (int j = threadIdx.x; j < H; j += blockDim.x) {
        float v = row[j];
        s += v; s2 += v * v;
    }
    for (int off = 32; off; off >>= 1) {
        s += __shfl_down(s, off);
        s2 += __shfl_down(s2, off);
    }
    __shared__ float rs[4], rs2[4];
    int wid = threadIdx.x >> 6, lane = threadIdx.x & 63;
    if (lane == 0) { rs[wid] = s; rs2[wid] = s2; }
    __syncthreads();
    if (threadIdx.x == 0) {
        float S = 0.f, S2 = 0.f;
        for (int w = 0; w < 4; w++) { S += rs[w]; S2 += rs2[w]; }
        rs[0] = S; rs2[0] = S2;
    }
    __syncthreads();
    float mu = rs[0] / H;
    float var = rs2[0] / H - mu * mu;
    float inv = rsqrtf(var + 1e-5f);
    for (int j = threadIdx.x; j < H; j += blockDim.x) {
        float v = (row[j] - mu) * inv * g[j] + b[j];
        r[(size_t)gi * H + j] = silu_f(v);
    }
}

__global__ void k_head2(const float* __restrict__ r2, const float* __restrict__ w,
                        const float* __restrict__ b, float* __restrict__ out, int Kh) {
    int gi = blockIdx.x;
    int t = threadIdx.x;
    float s = 0.f;
    for (int k = t; k < Kh; k += 64) s += r2[(size_t)gi * Kh + k] * w[k];
    for (int off = 32; off; off >>= 1) s += __shfl_down(s, off);
    if (t == 0) out[gi] = s + b[0];
}

extern "C" void kernel_launch(void* const* d_in, const int* in_sizes, int n_in,
                              void* d_out, int out_size, void* d_ws, size_t ws_size,
                              hipStream_t stream) {
    const int*   x         = (const int*)d_in[0];
    const int*   edge_attr = (const int*)d_in[1];
    const int*   eidx      = (const int*)d_in[2];
    const int*   batch     = (const int*)d_in[3];
    const float* atom_emb  = (const float*)d_in[5];
    const float* bond_emb  = (const float*)d_in[6];
    const float* We  = (const float*)d_in[7];
    const float* be  = (const float*)d_in[8];
    const float* W1  = (const float*)d_in[9];
    const float* b1  = (const float*)d_in[10];
    const float* bn1 = (const float*)d_in[11];
    const float* W2  = (const float*)d_in[12];
    const float* b2  = (const float*)d_in[13];
    const float* bn2 = (const float*)d_in[14];
    const float* epsp= (const float*)d_in[15];
    const float* Wp  = (const float*)d_in[16];
    const float* bp  = (const float*)d_in[17];
    const float* vnW1= (const float*)d_in[18];
    const float* vnb1= (const float*)d_in[19];
    const float* vnbn= (const float*)d_in[20];
    const float* vnW2= (const float*)d_in[21];
    const float* vnb2= (const float*)d_in[22];
    const float* ln_g= (const float*)d_in[23];
    const float* ln_b= (const float*)d_in[24];
    const float* hW1 = (const float*)d_in[25];
    const float* hb1 = (const float*)d_in[26];
    const float* hW2 = (const float*)d_in[27];
    const float* hb2 = (const float*)d_in[28];
    float* out = (float*)d_out;

    const int N  = in_sizes[0];
    const int E  = in_sizes[1];
    const int G  = out_size;
    const int L  = in_sizes[15];
    const int H  = in_sizes[19];
    const int H2 = 2 * H;
    const int ED = in_sizes[7] / (L * H);
    const int BV = in_sizes[6] / ED;
    const int HH = in_sizes[26];
    (void)n_in;

    const int* src = eidx;
    const int* dst = eidx + E;

    // padded dims for MFMA path
    const int KP1 = ((H  + 31) / 32) * 32;            // 320
    const int KP2 = ((H2 + 31) / 32) * 32;            // 608
    const int RP1 = ((H2 + 127) / 128) * 128;         // 640
    const int RP2 = ((H  + 127) / 128) * 128;         // 384
    const int Npad = ((N + 127) / 128) * 128;

    // ---- workspace carve-up (bytes, 256B aligned), strictly within ws_size ----
    char* wsb = (char*)d_ws;
    auto alb = [](size_t v) { return (v + 255) & ~(size_t)255; };
    const size_t fN = (size_t)N * H;
    const size_t fG = (size_t)G * H;

    size_t off = 0;
    bf16*  hbf   = (bf16*) (wsb + off); off += alb(fN * 2);
    bf16*  zb    = (bf16*) (wsb + off); off += alb((size_t)Npad * KP1 * 2);
    float* hp    = (float*)(wsb + off); off += alb(fG * 4);
    float* hg    = (float*)(wsb + off); off += alb(fG * 4);
    float* vn    = (float*)(wsb + off); off += alb(fG * 4);
    float* vn_in = (float*)(wsb + off); off += alb(fG * 4);
    float* vn_t  = (float*)(wsb + off); off += alb(fG * 4);
    float* rbuf  = (float*)(wsb + off); off += alb(fG * 4);
    float* r2    = (float*)(wsb + off); off += alb((size_t)G * HH * 4);
    float* tbl   = (float*)(wsb + off); off += alb((size_t)L * BV * H * 4);
    bf16*  W1b   = (bf16*) (wsb + off); off += alb((size_t)RP1 * KP1 * 2);
    bf16*  W2b   = (bf16*) (wsb + off); off += alb((size_t)RP2 * KP2 * 2);
    // CSR arrays (ints)
    int* eoff = (int*)(wsb + off); off += alb((size_t)(N + 1) * 4);
    int* ecur = (int*)(wsb + off); off += alb((size_t)N * 4);
    int* esrc = (int*)(wsb + off); off += alb((size_t)E * 4);
    int* eea  = (int*)(wsb + off); off += alb((size_t)E * 4);
    int* goff = (int*)(wsb + off); off += alb((size_t)(G + 1) * 4);
    int* gcnt = (int*)(wsb + off); off += alb((size_t)G * 4);
    int* bsum = (int*)(wsb + off); off += alb(1024 * 4);

    // t1 chunk region gets the rest
    size_t left = (ws_size > off + 256) ? (ws_size - off - 256) : 0;
    long long chl = (long long)(left / ((size_t)KP2 * 2));
    int CH = (int)((chl > Npad) ? Npad : chl);
    CH = (CH / 128) * 128;
    if (CH < 128) {
        k_fill<<<64, 256, 0, stream>>>(out, 10000.0f + (float)(ws_size >> 20), G);
        return;
    }
    bf16* t1 = (bf16*)(wsb + off);

    auto gemm_f = [&](const float* A, const float* B, const float* bias, const float* bn,
                      float* C, int M, int Nc, int K, int flags) {
        dim3 grid((M + GBM - 1) / GBM, (Nc + GBN - 1) / GBN);
        k_gemm<<<grid, dim3(256), 0, stream>>>(A, B, bias, bn, C, M, Nc, K, flags);
    };
    auto mfma = [&](const bf16* A, const bf16* B, const float* bias, const float* bn,
                    const bf16* resb, bf16* outp, int M, int Nc, int Kp, int ldA,
                    int ldOut, int ldPad, int dosilu, int ncolT) {
        int mt = (M + 127) / 128;
        k_mfma_gemm<<<dim3(mt * ncolT), dim3(256), 0, stream>>>(
            A, B, bias, bn, resb, outp, M, Nc, Kp, ldA, ldOut, ldPad, dosilu, ncolT);
    };
    auto zero = [&](void* p, size_t nfloats) { k_zero<<<1024, 256, 0, stream>>>((float*)p, nfloats); };

    const int NH = N * H;

    // ---- one-time CSR builds (dst and batch are layer-invariant) ----
    {
        int nb = (N + 1023) / 1024;
        zero(ecur, N);
        k_hist<<<1024, 256, 0, stream>>>(dst, ecur, E);
        k_scan1<<<nb, 256, 0, stream>>>(ecur, eoff, bsum, N);
        k_scan1<<<1, 256, 0, stream>>>(bsum, bsum, nullptr, nb);
        k_scan_add<<<512, 256, 0, stream>>>(eoff, bsum, ecur, N, E);
        k_escatter<<<1024, 256, 0, stream>>>(dst, src, edge_attr, ecur, esrc, eea, E);

        int nbg = (G + 1023) / 1024;
        zero(gcnt, G);
        k_hist<<<1024, 256, 0, stream>>>(batch, gcnt, N);
        k_scan1<<<nbg, 256, 0, stream>>>(gcnt, goff, bsum, G);
        k_scan1<<<1, 256, 0, stream>>>(bsum, bsum, nullptr, nbg);
        k_scan_add<<<64, 256, 0, stream>>>(goff, bsum, nullptr, G, N);
    }

    zero(hg, fG);
    zero(vn, fG);

    k_eptable<<<L * BV, 320, 0, stream>>>(bond_emb, We, be, tbl, BV, H, ED);
    k_encode<<<2048, 256, 0, stream>>>(x, atom_emb, hbf, H, NH);

    for (int i = 0; i < L; i++) {
        if (i > 0) {
            k_add<<<1024, 256, 0, stream>>>(hp, vn, vn_in, G * H);
            gemm_f(vn_in, vnW1, vnb1, vnbn, vn_t, G, H, H, 1);
            gemm_f(vn_t, vnW2, vnb2, nullptr, vn, G, H, H, 0);
            k_addvn<<<2048, 256, 0, stream>>>(hbf, vn, batch, H, NH);
        }
        // fused message + zmix: zb = (1+eps)h + gather-sum relu(h_src + ep)
        k_msg_csr<<<8192, KP1, 0, stream>>>(eoff, esrc, eea, hbf,
                                            tbl + (size_t)i * BV * H, epsp, i,
                                            zb, H, KP1, N);
        // weights -> bf16 padded
        k_castw<<<512, 256, 0, stream>>>(W1 + (size_t)i * H2 * H, W1b, H2, H, KP1, RP1 * KP1);
        k_castw<<<512, 256, 0, stream>>>(W2 + (size_t)i * H * H2, W2b, H, H2, KP2, RP2 * KP2);
        // node MLP, row-chunked through t1
        for (int r0 = 0; r0 < N; r0 += CH) {
            int m = (N - r0 < CH) ? (N - r0) : CH;
            mfma(zb + (size_t)r0 * KP1, W1b, b1 + (size_t)i * H2, bn1 + (size_t)i * 4 * H2,
                 nullptr, t1, m, H2, KP1, KP1, KP2, KP2, 1, RP1 / 128);
            mfma(t1, W2b, b2 + (size_t)i * H, bn2 + (size_t)i * 4 * H,
                 (i > 0) ? (hbf + (size_t)r0 * H) : nullptr, hbf + (size_t)r0 * H,
                 m, H, KP2, KP2, H, H, 1, RP2 / 128);
        }
        // CSR pooling + graph accumulation
        k_pool_csr<<<4096, KP1, 0, stream>>>(goff, hbf, hp, H, G);
        gemm_f(hp, Wp + (size_t)i * H * H, bp + (size_t)i * H, nullptr, hg, G, H, H, 2);
    }

    // readout
    k_ln_silu<<<G, 256, 0, stream>>>(hg, ln_g, ln_b, rbuf, H);
    gemm_f(rbuf, hW1, hb1, nullptr, r2, G, HH, H, 1);
    k_head2<<<G, 64, 0, stream>>>(r2, hW2, hb2, out, HH);
}

// Round 8
// 3257.388 us; speedup vs baseline: 3.1882x; 1.0130x over previous
//
#include <hip/hip_runtime.h>
#include <hip/hip_bf16.h>
#include <math.h>

// ---------------------------------------------------------------------------
// GIN model (GINEConv x5 + virtual node + readout).
// CSR message passing + pooling (no hot-path atomics).
// Node-MLP GEMMs: bf16 MFMA 128x128, global_load_lds + double-buffer prefetch
// (T3-minimum schedule), XOR slot swizzle (bank-conflict-free ds_read_b128),
// XCD-chunked block swizzle for A-operand L2 reuse.
// ---------------------------------------------------------------------------

typedef __hip_bfloat16 bf16;
typedef __attribute__((ext_vector_type(8))) __bf16 bf16x8;
typedef __attribute__((ext_vector_type(4))) float f32x4;

__device__ __forceinline__ float silu_f(float v) { return v / (1.0f + __expf(-v)); }

// async global->LDS, 16B per lane; lds base must be wave-uniform.
#define GLOAD16(gp, lp) __builtin_amdgcn_global_load_lds( \
    (const __attribute__((address_space(1))) unsigned int*)(const void*)(gp), \
    (__attribute__((address_space(3))) unsigned int*)(void*)(lp), 16, 0, 0)

__global__ void k_fill(float* __restrict__ p, float v, int n) {
    int stride = gridDim.x * blockDim.x;
    for (int i = blockIdx.x * blockDim.x + threadIdx.x; i < n; i += stride) p[i] = v;
}

__global__ void k_zero(float* __restrict__ p, size_t n) {
    size_t stride = (size_t)gridDim.x * blockDim.x;
    for (size_t i = (size_t)blockIdx.x * blockDim.x + threadIdx.x; i < n; i += stride)
        p[i] = 0.0f;
}

// ---------------- CSR build helpers ----------------
__global__ void k_hist(const int* __restrict__ key, int* __restrict__ cnt, int n) {
    int stride = gridDim.x * blockDim.x;
    for (int i = blockIdx.x * blockDim.x + threadIdx.x; i < n; i += stride)
        atomicAdd(&cnt[key[i]], 1);
}

__global__ __launch_bounds__(256)
void k_scan1(const int* __restrict__ in, int* __restrict__ out,
             int* __restrict__ bsum, int n) {
    __shared__ int wsum[4];
    int base = blockIdx.x << 10;
    int t = threadIdx.x;
    int i0 = base + t * 4;
    int v0 = (i0 + 0 < n) ? in[i0 + 0] : 0;
    int v1 = (i0 + 1 < n) ? in[i0 + 1] : 0;
    int v2 = (i0 + 2 < n) ? in[i0 + 2] : 0;
    int v3 = (i0 + 3 < n) ? in[i0 + 3] : 0;
    int s = v0 + v1 + v2 + v3;
    int lane = t & 63, wid = t >> 6;
    int x = s;
    for (int d = 1; d < 64; d <<= 1) {
        int y = __shfl_up(x, d);
        if (lane >= d) x += y;
    }
    if (lane == 63) wsum[wid] = x;
    __syncthreads();
    int wadd = 0;
    for (int w = 0; w < wid; w++) wadd += wsum[w];
    x += wadd;
    int run = x - s;
    if (i0 + 0 < n) out[i0 + 0] = run; run += v0;
    if (i0 + 1 < n) out[i0 + 1] = run; run += v1;
    if (i0 + 2 < n) out[i0 + 2] = run; run += v2;
    if (i0 + 3 < n) out[i0 + 3] = run; run += v3;
    if (bsum && t == 255) bsum[blockIdx.x] = x;
}

__global__ void k_scan_add(int* __restrict__ out, const int* __restrict__ bsum,
                           int* __restrict__ cur, int n, int total) {
    int stride = gridDim.x * blockDim.x;
    for (int i = blockIdx.x * blockDim.x + threadIdx.x; i < n; i += stride) {
        int v = out[i] + bsum[i >> 10];
        out[i] = v;
        if (cur) cur[i] = v;
    }
    if (blockIdx.x == 0 && threadIdx.x == 0) out[n] = total;
}

__global__ void k_escatter(const int* __restrict__ dst, const int* __restrict__ src,
                           const int* __restrict__ ea, int* __restrict__ cur,
                           int* __restrict__ esrc, int* __restrict__ eea, int E) {
    int stride = gridDim.x * blockDim.x;
    for (int e = blockIdx.x * blockDim.x + threadIdx.x; e < E; e += stride) {
        int p = atomicAdd(&cur[dst[e]], 1);
        esrc[p] = src[e];
        eea[p]  = ea[e];
    }
}

// ---------------- model kernels ----------------
__global__ void k_eptable(const float* __restrict__ bond_emb,
                          const float* __restrict__ We,
                          const float* __restrict__ be,
                          float* __restrict__ tbl, int BV, int H, int ED) {
    int l = blockIdx.x / BV;
    int a = blockIdx.x % BV;
    int j = threadIdx.x;
    if (j >= H) return;
    const float* w = We + ((size_t)l * H + j) * ED;
    const float* bb = bond_emb + (size_t)a * ED;
    float s = be[(size_t)l * H + j];
    for (int k = 0; k < ED; k++) s += bb[k] * w[k];
    tbl[((size_t)l * BV + a) * H + j] = s;
}

__global__ void k_encode(const int* __restrict__ x, const float* __restrict__ emb,
                         bf16* __restrict__ h, int H, int total) {
    int stride = gridDim.x * blockDim.x;
    for (int i = blockIdx.x * blockDim.x + threadIdx.x; i < total; i += stride) {
        int n = i / H, j = i - n * H;
        h[i] = __float2bfloat16(emb[(size_t)x[n] * H + j]);
    }
}

// CSR message + zmix fused
__global__ __launch_bounds__(320)
void k_msg_csr(const int* __restrict__ eoff, const int* __restrict__ esrc,
               const int* __restrict__ eea, const bf16* __restrict__ h,
               const float* __restrict__ tbl, const float* __restrict__ epsp, int l,
               bf16* __restrict__ zb, int H, int KP1, int N) {
    int j = threadIdx.x;
    float epl = 1.0f + epsp[l];
    for (int n = blockIdx.x; n < N; n += gridDim.x) {
        float z = 0.0f;
        if (j < H) {
            float s = 0.0f;
            int e0 = eoff[n], e1 = eoff[n + 1];
            for (int e = e0; e < e1; e++) {
                float v = __bfloat162float(h[(size_t)esrc[e] * H + j])
                        + tbl[(size_t)eea[e] * H + j];
                if (v > 0.0f) s += v;
            }
            z = epl * __bfloat162float(h[(size_t)n * H + j]) + s;
        }
        zb[(size_t)n * KP1 + j] = __float2bfloat16(z);
    }
}

// CSR pooling (batch sorted)
__global__ __launch_bounds__(320)
void k_pool_csr(const int* __restrict__ goff, const bf16* __restrict__ h,
                float* __restrict__ hp, int H, int G) {
    int j = threadIdx.x;
    if (j >= H) return;
    for (int g = blockIdx.x; g < G; g += gridDim.x) {
        float s = 0.0f;
        int n0 = goff[g], n1 = goff[g + 1];
        for (int n = n0; n < n1; n++)
            s += __bfloat162float(h[(size_t)n * H + j]);
        hp[(size_t)g * H + j] = s;
    }
}

__global__ void k_add(const float* __restrict__ a, const float* __restrict__ b,
                      float* __restrict__ c, int n) {
    int stride = gridDim.x * blockDim.x;
    for (int i = blockIdx.x * blockDim.x + threadIdx.x; i < n; i += stride)
        c[i] = a[i] + b[i];
}

__global__ void k_addvn(bf16* __restrict__ h, const float* __restrict__ vn,
                        const int* __restrict__ batch, int H, int total) {
    int stride = gridDim.x * blockDim.x;
    for (int i = blockIdx.x * blockDim.x + threadIdx.x; i < total; i += stride) {
        int n = i / H, j = i - n * H;
        h[i] = __float2bfloat16(__bfloat162float(h[i]) + vn[(size_t)batch[n] * H + j]);
    }
}

__global__ void k_castw(const float* __restrict__ W, bf16* __restrict__ Wb,
                        int R, int K, int Kp, int total) {
    int stride = gridDim.x * blockDim.x;
    for (int i = blockIdx.x * blockDim.x + threadIdx.x; i < total; i += stride) {
        int r = i / Kp, c = i - r * Kp;
        float v = (r < R && c < K) ? W[(size_t)r * K + c] : 0.0f;
        Wb[i] = __float2bfloat16(v);
    }
}

// --- MFMA GEMM: out[m,n] = epi( sum_k A[m,k]*B[n,k] ), A,B bf16 k-contig.
// Double-buffered LDS with global_load_lds prefetch (stage t+1 before compute t,
// one __syncthreads per K-step whose vmcnt(0) drain is the prefetch wait).
// XOR slot swizzle (slot ^= (row>>1)&3) applied to BOTH the staged global
// source and the ds_read address -> conflict-free b128 fragment reads.
// 1D grid, column-fastest + bijective XCD-chunked swizzle for A L2 reuse.
__global__ __launch_bounds__(256)
void k_mfma_gemm(const bf16* __restrict__ A, const bf16* __restrict__ B,
                 const float* __restrict__ bias, const float* __restrict__ bn,
                 const bf16* __restrict__ resb, bf16* __restrict__ out,
                 int M, int Nc, int Kp, int ldA, int ldOut, int ldPad,
                 int dosilu, int ncol) {
    __shared__ short As[2 * 128 * 32];
    __shared__ short Bs[2 * 128 * 32];
    // XCD-chunked bijective swizzle (m204)
    const int nwg = gridDim.x;
    const int bid = blockIdx.x;
    const int q = nwg >> 3, r = nwg & 7;
    const int xcd = bid & 7, ii = bid >> 3;
    const int wgid = (xcd < r ? xcd * (q + 1) : r * (q + 1) + (xcd - r) * q) + ii;
    const int rb = wgid / ncol, cb = wgid - rb * ncol;
    const int bm = rb * 128, bn0 = cb * 128;

    const int tid = threadIdx.x;
    const int wave = tid >> 6, lane = tid & 63;
    const int wr = wave >> 1, wc = wave & 1;
    const int l15 = lane & 15, l4 = lane >> 4;
    // staging geometry: lane covers (row within 16, 16B slot)
    const int srw = (lane >> 2);             // row within wave's 16-row band
    const int sl  = lane & 3;                // linear 16B slot in LDS

    f32x4 acc[4][4];
    #pragma unroll
    for (int mi = 0; mi < 4; mi++)
        #pragma unroll
        for (int ni = 0; ni < 4; ni++)
            acc[mi][ni] = (f32x4){0.f, 0.f, 0.f, 0.f};

    // stage tile k0 into buffer `buf` (A and B), source cols pre-swizzled
    auto STAGE = [&](int buf, int k0) {
        short* Ab = As + buf * 4096;
        short* Bb = Bs + buf * 4096;
        #pragma unroll
        for (int it = 0; it < 2; it++) {
            int row = it * 64 + wave * 16 + srw;
            int sg = (sl ^ ((row >> 1) & 3)) << 3;   // swizzled source col (shorts)
            GLOAD16(A + (size_t)(bm + row) * ldA + k0 + sg,
                    Ab + it * 2048 + wave * 512);
            GLOAD16(B + (size_t)(bn0 + row) * Kp + k0 + sg,
                    Bb + it * 2048 + wave * 512);
        }
    };

    STAGE(0, 0);
    __syncthreads();

    int cur = 0;
    for (int k0 = 0; k0 < Kp; k0 += 32) {
        if (k0 + 32 < Kp) STAGE(cur ^ 1, k0 + 32);   // prefetch next tile
        const short* Ab = As + cur * 4096;
        const short* Bb = Bs + cur * 4096;
        bf16x8 a[4], b[4];
        #pragma unroll
        for (int mi = 0; mi < 4; mi++) {
            int row = wr * 64 + mi * 16 + l15;
            a[mi] = *(const bf16x8*)&Ab[row * 32 + ((l4 ^ ((row >> 1) & 3)) << 3)];
        }
        #pragma unroll
        for (int ni = 0; ni < 4; ni++) {
            int row = wc * 64 + ni * 16 + l15;
            b[ni] = *(const bf16x8*)&Bb[row * 32 + ((l4 ^ ((row >> 1) & 3)) << 3)];
        }
        #pragma unroll
        for (int mi = 0; mi < 4; mi++)
            #pragma unroll
            for (int ni = 0; ni < 4; ni++)
                acc[mi][ni] = __builtin_amdgcn_mfma_f32_16x16x32_bf16(
                    a[mi], b[ni], acc[mi][ni], 0, 0, 0);
        __syncthreads();   // drains vmcnt(0): prefetch landed; all reads of cur done
        cur ^= 1;
    }

    #pragma unroll
    for (int ni = 0; ni < 4; ni++) {
        int col = bn0 + wc * 64 + ni * 16 + l15;
        if (col >= ldPad) continue;
        bool pad = (col >= Nc);
        float bi = (!pad && bias) ? bias[col] : 0.f;
        float sc = 1.f, mm = 0.f, bb = 0.f;
        if (!pad && bn) {
            sc = bn[col] * rsqrtf(bn[3 * Nc + col] + 1e-5f);
            mm = bn[2 * Nc + col];
            bb = bn[Nc + col];
        }
        #pragma unroll
        for (int mi = 0; mi < 4; mi++) {
            #pragma unroll
            for (int rr = 0; rr < 4; rr++) {
                int row = bm + wr * 64 + mi * 16 + l4 * 4 + rr;
                if (row >= M) continue;
                size_t idx = (size_t)row * ldOut + col;
                if (pad) { out[idx] = __float2bfloat16(0.f); continue; }
                float v = acc[mi][ni][rr] + bi;
                if (bn) v = (v - mm) * sc + bb;
                if (dosilu) v = silu_f(v);
                if (resb) v += __bfloat162float(resb[idx]);
                out[idx] = __float2bfloat16(v);
            }
        }
    }
}

// --- small fp32 GEMM (vn / pool / readout)
#define GBM 64
#define GBN 64
#define GBK 16
__global__ __launch_bounds__(256)
void k_gemm(const float* __restrict__ A, const float* __restrict__ B,
            const float* __restrict__ bias, const float* __restrict__ bn,
            float* __restrict__ C, int M, int Nc, int K, int flags) { // 1=silu 2=accum
    __shared__ float As[GBK][GBM + 4];
    __shared__ float Bs[GBK][GBN + 4];
    const int bm = blockIdx.x * GBM;
    const int bnc = blockIdx.y * GBN;
    const int tid = threadIdx.x;
    const int tx = tid & 15, ty = tid >> 4;
    const int ar = tid >> 2;
    const int ak = (tid & 3) << 2;

    float acc[4][4] = {{0.f}};

    for (int k0 = 0; k0 < K; k0 += GBK) {
        {
            int gr = bm + ar, gk = k0 + ak;
            float4 v = make_float4(0.f, 0.f, 0.f, 0.f);
            if (gr < M && gk < K) {
                const float* p = A + (size_t)gr * K;
                if (gk + 3 < K) v = *(const float4*)(p + gk);
                else {
                    v.x = p[gk];
                    if (gk + 1 < K) v.y = p[gk + 1];
                    if (gk + 2 < K) v.z = p[gk + 2];
                }
            }
            As[ak][ar] = v.x; As[ak + 1][ar] = v.y; As[ak + 2][ar] = v.z; As[ak + 3][ar] = v.w;
        }
        {
            int gr = bnc + ar, gk = k0 + ak;
            float4 v = make_float4(0.f, 0.f, 0.f, 0.f);
            if (gr < Nc && gk < K) {
                const float* p = B + (size_t)gr * K;
                if (gk + 3 < K) v = *(const float4*)(p + gk);
                else {
                    v.x = p[gk];
                    if (gk + 1 < K) v.y = p[gk + 1];
                    if (gk + 2 < K) v.z = p[gk + 2];
                }
            }
            Bs[ak][ar] = v.x; Bs[ak + 1][ar] = v.y; Bs[ak + 2][ar] = v.z; Bs[ak + 3][ar] = v.w;
        }
        __syncthreads();
        #pragma unroll
        for (int kk = 0; kk < GBK; kk++) {
            float4 a = *(const float4*)&As[kk][ty * 4];
            float4 b = *(const float4*)&Bs[kk][tx * 4];
            acc[0][0] += a.x * b.x; acc[0][1] += a.x * b.y; acc[0][2] += a.x * b.z; acc[0][3] += a.x * b.w;
            acc[1][0] += a.y * b.x; acc[1][1] += a.y * b.y; acc[1][2] += a.y * b.z; acc[1][3] += a.y * b.w;
            acc[2][0] += a.z * b.x; acc[2][1] += a.z * b.y; acc[2][2] += a.z * b.z; acc[2][3] += a.z * b.w;
            acc[3][0] += a.w * b.x; acc[3][1] += a.w * b.y; acc[3][2] += a.w * b.z; acc[3][3] += a.w * b.w;
        }
        __syncthreads();
    }

    #pragma unroll
    for (int i = 0; i < 4; i++) {
        int row = bm + ty * 4 + i;
        if (row >= M) continue;
        #pragma unroll
        for (int j = 0; j < 4; j++) {
            int col = bnc + tx * 4 + j;
            if (col >= Nc) continue;
            float v = acc[i][j];
            if (bias) v += bias[col];
            if (bn) {
                float g = bn[col], bb = bn[Nc + col], mm = bn[2 * Nc + col], vv = bn[3 * Nc + col];
                v = (v - mm) * (g * rsqrtf(vv + 1e-5f)) + bb;
            }
            if (flags & 1) v = silu_f(v);
            size_t idx = (size_t)row * Nc + col;
            if (flags & 2) C[idx] += v;
            else           C[idx] = v;
        }
    }
}

// per-row LayerNorm + SiLU
__global__ __launch_bounds__(256)
void k_ln_silu(const float* __restrict__ hg, const float* __restrict__ g,
               const float* __restrict__ b, float* __restrict__ r, int H) {
    int gi = blockIdx.x;
    const float* row = hg + (size_t)gi * H;
    float s = 0.f, s2 = 0.f;
    for (int j = threadIdx.x; j < H; j += blockDim.x) {
        float v = row[j];
        s += v; s2 += v * v;
    }
    for (int off = 32; off; off >>= 1) {
        s += __shfl_down(s, off);
        s2 += __shfl_down(s2, off);
    }
    __shared__ float rs[4], rs2[4];
    int wid = threadIdx.x >> 6, lane = threadIdx.x & 63;
    if (lane == 0) { rs[wid] = s; rs2[wid] = s2; }
    __syncthreads();
    if (threadIdx.x == 0) {
        float S = 0.f, S2 = 0.f;
        for (int w = 0; w < 4; w++) { S += rs[w]; S2 += rs2[w]; }
        rs[0] = S; rs2[0] = S2;
    }
    __syncthreads();
    float mu = rs[0] / H;
    float var = rs2[0] / H - mu * mu;
    float inv = rsqrtf(var + 1e-5f);
    for (int j = threadIdx.x; j < H; j += blockDim.x) {
        float v = (row[j] - mu) * inv * g[j] + b[j];
        r[(size_t)gi * H + j] = silu_f(v);
    }
}

__global__ void k_head2(const float* __restrict__ r2, const float* __restrict__ w,
                        const float* __restrict__ b, float* __restrict__ out, int Kh) {
    int gi = blockIdx.x;
    int t = threadIdx.x;
    float s = 0.f;
    for (int k = t; k < Kh; k += 64) s += r2[(size_t)gi * Kh + k] * w[k];
    for (int off = 32; off; off >>= 1) s += __shfl_down(s, off);
    if (t == 0) out[gi] = s + b[0];
}

extern "C" void kernel_launch(void* const* d_in, const int* in_sizes, int n_in,
                              void* d_out, int out_size, void* d_ws, size_t ws_size,
                              hipStream_t stream) {
    const int*   x         = (const int*)d_in[0];
    const int*   edge_attr = (const int*)d_in[1];
    const int*   eidx      = (const int*)d_in[2];
    const int*   batch     = (const int*)d_in[3];
    const float* atom_emb  = (const float*)d_in[5];
    const float* bond_emb  = (const float*)d_in[6];
    const float* We  = (const float*)d_in[7];
    const float* be  = (const float*)d_in[8];
    const float* W1  = (const float*)d_in[9];
    const float* b1  = (const float*)d_in[10];
    const float* bn1 = (const float*)d_in[11];
    const float* W2  = (const float*)d_in[12];
    const float* b2  = (const float*)d_in[13];
    const float* bn2 = (const float*)d_in[14];
    const float* epsp= (const float*)d_in[15];
    const float* Wp  = (const float*)d_in[16];
    const float* bp  = (const float*)d_in[17];
    const float* vnW1= (const float*)d_in[18];
    const float* vnb1= (const float*)d_in[19];
    const float* vnbn= (const float*)d_in[20];
    const float* vnW2= (const float*)d_in[21];
    const float* vnb2= (const float*)d_in[22];
    const float* ln_g= (const float*)d_in[23];
    const float* ln_b= (const float*)d_in[24];
    const float* hW1 = (const float*)d_in[25];
    const float* hb1 = (const float*)d_in[26];
    const float* hW2 = (const float*)d_in[27];
    const float* hb2 = (const float*)d_in[28];
    float* out = (float*)d_out;

    const int N  = in_sizes[0];
    const int E  = in_sizes[1];
    const int G  = out_size;
    const int L  = in_sizes[15];
    const int H  = in_sizes[19];
    const int H2 = 2 * H;
    const int ED = in_sizes[7] / (L * H);
    const int BV = in_sizes[6] / ED;
    const int HH = in_sizes[26];
    (void)n_in;

    const int* src = eidx;
    const int* dst = eidx + E;

    // padded dims for MFMA path
    const int KP1 = ((H  + 31) / 32) * 32;            // 320
    const int KP2 = ((H2 + 31) / 32) * 32;            // 608
    const int RP1 = ((H2 + 127) / 128) * 128;         // 640
    const int RP2 = ((H  + 127) / 128) * 128;         // 384
    const int Npad = ((N + 127) / 128) * 128;

    // ---- workspace carve-up (bytes, 256B aligned), strictly within ws_size ----
    char* wsb = (char*)d_ws;
    auto alb = [](size_t v) { return (v + 255) & ~(size_t)255; };
    const size_t fN = (size_t)N * H;
    const size_t fG = (size_t)G * H;

    size_t off = 0;
    bf16*  hbf   = (bf16*) (wsb + off); off += alb(fN * 2);
    bf16*  zb    = (bf16*) (wsb + off); off += alb((size_t)Npad * KP1 * 2);
    float* hp    = (float*)(wsb + off); off += alb(fG * 4);
    float* hg    = (float*)(wsb + off); off += alb(fG * 4);
    float* vn    = (float*)(wsb + off); off += alb(fG * 4);
    float* vn_in = (float*)(wsb + off); off += alb(fG * 4);
    float* vn_t  = (float*)(wsb + off); off += alb(fG * 4);
    float* rbuf  = (float*)(wsb + off); off += alb(fG * 4);
    float* r2    = (float*)(wsb + off); off += alb((size_t)G * HH * 4);
    float* tbl   = (float*)(wsb + off); off += alb((size_t)L * BV * H * 4);
    bf16*  W1b   = (bf16*) (wsb + off); off += alb((size_t)RP1 * KP1 * 2);
    bf16*  W2b   = (bf16*) (wsb + off); off += alb((size_t)RP2 * KP2 * 2);
    // CSR arrays (ints)
    int* eoff = (int*)(wsb + off); off += alb((size_t)(N + 1) * 4);
    int* ecur = (int*)(wsb + off); off += alb((size_t)N * 4);
    int* esrc = (int*)(wsb + off); off += alb((size_t)E * 4);
    int* eea  = (int*)(wsb + off); off += alb((size_t)E * 4);
    int* goff = (int*)(wsb + off); off += alb((size_t)(G + 1) * 4);
    int* gcnt = (int*)(wsb + off); off += alb((size_t)G * 4);
    int* bsum = (int*)(wsb + off); off += alb(1024 * 4);

    // t1 chunk region gets the rest
    size_t left = (ws_size > off + 256) ? (ws_size - off - 256) : 0;
    long long chl = (long long)(left / ((size_t)KP2 * 2));
    int CH = (int)((chl > Npad) ? Npad : chl);
    CH = (CH / 128) * 128;
    if (CH < 128) {
        k_fill<<<64, 256, 0, stream>>>(out, 10000.0f + (float)(ws_size >> 20), G);
        return;
    }
    bf16* t1 = (bf16*)(wsb + off);

    auto gemm_f = [&](const float* A, const float* B, const float* bias, const float* bn,
                      float* C, int M, int Nc, int K, int flags) {
        dim3 grid((M + GBM - 1) / GBM, (Nc + GBN - 1) / GBN);
        k_gemm<<<grid, dim3(256), 0, stream>>>(A, B, bias, bn, C, M, Nc, K, flags);
    };
    auto mfma = [&](const bf16* A, const bf16* B, const float* bias, const float* bn,
                    const bf16* resb, bf16* outp, int M, int Nc, int Kp, int ldA,
                    int ldOut, int ldPad, int dosilu, int ncolT) {
        int mt = (M + 127) / 128;
        k_mfma_gemm<<<dim3(mt * ncolT), dim3(256), 0, stream>>>(
            A, B, bias, bn, resb, outp, M, Nc, Kp, ldA, ldOut, ldPad, dosilu, ncolT);
    };
    auto zero = [&](void* p, size_t nfloats) { k_zero<<<1024, 256, 0, stream>>>((float*)p, nfloats); };

    const int NH = N * H;

    // ---- one-time CSR builds (dst and batch are layer-invariant) ----
    {
        int nb = (N + 1023) / 1024;
        zero(ecur, N);
        k_hist<<<1024, 256, 0, stream>>>(dst, ecur, E);
        k_scan1<<<nb, 256, 0, stream>>>(ecur, eoff, bsum, N);
        k_scan1<<<1, 256, 0, stream>>>(bsum, bsum, nullptr, nb);
        k_scan_add<<<512, 256, 0, stream>>>(eoff, bsum, ecur, N, E);
        k_escatter<<<1024, 256, 0, stream>>>(dst, src, edge_attr, ecur, esrc, eea, E);

        int nbg = (G + 1023) / 1024;
        zero(gcnt, G);
        k_hist<<<1024, 256, 0, stream>>>(batch, gcnt, N);
        k_scan1<<<nbg, 256, 0, stream>>>(gcnt, goff, bsum, G);
        k_scan1<<<1, 256, 0, stream>>>(bsum, bsum, nullptr, nbg);
        k_scan_add<<<64, 256, 0, stream>>>(goff, bsum, nullptr, G, N);
    }

    zero(hg, fG);
    zero(vn, fG);

    k_eptable<<<L * BV, 320, 0, stream>>>(bond_emb, We, be, tbl, BV, H, ED);
    k_encode<<<2048, 256, 0, stream>>>(x, atom_emb, hbf, H, NH);

    for (int i = 0; i < L; i++) {
        if (i > 0) {
            k_add<<<1024, 256, 0, stream>>>(hp, vn, vn_in, G * H);
            gemm_f(vn_in, vnW1, vnb1, vnbn, vn_t, G, H, H, 1);
            gemm_f(vn_t, vnW2, vnb2, nullptr, vn, G, H, H, 0);
            k_addvn<<<2048, 256, 0, stream>>>(hbf, vn, batch, H, NH);
        }
        // fused message + zmix: zb = (1+eps)h + gather-sum relu(h_src + ep)
        k_msg_csr<<<8192, KP1, 0, stream>>>(eoff, esrc, eea, hbf,
                                            tbl + (size_t)i * BV * H, epsp, i,
                                            zb, H, KP1, N);
        // weights -> bf16 padded
        k_castw<<<512, 256, 0, stream>>>(W1 + (size_t)i * H2 * H, W1b, H2, H, KP1, RP1 * KP1);
        k_castw<<<512, 256, 0, stream>>>(W2 + (size_t)i * H * H2, W2b, H, H2, KP2, RP2 * KP2);
        // node MLP, row-chunked through t1
        for (int r0 = 0; r0 < N; r0 += CH) {
            int m = (N - r0 < CH) ? (N - r0) : CH;
            mfma(zb + (size_t)r0 * KP1, W1b, b1 + (size_t)i * H2, bn1 + (size_t)i * 4 * H2,
                 nullptr, t1, m, H2, KP1, KP1, KP2, KP2, 1, RP1 / 128);
            mfma(t1, W2b, b2 + (size_t)i * H, bn2 + (size_t)i * 4 * H,
                 (i > 0) ? (hbf + (size_t)r0 * H) : nullptr, hbf + (size_t)r0 * H,
                 m, H, KP2, KP2, H, H, 1, RP2 / 128);
        }
        // CSR pooling + graph accumulation
        k_pool_csr<<<4096, KP1, 0, stream>>>(goff, hbf, hp, H, G);
        gemm_f(hp, Wp + (size_t)i * H * H, bp + (size_t)i * H, nullptr, hg, G, H, H, 2);
    }

    // readout
    k_ln_silu<<<G, 256, 0, stream>>>(hg, ln_g, ln_b, rbuf, H);
    gemm_f(rbuf, hW1, hb1, nullptr, r2, G, HH, H, 1);
    k_head2<<<G, 64, 0, stream>>>(r2, hW2, hb2, out, HH);
}

// Round 9
// 2854.312 us; speedup vs baseline: 3.6384x; 1.1412x over previous
//
#include <hip/hip_runtime.h>
#include <hip/hip_bf16.h>
#include <math.h>

// ---------------------------------------------------------------------------
// GIN model (GINEConv x5 + virtual node + readout).
// CSR message passing + pooling (no hot-path atomics).
// Node-MLP GEMMs: bf16 MFMA 128x128 tile, 8 waves (32x64 per wave, low reg
// pressure), global_load_lds double-buffer with COUNTED vmcnt + raw barriers
// (prefetch stays in flight across barriers), XOR slot swizzle, XCD-chunked
// block swizzle for A-operand L2 reuse.
// ---------------------------------------------------------------------------

typedef __hip_bfloat16 bf16;
typedef __attribute__((ext_vector_type(8))) __bf16 bf16x8;
typedef __attribute__((ext_vector_type(4))) float f32x4;

__device__ __forceinline__ float silu_f(float v) { return v / (1.0f + __expf(-v)); }

// async global->LDS, 16B per lane; lds base must be wave-uniform.
#define GLOAD16(gp, lp) __builtin_amdgcn_global_load_lds( \
    (const __attribute__((address_space(1))) unsigned int*)(const void*)(gp), \
    (__attribute__((address_space(3))) unsigned int*)(void*)(lp), 16, 0, 0)

__global__ void k_fill(float* __restrict__ p, float v, int n) {
    int stride = gridDim.x * blockDim.x;
    for (int i = blockIdx.x * blockDim.x + threadIdx.x; i < n; i += stride) p[i] = v;
}

__global__ void k_zero(float* __restrict__ p, size_t n) {
    size_t stride = (size_t)gridDim.x * blockDim.x;
    for (size_t i = (size_t)blockIdx.x * blockDim.x + threadIdx.x; i < n; i += stride)
        p[i] = 0.0f;
}

// ---------------- CSR build helpers ----------------
__global__ void k_hist(const int* __restrict__ key, int* __restrict__ cnt, int n) {
    int stride = gridDim.x * blockDim.x;
    for (int i = blockIdx.x * blockDim.x + threadIdx.x; i < n; i += stride)
        atomicAdd(&cnt[key[i]], 1);
}

__global__ __launch_bounds__(256)
void k_scan1(const int* __restrict__ in, int* __restrict__ out,
             int* __restrict__ bsum, int n) {
    __shared__ int wsum[4];
    int base = blockIdx.x << 10;
    int t = threadIdx.x;
    int i0 = base + t * 4;
    int v0 = (i0 + 0 < n) ? in[i0 + 0] : 0;
    int v1 = (i0 + 1 < n) ? in[i0 + 1] : 0;
    int v2 = (i0 + 2 < n) ? in[i0 + 2] : 0;
    int v3 = (i0 + 3 < n) ? in[i0 + 3] : 0;
    int s = v0 + v1 + v2 + v3;
    int lane = t & 63, wid = t >> 6;
    int x = s;
    for (int d = 1; d < 64; d <<= 1) {
        int y = __shfl_up(x, d);
        if (lane >= d) x += y;
    }
    if (lane == 63) wsum[wid] = x;
    __syncthreads();
    int wadd = 0;
    for (int w = 0; w < wid; w++) wadd += wsum[w];
    x += wadd;
    int run = x - s;
    if (i0 + 0 < n) out[i0 + 0] = run; run += v0;
    if (i0 + 1 < n) out[i0 + 1] = run; run += v1;
    if (i0 + 2 < n) out[i0 + 2] = run; run += v2;
    if (i0 + 3 < n) out[i0 + 3] = run; run += v3;
    if (bsum && t == 255) bsum[blockIdx.x] = x;
}

__global__ void k_scan_add(int* __restrict__ out, const int* __restrict__ bsum,
                           int* __restrict__ cur, int n, int total) {
    int stride = gridDim.x * blockDim.x;
    for (int i = blockIdx.x * blockDim.x + threadIdx.x; i < n; i += stride) {
        int v = out[i] + bsum[i >> 10];
        out[i] = v;
        if (cur) cur[i] = v;
    }
    if (blockIdx.x == 0 && threadIdx.x == 0) out[n] = total;
}

__global__ void k_escatter(const int* __restrict__ dst, const int* __restrict__ src,
                           const int* __restrict__ ea, int* __restrict__ cur,
                           int* __restrict__ esrc, int* __restrict__ eea, int E) {
    int stride = gridDim.x * blockDim.x;
    for (int e = blockIdx.x * blockDim.x + threadIdx.x; e < E; e += stride) {
        int p = atomicAdd(&cur[dst[e]], 1);
        esrc[p] = src[e];
        eea[p]  = ea[e];
    }
}

// ---------------- model kernels ----------------
__global__ void k_eptable(const float* __restrict__ bond_emb,
                          const float* __restrict__ We,
                          const float* __restrict__ be,
                          float* __restrict__ tbl, int BV, int H, int ED) {
    int l = blockIdx.x / BV;
    int a = blockIdx.x % BV;
    int j = threadIdx.x;
    if (j >= H) return;
    const float* w = We + ((size_t)l * H + j) * ED;
    const float* bb = bond_emb + (size_t)a * ED;
    float s = be[(size_t)l * H + j];
    for (int k = 0; k < ED; k++) s += bb[k] * w[k];
    tbl[((size_t)l * BV + a) * H + j] = s;
}

__global__ void k_encode(const int* __restrict__ x, const float* __restrict__ emb,
                         bf16* __restrict__ h, int H, int total) {
    int stride = gridDim.x * blockDim.x;
    for (int i = blockIdx.x * blockDim.x + threadIdx.x; i < total; i += stride) {
        int n = i / H, j = i - n * H;
        h[i] = __float2bfloat16(emb[(size_t)x[n] * H + j]);
    }
}

// CSR message + zmix fused
__global__ __launch_bounds__(320)
void k_msg_csr(const int* __restrict__ eoff, const int* __restrict__ esrc,
               const int* __restrict__ eea, const bf16* __restrict__ h,
               const float* __restrict__ tbl, const float* __restrict__ epsp, int l,
               bf16* __restrict__ zb, int H, int KP1, int N) {
    int j = threadIdx.x;
    float epl = 1.0f + epsp[l];
    for (int n = blockIdx.x; n < N; n += gridDim.x) {
        float z = 0.0f;
        if (j < H) {
            float s = 0.0f;
            int e0 = eoff[n], e1 = eoff[n + 1];
            for (int e = e0; e < e1; e++) {
                float v = __bfloat162float(h[(size_t)esrc[e] * H + j])
                        + tbl[(size_t)eea[e] * H + j];
                if (v > 0.0f) s += v;
            }
            z = epl * __bfloat162float(h[(size_t)n * H + j]) + s;
        }
        zb[(size_t)n * KP1 + j] = __float2bfloat16(z);
    }
}

// CSR pooling (batch sorted)
__global__ __launch_bounds__(320)
void k_pool_csr(const int* __restrict__ goff, const bf16* __restrict__ h,
                float* __restrict__ hp, int H, int G) {
    int j = threadIdx.x;
    if (j >= H) return;
    for (int g = blockIdx.x; g < G; g += gridDim.x) {
        float s = 0.0f;
        int n0 = goff[g], n1 = goff[g + 1];
        for (int n = n0; n < n1; n++)
            s += __bfloat162float(h[(size_t)n * H + j]);
        hp[(size_t)g * H + j] = s;
    }
}

__global__ void k_add(const float* __restrict__ a, const float* __restrict__ b,
                      float* __restrict__ c, int n) {
    int stride = gridDim.x * blockDim.x;
    for (int i = blockIdx.x * blockDim.x + threadIdx.x; i < n; i += stride)
        c[i] = a[i] + b[i];
}

__global__ void k_addvn(bf16* __restrict__ h, const float* __restrict__ vn,
                        const int* __restrict__ batch, int H, int total) {
    int stride = gridDim.x * blockDim.x;
    for (int i = blockIdx.x * blockDim.x + threadIdx.x; i < total; i += stride) {
        int n = i / H, j = i - n * H;
        h[i] = __float2bfloat16(__bfloat162float(h[i]) + vn[(size_t)batch[n] * H + j]);
    }
}

// weight cast + zero-pad for ALL layers: dst[l][r][c] (L x Rp x Kp)
__global__ void k_castw_all(const float* __restrict__ W, bf16* __restrict__ Wb,
                            int L, int R, int K, int Kp, int total) {
    int stride = gridDim.x * blockDim.x;
    int perL = R * K;        // src per layer
    int perLp;
    perLp = 0;               // silence unused warnings pattern
    (void)perLp;
    int pl = ((R + 0) * Kp); // not used directly
    (void)pl;
    for (int i = blockIdx.x * blockDim.x + threadIdx.x; i < total; i += stride) {
        int rpk = i;         // l*(Rp*Kp) decomposition done by caller sizing
        int RpKp = total / L;
        int l = rpk / RpKp, rem = rpk - l * RpKp;
        int r = rem / Kp, c = rem - r * Kp;
        float v = (r < R && c < K) ? W[(size_t)l * perL + (size_t)r * K + c] : 0.0f;
        Wb[i] = __float2bfloat16(v);
    }
}

// --- MFMA GEMM: out[m,n] = epi( sum_k A[m,k]*B[n,k] ), A,B bf16 k-contig.
// 512 threads / 8 waves, tile 128x128, per-wave 32x64 (acc 2x4 f32x4 = 32 regs).
// Double-buffered LDS; counted "s_waitcnt vmcnt(2)" + raw s_barrier keeps the
// next tile's loads in flight ACROSS the barrier (T4). XOR slot swizzle on
// both staged source and ds_read. XCD-chunked bijective block swizzle.
__global__ __launch_bounds__(512)
void k_mfma_gemm(const bf16* __restrict__ A, const bf16* __restrict__ B,
                 const float* __restrict__ bias, const float* __restrict__ bn,
                 const bf16* __restrict__ resb, bf16* __restrict__ out,
                 int M, int Nc, int Kp, int ldA, int ldOut, int ldPad,
                 int dosilu, int ncol) {
    __shared__ short As[2 * 128 * 32];
    __shared__ short Bs[2 * 128 * 32];
    // XCD-chunked bijective swizzle (m204)
    const int nwg = gridDim.x;
    const int bid = blockIdx.x;
    const int q = nwg >> 3, r = nwg & 7;
    const int xcd = bid & 7, ii = bid >> 3;
    const int wgid = (xcd < r ? xcd * (q + 1) : r * (q + 1) + (xcd - r) * q) + ii;
    const int rb = wgid / ncol, cb = wgid - rb * ncol;
    const int bm = rb * 128, bn0 = cb * 128;

    const int tid = threadIdx.x;
    const int wave = tid >> 6, lane = tid & 63;
    const int wr = wave >> 1, wc = wave & 1;       // wr 0..3 (32-row band), wc 0..1 (64-col band)
    const int l15 = lane & 15, l4 = lane >> 4;
    const int srow = wave * 16 + (lane >> 2);      // staging row 0..127
    const int sslot = lane & 3;                    // linear 16B slot

    f32x4 acc[2][4];
    #pragma unroll
    for (int mi = 0; mi < 2; mi++)
        #pragma unroll
        for (int ni = 0; ni < 4; ni++)
            acc[mi][ni] = (f32x4){0.f, 0.f, 0.f, 0.f};

    const int sg = (sslot ^ ((srow >> 1) & 3)) << 3;   // swizzled source col (shorts)

    // stage one 128x32 tile of A and B into buffer `buf`
    auto STAGE = [&](int buf, int k0) {
        GLOAD16(A + (size_t)(bm + srow) * ldA + k0 + sg, As + buf * 4096 + wave * 512);
        GLOAD16(B + (size_t)(bn0 + srow) * Kp + k0 + sg, Bs + buf * 4096 + wave * 512);
    };

    const int nt = Kp >> 5;
    STAGE(0, 0);
    for (int t = 0; t < nt; ++t) {
        if (t + 1 < nt) {
            STAGE((t + 1) & 1, (t + 1) << 5);
            asm volatile("s_waitcnt vmcnt(2)" ::: "memory");  // own 2 oldest (tile t) done
        } else {
            asm volatile("s_waitcnt vmcnt(0)" ::: "memory");
        }
        __builtin_amdgcn_sched_barrier(0);
        __builtin_amdgcn_s_barrier();          // all waves' tile t landed
        const short* Ab = As + (t & 1) * 4096;
        const short* Bb = Bs + (t & 1) * 4096;
        bf16x8 a[2], b[4];
        #pragma unroll
        for (int mi = 0; mi < 2; mi++) {
            int row = wr * 32 + mi * 16 + l15;
            a[mi] = *(const bf16x8*)&Ab[row * 32 + ((l4 ^ ((row >> 1) & 3)) << 3)];
        }
        #pragma unroll
        for (int ni = 0; ni < 4; ni++) {
            int row = wc * 64 + ni * 16 + l15;
            b[ni] = *(const bf16x8*)&Bb[row * 32 + ((l4 ^ ((row >> 1) & 3)) << 3)];
        }
        #pragma unroll
        for (int mi = 0; mi < 2; mi++)
            #pragma unroll
            for (int ni = 0; ni < 4; ni++)
                acc[mi][ni] = __builtin_amdgcn_mfma_f32_16x16x32_bf16(
                    a[mi], b[ni], acc[mi][ni], 0, 0, 0);
        __builtin_amdgcn_sched_barrier(0);
        __builtin_amdgcn_s_barrier();          // all reads of tile t done before overwrite
    }

    #pragma unroll
    for (int ni = 0; ni < 4; ni++) {
        int col = bn0 + wc * 64 + ni * 16 + l15;
        if (col >= ldPad) continue;
        bool pad = (col >= Nc);
        float bi = (!pad && bias) ? bias[col] : 0.f;
        float sc = 1.f, mm = 0.f, bb = 0.f;
        if (!pad && bn) {
            sc = bn[col] * rsqrtf(bn[3 * Nc + col] + 1e-5f);
            mm = bn[2 * Nc + col];
            bb = bn[Nc + col];
        }
        #pragma unroll
        for (int mi = 0; mi < 2; mi++) {
            #pragma unroll
            for (int rr = 0; rr < 4; rr++) {
                int row = bm + wr * 32 + mi * 16 + l4 * 4 + rr;
                if (row >= M) continue;
                size_t idx = (size_t)row * ldOut + col;
                if (pad) { out[idx] = __float2bfloat16(0.f); continue; }
                float v = acc[mi][ni][rr] + bi;
                if (bn) v = (v - mm) * sc + bb;
                if (dosilu) v = silu_f(v);
                if (resb) v += __bfloat162float(resb[idx]);
                out[idx] = __float2bfloat16(v);
            }
        }
    }
}

// --- small fp32 GEMM (vn / pool / readout)
#define GBM 64
#define GBN 64
#define GBK 16
__global__ __launch_bounds__(256)
void k_gemm(const float* __restrict__ A, const float* __restrict__ B,
            const float* __restrict__ bias, const float* __restrict__ bn,
            float* __restrict__ C, int M, int Nc, int K, int flags) { // 1=silu 2=accum
    __shared__ float As[GBK][GBM + 4];
    __shared__ float Bs[GBK][GBN + 4];
    const int bm = blockIdx.x * GBM;
    const int bnc = blockIdx.y * GBN;
    const int tid = threadIdx.x;
    const int tx = tid & 15, ty = tid >> 4;
    const int ar = tid >> 2;
    const int ak = (tid & 3) << 2;

    float acc[4][4] = {{0.f}};

    for (int k0 = 0; k0 < K; k0 += GBK) {
        {
            int gr = bm + ar, gk = k0 + ak;
            float4 v = make_float4(0.f, 0.f, 0.f, 0.f);
            if (gr < M && gk < K) {
                const float* p = A + (size_t)gr * K;
                if (gk + 3 < K) v = *(const float4*)(p + gk);
                else {
                    v.x = p[gk];
                    if (gk + 1 < K) v.y = p[gk + 1];
                    if (gk + 2 < K) v.z = p[gk + 2];
                }
            }
            As[ak][ar] = v.x; As[ak + 1][ar] = v.y; As[ak + 2][ar] = v.z; As[ak + 3][ar] = v.w;
        }
        {
            int gr = bnc + ar, gk = k0 + ak;
            float4 v = make_float4(0.f, 0.f, 0.f, 0.f);
            if (gr < Nc && gk < K) {
                const float* p = B + (size_t)gr * K;
                if (gk + 3 < K) v = *(const float4*)(p + gk);
                else {
                    v.x = p[gk];
                    if (gk + 1 < K) v.y = p[gk + 1];
                    if (gk + 2 < K) v.z = p[gk + 2];
                }
            }
            Bs[ak][ar] = v.x; Bs[ak + 1][ar] = v.y; Bs[ak + 2][ar] = v.z; Bs[ak + 3][ar] = v.w;
        }
        __syncthreads();
        #pragma unroll
        for (int kk = 0; kk < GBK; kk++) {
            float4 a = *(const float4*)&As[kk][ty * 4];
            float4 b = *(const float4*)&Bs[kk][tx * 4];
            acc[0][0] += a.x * b.x; acc[0][1] += a.x * b.y; acc[0][2] += a.x * b.z; acc[0][3] += a.x * b.w;
            acc[1][0] += a.y * b.x; acc[1][1] += a.y * b.y; acc[1][2] += a.y * b.z; acc[1][3] += a.y * b.w;
            acc[2][0] += a.z * b.x; acc[2][1] += a.z * b.y; acc[2][2] += a.z * b.z; acc[2][3] += a.z * b.w;
            acc[3][0] += a.w * b.x; acc[3][1] += a.w * b.y; acc[3][2] += a.w * b.z; acc[3][3] += a.w * b.w;
        }
        __syncthreads();
    }

    #pragma unroll
    for (int i = 0; i < 4; i++) {
        int row = bm + ty * 4 + i;
        if (row >= M) continue;
        #pragma unroll
        for (int j = 0; j < 4; j++) {
            int col = bnc + tx * 4 + j;
            if (col >= Nc) continue;
            float v = acc[i][j];
            if (bias) v += bias[col];
            if (bn) {
                float g = bn[col], bb = bn[Nc + col], mm = bn[2 * Nc + col], vv = bn[3 * Nc + col];
                v = (v - mm) * (g * rsqrtf(vv + 1e-5f)) + bb;
            }
            if (flags & 1) v = silu_f(v);
            size_t idx = (size_t)row * Nc + col;
            if (flags & 2) C[idx] += v;
            else           C[idx] = v;
        }
    }
}

// per-row LayerNorm + SiLU
__global__ __launch_bounds__(256)
void k_ln_silu(const float* __restrict__ hg, const float* __restrict__ g,
               const float* __restrict__ b, float* __restrict__ r, int H) {
    int gi = blockIdx.x;
    const float* row = hg + (size_t)gi * H;
    float s = 0.f, s2 = 0.f;
    for (int j = threadIdx.x; j < H; j += blockDim.x) {
        float v = row[j];
        s += v; s2 += v * v;
    }
    for (int off = 32; off; off >>= 1) {
        s += __shfl_down(s, off);
        s2 += __shfl_down(s2, off);
    }
    __shared__ float rs[4], rs2[4];
    int wid = threadIdx.x >> 6, lane = threadIdx.x & 63;
    if (lane == 0) { rs[wid] = s; rs2[wid] = s2; }
    __syncthreads();
    if (threadIdx.x == 0) {
        float S = 0.f, S2 = 0.f;
        for (int w = 0; w < 4; w++) { S += rs[w]; S2 += rs2[w]; }
        rs[0] = S; rs2[0] = S2;
    }
    __syncthreads();
    float mu = rs[0] / H;
    float var = rs2[0] / H - mu * mu;
    float inv = rsqrtf(var + 1e-5f);
    for (int j = threadIdx.x; j < H; j += blockDim.x) {
        float v = (row[j] - mu) * inv * g[j] + b[j];
        r[(size_t)gi * H + j] = silu_f(v);
    }
}

__global__ void k_head2(const float* __restrict__ r2, const float* __restrict__ w,
                        const float* __restrict__ b, float* __restrict__ out, int Kh) {
    int gi = blockIdx.x;
    int t = threadIdx.x;
    float s = 0.f;
    for (int k = t; k < Kh; k += 64) s += r2[(size_t)gi * Kh + k] * w[k];
    for (int off = 32; off; off >>= 1) s += __shfl_down(s, off);
    if (t == 0) out[gi] = s + b[0];
}

extern "C" void kernel_launch(void* const* d_in, const int* in_sizes, int n_in,
                              void* d_out, int out_size, void* d_ws, size_t ws_size,
                              hipStream_t stream) {
    const int*   x         = (const int*)d_in[0];
    const int*   edge_attr = (const int*)d_in[1];
    const int*   eidx      = (const int*)d_in[2];
    const int*   batch     = (const int*)d_in[3];
    const float* atom_emb  = (const float*)d_in[5];
    const float* bond_emb  = (const float*)d_in[6];
    const float* We  = (const float*)d_in[7];
    const float* be  = (const float*)d_in[8];
    const float* W1  = (const float*)d_in[9];
    const float* b1  = (const float*)d_in[10];
    const float* bn1 = (const float*)d_in[11];
    const float* W2  = (const float*)d_in[12];
    const float* b2  = (const float*)d_in[13];
    const float* bn2 = (const float*)d_in[14];
    const float* epsp= (const float*)d_in[15];
    const float* Wp  = (const float*)d_in[16];
    const float* bp  = (const float*)d_in[17];
    const float* vnW1= (const float*)d_in[18];
    const float* vnb1= (const float*)d_in[19];
    const float* vnbn= (const float*)d_in[20];
    const float* vnW2= (const float*)d_in[21];
    const float* vnb2= (const float*)d_in[22];
    const float* ln_g= (const float*)d_in[23];
    const float* ln_b= (const float*)d_in[24];
    const float* hW1 = (const float*)d_in[25];
    const float* hb1 = (const float*)d_in[26];
    const float* hW2 = (const float*)d_in[27];
    const float* hb2 = (const float*)d_in[28];
    float* out = (float*)d_out;

    const int N  = in_sizes[0];
    const int E  = in_sizes[1];
    const int G  = out_size;
    const int L  = in_sizes[15];
    const int H  = in_sizes[19];
    const int H2 = 2 * H;
    const int ED = in_sizes[7] / (L * H);
    const int BV = in_sizes[6] / ED;
    const int HH = in_sizes[26];
    (void)n_in;

    const int* src = eidx;
    const int* dst = eidx + E;

    // padded dims for MFMA path
    const int KP1 = ((H  + 31) / 32) * 32;            // 320
    const int KP2 = ((H2 + 31) / 32) * 32;            // 608
    const int RP1 = ((H2 + 127) / 128) * 128;         // 640
    const int RP2 = ((H  + 127) / 128) * 128;         // 384
    const int Npad = ((N + 127) / 128) * 128;

    // ---- workspace carve-up (bytes, 256B aligned), strictly within ws_size ----
    char* wsb = (char*)d_ws;
    auto alb = [](size_t v) { return (v + 255) & ~(size_t)255; };
    const size_t fN = (size_t)N * H;
    const size_t fG = (size_t)G * H;

    size_t off = 0;
    bf16*  hbf   = (bf16*) (wsb + off); off += alb(fN * 2);
    bf16*  zb    = (bf16*) (wsb + off); off += alb((size_t)Npad * KP1 * 2);
    float* hp    = (float*)(wsb + off); off += alb(fG * 4);
    float* hg    = (float*)(wsb + off); off += alb(fG * 4);
    float* vn    = (float*)(wsb + off); off += alb(fG * 4);
    float* vn_in = (float*)(wsb + off); off += alb(fG * 4);
    float* vn_t  = (float*)(wsb + off); off += alb(fG * 4);
    float* rbuf  = (float*)(wsb + off); off += alb(fG * 4);
    float* r2    = (float*)(wsb + off); off += alb((size_t)G * HH * 4);
    float* tbl   = (float*)(wsb + off); off += alb((size_t)L * BV * H * 4);
    bf16*  W1b   = (bf16*) (wsb + off); off += alb((size_t)L * RP1 * KP1 * 2);
    bf16*  W2b   = (bf16*) (wsb + off); off += alb((size_t)L * RP2 * KP2 * 2);
    // CSR arrays (ints)
    int* eoff = (int*)(wsb + off); off += alb((size_t)(N + 1) * 4);
    int* ecur = (int*)(wsb + off); off += alb((size_t)N * 4);
    int* esrc = (int*)(wsb + off); off += alb((size_t)E * 4);
    int* eea  = (int*)(wsb + off); off += alb((size_t)E * 4);
    int* goff = (int*)(wsb + off); off += alb((size_t)(G + 1) * 4);
    int* gcnt = (int*)(wsb + off); off += alb((size_t)G * 4);
    int* bsum = (int*)(wsb + off); off += alb(1024 * 4);

    // t1 chunk region gets the rest
    size_t left = (ws_size > off + 256) ? (ws_size - off - 256) : 0;
    long long chl = (long long)(left / ((size_t)KP2 * 2));
    int CH = (int)((chl > Npad) ? Npad : chl);
    CH = (CH / 128) * 128;
    if (CH < 128) {
        k_fill<<<64, 256, 0, stream>>>(out, 10000.0f + (float)(ws_size >> 20), G);
        return;
    }
    bf16* t1 = (bf16*)(wsb + off);

    auto gemm_f = [&](const float* A, const float* B, const float* bias, const float* bn,
                      float* C, int M, int Nc, int K, int flags) {
        dim3 grid((M + GBM - 1) / GBM, (Nc + GBN - 1) / GBN);
        k_gemm<<<grid, dim3(256), 0, stream>>>(A, B, bias, bn, C, M, Nc, K, flags);
    };
    auto mfma = [&](const bf16* A, const bf16* B, const float* bias, const float* bn,
                    const bf16* resb, bf16* outp, int M, int Nc, int Kp, int ldA,
                    int ldOut, int ldPad, int dosilu, int ncolT) {
        int mt = (M + 127) / 128;
        k_mfma_gemm<<<dim3(mt * ncolT), dim3(512), 0, stream>>>(
            A, B, bias, bn, resb, outp, M, Nc, Kp, ldA, ldOut, ldPad, dosilu, ncolT);
    };
    auto zero = [&](void* p, size_t nfloats) { k_zero<<<1024, 256, 0, stream>>>((float*)p, nfloats); };

    const int NH = N * H;

    // ---- one-time CSR builds (dst and batch are layer-invariant) ----
    {
        int nb = (N + 1023) / 1024;
        zero(ecur, N);
        k_hist<<<1024, 256, 0, stream>>>(dst, ecur, E);
        k_scan1<<<nb, 256, 0, stream>>>(ecur, eoff, bsum, N);
        k_scan1<<<1, 256, 0, stream>>>(bsum, bsum, nullptr, nb);
        k_scan_add<<<512, 256, 0, stream>>>(eoff, bsum, ecur, N, E);
        k_escatter<<<1024, 256, 0, stream>>>(dst, src, edge_attr, ecur, esrc, eea, E);

        int nbg = (G + 1023) / 1024;
        zero(gcnt, G);
        k_hist<<<1024, 256, 0, stream>>>(batch, gcnt, N);
        k_scan1<<<nbg, 256, 0, stream>>>(gcnt, goff, bsum, G);
        k_scan1<<<1, 256, 0, stream>>>(bsum, bsum, nullptr, nbg);
        k_scan_add<<<64, 256, 0, stream>>>(goff, bsum, nullptr, G, N);
    }

    zero(hg, fG);
    zero(vn, fG);

    k_eptable<<<L * BV, 320, 0, stream>>>(bond_emb, We, be, tbl, BV, H, ED);
    k_encode<<<2048, 256, 0, stream>>>(x, atom_emb, hbf, H, NH);
    // all-layer weight casts (hoisted out of the layer loop)
    k_castw_all<<<2048, 256, 0, stream>>>(W1, W1b, L, H2, H, KP1, L * RP1 * KP1);
    k_castw_all<<<2048, 256, 0, stream>>>(W2, W2b, L, H, H2, KP2, L * RP2 * KP2);

    for (int i = 0; i < L; i++) {
        if (i > 0) {
            k_add<<<1024, 256, 0, stream>>>(hp, vn, vn_in, G * H);
            gemm_f(vn_in, vnW1, vnb1, vnbn, vn_t, G, H, H, 1);
            gemm_f(vn_t, vnW2, vnb2, nullptr, vn, G, H, H, 0);
            k_addvn<<<2048, 256, 0, stream>>>(hbf, vn, batch, H, NH);
        }
        // fused message + zmix: zb = (1+eps)h + gather-sum relu(h_src + ep)
        k_msg_csr<<<8192, KP1, 0, stream>>>(eoff, esrc, eea, hbf,
                                            tbl + (size_t)i * BV * H, epsp, i,
                                            zb, H, KP1, N);
        // node MLP, row-chunked through t1
        for (int r0 = 0; r0 < N; r0 += CH) {
            int m = (N - r0 < CH) ? (N - r0) : CH;
            mfma(zb + (size_t)r0 * KP1, W1b + (size_t)i * RP1 * KP1,
                 b1 + (size_t)i * H2, bn1 + (size_t)i * 4 * H2,
                 nullptr, t1, m, H2, KP1, KP1, KP2, KP2, 1, RP1 / 128);
            mfma(t1, W2b + (size_t)i * RP2 * KP2, b2 + (size_t)i * H, bn2 + (size_t)i * 4 * H,
                 (i > 0) ? (hbf + (size_t)r0 * H) : nullptr, hbf + (size_t)r0 * H,
                 m, H, KP2, KP2, H, H, 1, RP2 / 128);
        }
        // CSR pooling + graph accumulation
        k_pool_csr<<<4096, KP1, 0, stream>>>(goff, hbf, hp, H, G);
        gemm_f(hp, Wp + (size_t)i * H * H, bp + (size_t)i * H, nullptr, hg, G, H, H, 2);
    }

    // readout
    k_ln_silu<<<G, 256, 0, stream>>>(hg, ln_g, ln_b, rbuf, H);
    gemm_f(rbuf, hW1, hb1, nullptr, r2, G, HH, H, 1);
    k_head2<<<G, 64, 0, stream>>>(r2, hW2, hb2, out, HH);
}

// Round 10
// 2477.871 us; speedup vs baseline: 4.1912x; 1.1519x over previous
//
#include <hip/hip_runtime.h>
#include <hip/hip_bf16.h>
#include <math.h>

// ---------------------------------------------------------------------------
// GIN model (GINEConv x5 + virtual node + readout).
// CSR message passing (per-wave node chains) + CSR pooling.
// All heavy GEMMs on bf16 MFMA (128x128 tile, 8 waves, counted vmcnt dbuf,
// XOR slot swizzle, XCD-chunked block swizzle). Pool GEMMs collapsed into
// one layer-stacked GEMM; vn MLP on the MFMA path.
// ---------------------------------------------------------------------------

typedef __hip_bfloat16 bf16;
typedef __attribute__((ext_vector_type(8))) __bf16 bf16x8;
typedef __attribute__((ext_vector_type(4))) float f32x4;

__device__ __forceinline__ float silu_f(float v) { return v / (1.0f + __expf(-v)); }

// async global->LDS, 16B per lane; lds base must be wave-uniform.
#define GLOAD16(gp, lp) __builtin_amdgcn_global_load_lds( \
    (const __attribute__((address_space(1))) unsigned int*)(const void*)(gp), \
    (__attribute__((address_space(3))) unsigned int*)(void*)(lp), 16, 0, 0)

__global__ void k_fill(float* __restrict__ p, float v, int n) {
    int stride = gridDim.x * blockDim.x;
    for (int i = blockIdx.x * blockDim.x + threadIdx.x; i < n; i += stride) p[i] = v;
}

__global__ void k_zero(float* __restrict__ p, size_t n) {
    size_t stride = (size_t)gridDim.x * blockDim.x;
    for (size_t i = (size_t)blockIdx.x * blockDim.x + threadIdx.x; i < n; i += stride)
        p[i] = 0.0f;
}

// ---------------- CSR build helpers ----------------
__global__ void k_hist(const int* __restrict__ key, int* __restrict__ cnt, int n) {
    int stride = gridDim.x * blockDim.x;
    for (int i = blockIdx.x * blockDim.x + threadIdx.x; i < n; i += stride)
        atomicAdd(&cnt[key[i]], 1);
}

__global__ __launch_bounds__(256)
void k_scan1(const int* __restrict__ in, int* __restrict__ out,
             int* __restrict__ bsum, int n) {
    __shared__ int wsum[4];
    int base = blockIdx.x << 10;
    int t = threadIdx.x;
    int i0 = base + t * 4;
    int v0 = (i0 + 0 < n) ? in[i0 + 0] : 0;
    int v1 = (i0 + 1 < n) ? in[i0 + 1] : 0;
    int v2 = (i0 + 2 < n) ? in[i0 + 2] : 0;
    int v3 = (i0 + 3 < n) ? in[i0 + 3] : 0;
    int s = v0 + v1 + v2 + v3;
    int lane = t & 63, wid = t >> 6;
    int x = s;
    for (int d = 1; d < 64; d <<= 1) {
        int y = __shfl_up(x, d);
        if (lane >= d) x += y;
    }
    if (lane == 63) wsum[wid] = x;
    __syncthreads();
    int wadd = 0;
    for (int w = 0; w < wid; w++) wadd += wsum[w];
    x += wadd;
    int run = x - s;
    if (i0 + 0 < n) out[i0 + 0] = run; run += v0;
    if (i0 + 1 < n) out[i0 + 1] = run; run += v1;
    if (i0 + 2 < n) out[i0 + 2] = run; run += v2;
    if (i0 + 3 < n) out[i0 + 3] = run; run += v3;
    if (bsum && t == 255) bsum[blockIdx.x] = x;
}

__global__ void k_scan_add(int* __restrict__ out, const int* __restrict__ bsum,
                           int* __restrict__ cur, int n, int total) {
    int stride = gridDim.x * blockDim.x;
    for (int i = blockIdx.x * blockDim.x + threadIdx.x; i < n; i += stride) {
        int v = out[i] + bsum[i >> 10];
        out[i] = v;
        if (cur) cur[i] = v;
    }
    if (blockIdx.x == 0 && threadIdx.x == 0) out[n] = total;
}

__global__ void k_escatter(const int* __restrict__ dst, const int* __restrict__ src,
                           const int* __restrict__ ea, int* __restrict__ cur,
                           int* __restrict__ esrc, int* __restrict__ eea, int E) {
    int stride = gridDim.x * blockDim.x;
    for (int e = blockIdx.x * blockDim.x + threadIdx.x; e < E; e += stride) {
        int p = atomicAdd(&cur[dst[e]], 1);
        esrc[p] = src[e];
        eea[p]  = ea[e];
    }
}

// ---------------- model kernels ----------------
__global__ void k_eptable(const float* __restrict__ bond_emb,
                          const float* __restrict__ We,
                          const float* __restrict__ be,
                          float* __restrict__ tbl, int BV, int H, int ED) {
    int l = blockIdx.x / BV;
    int a = blockIdx.x % BV;
    int j = threadIdx.x;
    if (j >= H) return;
    const float* w = We + ((size_t)l * H + j) * ED;
    const float* bb = bond_emb + (size_t)a * ED;
    float s = be[(size_t)l * H + j];
    for (int k = 0; k < ED; k++) s += bb[k] * w[k];
    tbl[((size_t)l * BV + a) * H + j] = s;
}

__global__ void k_encode(const int* __restrict__ x, const float* __restrict__ emb,
                         bf16* __restrict__ h, int H, int total) {
    int stride = gridDim.x * blockDim.x;
    for (int i = blockIdx.x * blockDim.x + threadIdx.x; i < total; i += stride) {
        int n = i / H, j = i - n * H;
        h[i] = __float2bfloat16(emb[(size_t)x[n] * H + j]);
    }
}

// CSR message + zmix, ONE WAVE PER NODE (lane covers j, j+64, ..., j+256).
// Requires KP1 <= 320 (H <= 320).
__global__ __launch_bounds__(256)
void k_msg_csr(const int* __restrict__ eoff, const int* __restrict__ esrc,
               const int* __restrict__ eea, const bf16* __restrict__ h,
               const float* __restrict__ tbl, const float* __restrict__ epsp, int l,
               bf16* __restrict__ zb, int H, int KP1, int N) {
    const int wid = blockIdx.x * (blockDim.x >> 6) + (threadIdx.x >> 6);
    const int nw = gridDim.x * (blockDim.x >> 6);
    const int lane = threadIdx.x & 63;
    const float epl = 1.0f + epsp[l];
    for (int n = wid; n < N; n += nw) {
        int e0 = eoff[n], e1 = eoff[n + 1];
        float acc[5] = {0.f, 0.f, 0.f, 0.f, 0.f};
        for (int e = e0; e < e1; e++) {
            int s = esrc[e], a = eea[e];
            const bf16* hr = h + (size_t)s * H;
            const float* tr = tbl + (size_t)a * H;
            #pragma unroll
            for (int k = 0; k < 5; k++) {
                int j = lane + k * 64;
                if (j < H) {
                    float v = __bfloat162float(hr[j]) + tr[j];
                    if (v > 0.0f) acc[k] += v;
                }
            }
        }
        const bf16* hn = h + (size_t)n * H;
        #pragma unroll
        for (int k = 0; k < 5; k++) {
            int j = lane + k * 64;
            if (j >= KP1) continue;
            float z = 0.0f;
            if (j < H) z = epl * __bfloat162float(hn[j]) + acc[k];
            zb[(size_t)n * KP1 + j] = __float2bfloat16(z);
        }
    }
}

// CSR pooling (batch sorted): hp fp32 + bf16 slice of layer-stacked hps
__global__ __launch_bounds__(320)
void k_pool_csr(const int* __restrict__ goff, const bf16* __restrict__ h,
                float* __restrict__ hp, bf16* __restrict__ hps, int layer, int KPS,
                int H, int G) {
    int j = threadIdx.x;
    if (j >= H) return;
    for (int g = blockIdx.x; g < G; g += gridDim.x) {
        float s = 0.0f;
        int n0 = goff[g], n1 = goff[g + 1];
        for (int n = n0; n < n1; n++)
            s += __bfloat162float(h[(size_t)n * H + j]);
        hp[(size_t)g * H + j] = s;
        hps[(size_t)g * KPS + layer * H + j] = __float2bfloat16(s);
    }
}

__global__ void k_addvn(bf16* __restrict__ h, const float* __restrict__ vn,
                        const int* __restrict__ batch, int H, int total) {
    int stride = gridDim.x * blockDim.x;
    for (int i = blockIdx.x * blockDim.x + threadIdx.x; i < total; i += stride) {
        int n = i / H, j = i - n * H;
        h[i] = __float2bfloat16(__bfloat162float(h[i]) + vn[(size_t)batch[n] * H + j]);
    }
}

// o[g][c] = bf16( (c<H) ? hp[g][c] + vn[g][c] : 0 ), c < KP
__global__ void k_add_castpad(const float* __restrict__ hp, const float* __restrict__ vn,
                              bf16* __restrict__ o, int H, int KP, int total) {
    int stride = gridDim.x * blockDim.x;
    for (int i = blockIdx.x * blockDim.x + threadIdx.x; i < total; i += stride) {
        int g = i / KP, c = i - g * KP;
        float v = 0.0f;
        if (c < H) v = hp[(size_t)g * H + c] + vn[(size_t)g * H + c];
        o[i] = __float2bfloat16(v);
    }
}

// weight cast + zero-pad for L layers: dst[l][r][c] (L x Rp x Kp)
__global__ void k_castw_all(const float* __restrict__ W, bf16* __restrict__ Wb,
                            int L, int R, int K, int Kp, int total) {
    int stride = gridDim.x * blockDim.x;
    int perL = R * K;
    for (int i = blockIdx.x * blockDim.x + threadIdx.x; i < total; i += stride) {
        int RpKp = total / L;
        int l = i / RpKp, rem = i - l * RpKp;
        int r = rem / Kp, c = rem - r * Kp;
        float v = (r < R && c < K) ? W[(size_t)l * perL + (size_t)r * K + c] : 0.0f;
        Wb[i] = __float2bfloat16(v);
    }
}

// stacked pooling weight: Wb[r][c] (Rp x KPS), value = Wp[c/H][r][c%H]
__global__ void k_castWps(const float* __restrict__ Wp, bf16* __restrict__ Wb,
                          int L, int H, int KPS, int total) {
    int stride = gridDim.x * blockDim.x;
    for (int i = blockIdx.x * blockDim.x + threadIdx.x; i < total; i += stride) {
        int r = i / KPS, c = i - r * KPS;
        float v = 0.0f;
        if (r < H && c < L * H) {
            int li = c / H, k = c - li * H;
            v = Wp[(size_t)li * H * H + (size_t)r * H + k];
        }
        Wb[i] = __float2bfloat16(v);
    }
}

// o[j] = sum_i bp[i*H+j]
__global__ void k_sumbias(const float* __restrict__ bp, float* __restrict__ o,
                          int L, int H) {
    int j = blockIdx.x * blockDim.x + threadIdx.x;
    if (j < H) {
        float s = 0.f;
        for (int i = 0; i < L; i++) s += bp[(size_t)i * H + j];
        o[j] = s;
    }
}

// --- MFMA GEMM: out[m,n] = epi( sum_k A[m,k]*B[n,k] ), A,B bf16 k-contig.
// 512 threads / 8 waves, tile 128x128, per-wave 32x64. Double-buffered LDS,
// counted vmcnt(2) + raw barriers. XOR slot swizzle both sides. XCD swizzle.
// If outf != null: fp32 output (no residual, no pad writes).
__global__ __launch_bounds__(512)
void k_mfma_gemm(const bf16* __restrict__ A, const bf16* __restrict__ B,
                 const float* __restrict__ bias, const float* __restrict__ bn,
                 const bf16* __restrict__ resb, bf16* __restrict__ out,
                 float* __restrict__ outf,
                 int M, int Nc, int Kp, int ldA, int ldOut, int ldPad,
                 int dosilu, int ncol) {
    __shared__ short As[2 * 128 * 32];
    __shared__ short Bs[2 * 128 * 32];
    const int nwg = gridDim.x;
    const int bid = blockIdx.x;
    const int q = nwg >> 3, r = nwg & 7;
    const int xcd = bid & 7, ii = bid >> 3;
    const int wgid = (xcd < r ? xcd * (q + 1) : r * (q + 1) + (xcd - r) * q) + ii;
    const int rb = wgid / ncol, cb = wgid - rb * ncol;
    const int bm = rb * 128, bn0 = cb * 128;

    const int tid = threadIdx.x;
    const int wave = tid >> 6, lane = tid & 63;
    const int wr = wave >> 1, wc = wave & 1;
    const int l15 = lane & 15, l4 = lane >> 4;
    const int srow = wave * 16 + (lane >> 2);
    const int sslot = lane & 3;

    f32x4 acc[2][4];
    #pragma unroll
    for (int mi = 0; mi < 2; mi++)
        #pragma unroll
        for (int ni = 0; ni < 4; ni++)
            acc[mi][ni] = (f32x4){0.f, 0.f, 0.f, 0.f};

    const int sg = (sslot ^ ((srow >> 1) & 3)) << 3;

    auto STAGE = [&](int buf, int k0) {
        GLOAD16(A + (size_t)(bm + srow) * ldA + k0 + sg, As + buf * 4096 + wave * 512);
        GLOAD16(B + (size_t)(bn0 + srow) * Kp + k0 + sg, Bs + buf * 4096 + wave * 512);
    };

    const int nt = Kp >> 5;
    STAGE(0, 0);
    for (int t = 0; t < nt; ++t) {
        if (t + 1 < nt) {
            STAGE((t + 1) & 1, (t + 1) << 5);
            asm volatile("s_waitcnt vmcnt(2)" ::: "memory");
        } else {
            asm volatile("s_waitcnt vmcnt(0)" ::: "memory");
        }
        __builtin_amdgcn_sched_barrier(0);
        __builtin_amdgcn_s_barrier();
        const short* Ab = As + (t & 1) * 4096;
        const short* Bb = Bs + (t & 1) * 4096;
        bf16x8 a[2], b[4];
        #pragma unroll
        for (int mi = 0; mi < 2; mi++) {
            int row = wr * 32 + mi * 16 + l15;
            a[mi] = *(const bf16x8*)&Ab[row * 32 + ((l4 ^ ((row >> 1) & 3)) << 3)];
        }
        #pragma unroll
        for (int ni = 0; ni < 4; ni++) {
            int row = wc * 64 + ni * 16 + l15;
            b[ni] = *(const bf16x8*)&Bb[row * 32 + ((l4 ^ ((row >> 1) & 3)) << 3)];
        }
        #pragma unroll
        for (int mi = 0; mi < 2; mi++)
            #pragma unroll
            for (int ni = 0; ni < 4; ni++)
                acc[mi][ni] = __builtin_amdgcn_mfma_f32_16x16x32_bf16(
                    a[mi], b[ni], acc[mi][ni], 0, 0, 0);
        __builtin_amdgcn_sched_barrier(0);
        __builtin_amdgcn_s_barrier();
    }

    #pragma unroll
    for (int ni = 0; ni < 4; ni++) {
        int col = bn0 + wc * 64 + ni * 16 + l15;
        if (col >= ldPad) continue;
        bool pad = (col >= Nc);
        float bi = (!pad && bias) ? bias[col] : 0.f;
        float sc = 1.f, mm = 0.f, bb = 0.f;
        if (!pad && bn) {
            sc = bn[col] * rsqrtf(bn[3 * Nc + col] + 1e-5f);
            mm = bn[2 * Nc + col];
            bb = bn[Nc + col];
        }
        #pragma unroll
        for (int mi = 0; mi < 2; mi++) {
            #pragma unroll
            for (int rr = 0; rr < 4; rr++) {
                int row = bm + wr * 32 + mi * 16 + l4 * 4 + rr;
                if (row >= M) continue;
                size_t idx = (size_t)row * ldOut + col;
                if (outf) {
                    if (pad) continue;
                    float v = acc[mi][ni][rr] + bi;
                    if (bn) v = (v - mm) * sc + bb;
                    if (dosilu) v = silu_f(v);
                    outf[idx] = v;
                } else {
                    if (pad) { out[idx] = __float2bfloat16(0.f); continue; }
                    float v = acc[mi][ni][rr] + bi;
                    if (bn) v = (v - mm) * sc + bb;
                    if (dosilu) v = silu_f(v);
                    if (resb) v += __bfloat162float(resb[idx]);
                    out[idx] = __float2bfloat16(v);
                }
            }
        }
    }
}

// --- small fp32 GEMM (readout only)
#define GBM 64
#define GBN 64
#define GBK 16
__global__ __launch_bounds__(256)
void k_gemm(const float* __restrict__ A, const float* __restrict__ B,
            const float* __restrict__ bias, const float* __restrict__ bn,
            float* __restrict__ C, int M, int Nc, int K, int flags) {
    __shared__ float As[GBK][GBM + 4];
    __shared__ float Bs[GBK][GBN + 4];
    const int bm = blockIdx.x * GBM;
    const int bnc = blockIdx.y * GBN;
    const int tid = threadIdx.x;
    const int tx = tid & 15, ty = tid >> 4;
    const int ar = tid >> 2;
    const int ak = (tid & 3) << 2;

    float acc[4][4] = {{0.f}};

    for (int k0 = 0; k0 < K; k0 += GBK) {
        {
            int gr = bm + ar, gk = k0 + ak;
            float4 v = make_float4(0.f, 0.f, 0.f, 0.f);
            if (gr < M && gk < K) {
                const float* p = A + (size_t)gr * K;
                if (gk + 3 < K) v = *(const float4*)(p + gk);
                else {
                    v.x = p[gk];
                    if (gk + 1 < K) v.y = p[gk + 1];
                    if (gk + 2 < K) v.z = p[gk + 2];
                }
            }
            As[ak][ar] = v.x; As[ak + 1][ar] = v.y; As[ak + 2][ar] = v.z; As[ak + 3][ar] = v.w;
        }
        {
            int gr = bnc + ar, gk = k0 + ak;
            float4 v = make_float4(0.f, 0.f, 0.f, 0.f);
            if (gr < Nc && gk < K) {
                const float* p = B + (size_t)gr * K;
                if (gk + 3 < K) v = *(const float4*)(p + gk);
                else {
                    v.x = p[gk];
                    if (gk + 1 < K) v.y = p[gk + 1];
                    if (gk + 2 < K) v.z = p[gk + 2];
                }
            }
            Bs[ak][ar] = v.x; Bs[ak + 1][ar] = v.y; Bs[ak + 2][ar] = v.z; Bs[ak + 3][ar] = v.w;
        }
        __syncthreads();
        #pragma unroll
        for (int kk = 0; kk < GBK; kk++) {
            float4 a = *(const float4*)&As[kk][ty * 4];
            float4 b = *(const float4*)&Bs[kk][tx * 4];
            acc[0][0] += a.x * b.x; acc[0][1] += a.x * b.y; acc[0][2] += a.x * b.z; acc[0][3] += a.x * b.w;
            acc[1][0] += a.y * b.x; acc[1][1] += a.y * b.y; acc[1][2] += a.y * b.z; acc[1][3] += a.y * b.w;
            acc[2][0] += a.z * b.x; acc[2][1] += a.z * b.y; acc[2][2] += a.z * b.z; acc[2][3] += a.z * b.w;
            acc[3][0] += a.w * b.x; acc[3][1] += a.w * b.y; acc[3][2] += a.w * b.z; acc[3][3] += a.w * b.w;
        }
        __syncthreads();
    }

    #pragma unroll
    for (int i = 0; i < 4; i++) {
        int row = bm + ty * 4 + i;
        if (row >= M) continue;
        #pragma unroll
        for (int j = 0; j < 4; j++) {
            int col = bnc + tx * 4 + j;
            if (col >= Nc) continue;
            float v = acc[i][j];
            if (bias) v += bias[col];
            if (bn) {
                float g = bn[col], bb = bn[Nc + col], mm = bn[2 * Nc + col], vv = bn[3 * Nc + col];
                v = (v - mm) * (g * rsqrtf(vv + 1e-5f)) + bb;
            }
            if (flags & 1) v = silu_f(v);
            size_t idx = (size_t)row * Nc + col;
            if (flags & 2) C[idx] += v;
            else           C[idx] = v;
        }
    }
}

// per-row LayerNorm + SiLU
__global__ __launch_bounds__(256)
void k_ln_silu(const float* __restrict__ hg, const float* __restrict__ g,
               const float* __restrict__ b, float* __restrict__ r, int H) {
    int gi = blockIdx.x;
    const float* row = hg + (size_t)gi * H;
    float s = 0.f, s2 = 0.f;
    for (int j = threadIdx.x; j < H; j += blockDim.x) {
        float v = row[j];
        s += v; s2 += v * v;
    }
    for (int off = 32; off; off >>= 1) {
        s += __shfl_down(s, off);
        s2 += __shfl_down(s2, off);
    }
    __shared__ float rs[4], rs2[4];
    int wid = threadIdx.x >> 6, lane = threadIdx.x & 63;
    if (lane == 0) { rs[wid] = s; rs2[wid] = s2; }
    __syncthreads();
    if (threadIdx.x == 0) {
        float S = 0.f, S2 = 0.f;
        for (int w = 0; w < 4; w++) { S += rs[w]; S2 += rs2[w]; }
        rs[0] = S; rs2[0] = S2;
    }
    __syncthreads();
    float mu = rs[0] / H;
    float var = rs2[0] / H - mu * mu;
    float inv = rsqrtf(var + 1e-5f);
    for (int j = threadIdx.x; j < H; j += blockDim.x) {
        float v = (row[j] - mu) * inv * g[j] + b[j];
        r[(size_t)gi * H + j] = silu_f(v);
    }
}

__global__ void k_head2(const float* __restrict__ r2, const float* __restrict__ w,
                        const float* __restrict__ b, float* __restrict__ out, int Kh) {
    int gi = blockIdx.x;
    int t = threadIdx.x;
    float s = 0.f;
    for (int k = t; k < Kh; k += 64) s += r2[(size_t)gi * Kh + k] * w[k];
    for (int off = 32; off; off >>= 1) s += __shfl_down(s, off);
    if (t == 0) out[gi] = s + b[0];
}

extern "C" void kernel_launch(void* const* d_in, const int* in_sizes, int n_in,
                              void* d_out, int out_size, void* d_ws, size_t ws_size,
                              hipStream_t stream) {
    const int*   x         = (const int*)d_in[0];
    const int*   edge_attr = (const int*)d_in[1];
    const int*   eidx      = (const int*)d_in[2];
    const int*   batch     = (const int*)d_in[3];
    const float* atom_emb  = (const float*)d_in[5];
    const float* bond_emb  = (const float*)d_in[6];
    const float* We  = (const float*)d_in[7];
    const float* be  = (const float*)d_in[8];
    const float* W1  = (const float*)d_in[9];
    const float* b1  = (const float*)d_in[10];
    const float* bn1 = (const float*)d_in[11];
    const float* W2  = (const float*)d_in[12];
    const float* b2  = (const float*)d_in[13];
    const float* bn2 = (const float*)d_in[14];
    const float* epsp= (const float*)d_in[15];
    const float* Wp  = (const float*)d_in[16];
    const float* bp  = (const float*)d_in[17];
    const float* vnW1= (const float*)d_in[18];
    const float* vnb1= (const float*)d_in[19];
    const float* vnbn= (const float*)d_in[20];
    const float* vnW2= (const float*)d_in[21];
    const float* vnb2= (const float*)d_in[22];
    const float* ln_g= (const float*)d_in[23];
    const float* ln_b= (const float*)d_in[24];
    const float* hW1 = (const float*)d_in[25];
    const float* hb1 = (const float*)d_in[26];
    const float* hW2 = (const float*)d_in[27];
    const float* hb2 = (const float*)d_in[28];
    float* out = (float*)d_out;

    const int N  = in_sizes[0];
    const int E  = in_sizes[1];
    const int G  = out_size;
    const int L  = in_sizes[15];
    const int H  = in_sizes[19];
    const int H2 = 2 * H;
    const int ED = in_sizes[7] / (L * H);
    const int BV = in_sizes[6] / ED;
    const int HH = in_sizes[26];
    (void)n_in;

    const int* src = eidx;
    const int* dst = eidx + E;

    // padded dims for MFMA path
    const int KP1 = ((H  + 31) / 32) * 32;            // 320
    const int KP2 = ((H2 + 31) / 32) * 32;            // 608
    const int KPS = ((L * H + 31) / 32) * 32;         // 1504
    const int RP1 = ((H2 + 127) / 128) * 128;         // 640
    const int RP2 = ((H  + 127) / 128) * 128;         // 384
    const int Npad = ((N + 127) / 128) * 128;
    const int GP   = ((G + 127) / 128) * 128;         // 4096

    // ---- workspace carve-up (bytes, 256B aligned), strictly within ws_size ----
    char* wsb = (char*)d_ws;
    auto alb = [](size_t v) { return (v + 255) & ~(size_t)255; };
    const size_t fN = (size_t)N * H;
    const size_t fG = (size_t)G * H;

    size_t off = 0;
    bf16*  hbf   = (bf16*) (wsb + off); off += alb(fN * 2);
    bf16*  zb    = (bf16*) (wsb + off); off += alb((size_t)Npad * KP1 * 2);
    float* hp    = (float*)(wsb + off); off += alb(fG * 4);
    float* hg    = (float*)(wsb + off); off += alb(fG * 4);
    float* vn    = (float*)(wsb + off); off += alb(fG * 4);
    float* rbuf  = (float*)(wsb + off); off += alb(fG * 4);
    float* r2    = (float*)(wsb + off); off += alb((size_t)G * HH * 4);
    float* tbl   = (float*)(wsb + off); off += alb((size_t)L * BV * H * 4);
    float* bsumf = (float*)(wsb + off); off += alb((size_t)RP2 * 4);
    bf16*  W1b   = (bf16*) (wsb + off); off += alb((size_t)L * RP1 * KP1 * 2);
    bf16*  W2b   = (bf16*) (wsb + off); off += alb((size_t)L * RP2 * KP2 * 2);
    bf16*  vnW1b = (bf16*) (wsb + off); off += alb((size_t)RP2 * KP1 * 2);
    bf16*  vnW2b = (bf16*) (wsb + off); off += alb((size_t)RP2 * KP1 * 2);
    bf16*  Wpsb  = (bf16*) (wsb + off); off += alb((size_t)RP2 * KPS * 2);
    bf16*  hps   = (bf16*) (wsb + off); off += alb((size_t)GP * KPS * 2);
    bf16*  vninb = (bf16*) (wsb + off); off += alb((size_t)GP * KP1 * 2);
    bf16*  vntb  = (bf16*) (wsb + off); off += alb((size_t)GP * KP1 * 2);
    // CSR arrays (ints)
    int* eoff = (int*)(wsb + off); off += alb((size_t)(N + 1) * 4);
    int* ecur = (int*)(wsb + off); off += alb((size_t)N * 4);
    int* esrc = (int*)(wsb + off); off += alb((size_t)E * 4);
    int* eea  = (int*)(wsb + off); off += alb((size_t)E * 4);
    int* goff = (int*)(wsb + off); off += alb((size_t)(G + 1) * 4);
    int* gcnt = (int*)(wsb + off); off += alb((size_t)G * 4);
    int* bsum = (int*)(wsb + off); off += alb(1024 * 4);

    // t1 chunk region gets the rest
    size_t left = (ws_size > off + 256) ? (ws_size - off - 256) : 0;
    long long chl = (long long)(left / ((size_t)KP2 * 2));
    int CH = (int)((chl > Npad) ? Npad : chl);
    CH = (CH / 128) * 128;
    if (CH < 128) {
        k_fill<<<64, 256, 0, stream>>>(out, 10000.0f + (float)(ws_size >> 20), G);
        return;
    }
    bf16* t1 = (bf16*)(wsb + off);

    auto gemm_f = [&](const float* A, const float* B, const float* bias, const float* bn,
                      float* C, int M, int Nc, int K, int flags) {
        dim3 grid((M + GBM - 1) / GBM, (Nc + GBN - 1) / GBN);
        k_gemm<<<grid, dim3(256), 0, stream>>>(A, B, bias, bn, C, M, Nc, K, flags);
    };
    auto mfma = [&](const bf16* A, const bf16* B, const float* bias, const float* bn,
                    const bf16* resb, bf16* outb, float* outf, int M, int Nc, int Kp,
                    int ldA, int ldOut, int ldPad, int dosilu, int ncolT) {
        int mt = (M + 127) / 128;
        k_mfma_gemm<<<dim3(mt * ncolT), dim3(512), 0, stream>>>(
            A, B, bias, bn, resb, outb, outf, M, Nc, Kp, ldA, ldOut, ldPad, dosilu, ncolT);
    };
    auto zero = [&](void* p, size_t nfloats) { k_zero<<<1024, 256, 0, stream>>>((float*)p, nfloats); };

    const int NH = N * H;

    // ---- CSR builds (dst and batch are layer-invariant) ----
    {
        int nb = (N + 1023) / 1024;
        zero(ecur, N);
        k_hist<<<1024, 256, 0, stream>>>(dst, ecur, E);
        k_scan1<<<nb, 256, 0, stream>>>(ecur, eoff, bsum, N);
        k_scan1<<<1, 256, 0, stream>>>(bsum, bsum, nullptr, nb);
        k_scan_add<<<512, 256, 0, stream>>>(eoff, bsum, ecur, N, E);
        k_escatter<<<1024, 256, 0, stream>>>(dst, src, edge_attr, ecur, esrc, eea, E);

        int nbg = (G + 1023) / 1024;
        zero(gcnt, G);
        k_hist<<<1024, 256, 0, stream>>>(batch, gcnt, N);
        k_scan1<<<nbg, 256, 0, stream>>>(gcnt, goff, bsum, G);
        k_scan1<<<1, 256, 0, stream>>>(bsum, bsum, nullptr, nbg);
        k_scan_add<<<64, 256, 0, stream>>>(goff, bsum, nullptr, G, N);
    }

    zero(vn, fG);
    zero(hps, (size_t)GP * KPS / 2);   // bf16 buffer: bytes/4 floats

    k_eptable<<<L * BV, 320, 0, stream>>>(bond_emb, We, be, tbl, BV, H, ED);
    k_encode<<<2048, 256, 0, stream>>>(x, atom_emb, hbf, H, NH);
    // weight casts (once per launch)
    k_castw_all<<<2048, 256, 0, stream>>>(W1, W1b, L, H2, H, KP1, L * RP1 * KP1);
    k_castw_all<<<2048, 256, 0, stream>>>(W2, W2b, L, H, H2, KP2, L * RP2 * KP2);
    k_castw_all<<<256, 256, 0, stream>>>(vnW1, vnW1b, 1, H, H, KP1, RP2 * KP1);
    k_castw_all<<<256, 256, 0, stream>>>(vnW2, vnW2b, 1, H, H, KP1, RP2 * KP1);
    k_castWps<<<512, 256, 0, stream>>>(Wp, Wpsb, L, H, KPS, RP2 * KPS);
    k_sumbias<<<(H + 255) / 256, 256, 0, stream>>>(bp, bsumf, L, H);

    for (int i = 0; i < L; i++) {
        if (i > 0) {
            // vn MLP on MFMA path: vnin = bf16pad(hp + vn); vn = (silu(bn(vnin@W1^T+b1)))@W2^T+b2
            k_add_castpad<<<2048, 256, 0, stream>>>(hp, vn, vninb, H, KP1, G * KP1);
            mfma(vninb, vnW1b, vnb1, vnbn, nullptr, vntb, nullptr,
                 G, H, KP1, KP1, KP1, KP1, 1, RP2 / 128);
            mfma(vntb, vnW2b, vnb2, nullptr, nullptr, nullptr, vn,
                 G, H, KP1, KP1, H, H, 0, RP2 / 128);
            k_addvn<<<2048, 256, 0, stream>>>(hbf, vn, batch, H, NH);
        }
        // fused message + zmix (one wave per node)
        k_msg_csr<<<2048, 256, 0, stream>>>(eoff, esrc, eea, hbf,
                                            tbl + (size_t)i * BV * H, epsp, i,
                                            zb, H, KP1, N);
        // node MLP, row-chunked through t1
        for (int r0 = 0; r0 < N; r0 += CH) {
            int m = (N - r0 < CH) ? (N - r0) : CH;
            mfma(zb + (size_t)r0 * KP1, W1b + (size_t)i * RP1 * KP1,
                 b1 + (size_t)i * H2, bn1 + (size_t)i * 4 * H2,
                 nullptr, t1, nullptr, m, H2, KP1, KP1, KP2, KP2, 1, RP1 / 128);
            mfma(t1, W2b + (size_t)i * RP2 * KP2, b2 + (size_t)i * H,
                 bn2 + (size_t)i * 4 * H,
                 (i > 0) ? (hbf + (size_t)r0 * H) : nullptr, hbf + (size_t)r0 * H,
                 nullptr, m, H, KP2, KP2, H, H, 1, RP2 / 128);
        }
        // CSR pooling: hp fp32 + bf16 slice into layer-stacked hps
        k_pool_csr<<<4096, KP1, 0, stream>>>(goff, hbf, hp, hps, i, KPS, H, G);
    }

    // hg = hps @ Wps^T + sum(bp)  (single stacked GEMM, fp32 out)
    mfma(hps, Wpsb, bsumf, nullptr, nullptr, nullptr, hg,
         G, H, KPS, KPS, H, H, 0, RP2 / 128);

    // readout
    k_ln_silu<<<G, 256, 0, stream>>>(hg, ln_g, ln_b, rbuf, H);
    gemm_f(rbuf, hW1, hb1, nullptr, r2, G, HH, H, 1);
    k_head2<<<G, 64, 0, stream>>>(r2, hW2, hb2, out, HH);
}

// Round 11
// 2222.798 us; speedup vs baseline: 4.6721x; 1.1148x over previous
//
#include <hip/hip_runtime.h>
#include <hip/hip_bf16.h>
#include <math.h>

// ---------------------------------------------------------------------------
// GIN model (GINEConv x5 + virtual node + readout).
// CSR message passing (per-wave node chains, packed-pair loads, bf16 tbl).
// All heavy GEMMs on bf16 MFMA: 128x128 tile, 8 waves, 3-buffer LDS pipeline
// (depth-2 prefetch, counted vmcnt(2), ONE barrier per K-step), XOR slot
// swizzle, XCD-chunked block swizzle. Pool GEMMs collapsed into one stacked
// GEMM; vn MLP on the MFMA path.
// ---------------------------------------------------------------------------

typedef __hip_bfloat16 bf16;
typedef __attribute__((ext_vector_type(8))) __bf16 bf16x8;
typedef __attribute__((ext_vector_type(4))) float f32x4;

__device__ __forceinline__ float silu_f(float v) { return v / (1.0f + __expf(-v)); }
__device__ __forceinline__ float bfu_lo(unsigned u) {
    unsigned t = (u & 0xffffu) << 16; return *(float*)&t;
}
__device__ __forceinline__ float bfu_hi(unsigned u) {
    unsigned t = u & 0xffff0000u; return *(float*)&t;
}
__device__ __forceinline__ unsigned packbf(float a, float b) {
    bf16 x = __float2bfloat16(a), y = __float2bfloat16(b);
    return (unsigned)*(unsigned short*)&x | ((unsigned)*(unsigned short*)&y << 16);
}

// async global->LDS, 16B per lane; lds base must be wave-uniform.
#define GLOAD16(gp, lp) __builtin_amdgcn_global_load_lds( \
    (const __attribute__((address_space(1))) unsigned int*)(const void*)(gp), \
    (__attribute__((address_space(3))) unsigned int*)(void*)(lp), 16, 0, 0)

__global__ void k_fill(float* __restrict__ p, float v, int n) {
    int stride = gridDim.x * blockDim.x;
    for (int i = blockIdx.x * blockDim.x + threadIdx.x; i < n; i += stride) p[i] = v;
}

__global__ void k_zero(float* __restrict__ p, size_t n) {
    size_t stride = (size_t)gridDim.x * blockDim.x;
    for (size_t i = (size_t)blockIdx.x * blockDim.x + threadIdx.x; i < n; i += stride)
        p[i] = 0.0f;
}

// ---------------- CSR build helpers ----------------
__global__ void k_hist(const int* __restrict__ key, int* __restrict__ cnt, int n) {
    int stride = gridDim.x * blockDim.x;
    for (int i = blockIdx.x * blockDim.x + threadIdx.x; i < n; i += stride)
        atomicAdd(&cnt[key[i]], 1);
}

__global__ __launch_bounds__(256)
void k_scan1(const int* __restrict__ in, int* __restrict__ out,
             int* __restrict__ bsum, int n) {
    __shared__ int wsum[4];
    int base = blockIdx.x << 10;
    int t = threadIdx.x;
    int i0 = base + t * 4;
    int v0 = (i0 + 0 < n) ? in[i0 + 0] : 0;
    int v1 = (i0 + 1 < n) ? in[i0 + 1] : 0;
    int v2 = (i0 + 2 < n) ? in[i0 + 2] : 0;
    int v3 = (i0 + 3 < n) ? in[i0 + 3] : 0;
    int s = v0 + v1 + v2 + v3;
    int lane = t & 63, wid = t >> 6;
    int x = s;
    for (int d = 1; d < 64; d <<= 1) {
        int y = __shfl_up(x, d);
        if (lane >= d) x += y;
    }
    if (lane == 63) wsum[wid] = x;
    __syncthreads();
    int wadd = 0;
    for (int w = 0; w < wid; w++) wadd += wsum[w];
    x += wadd;
    int run = x - s;
    if (i0 + 0 < n) out[i0 + 0] = run; run += v0;
    if (i0 + 1 < n) out[i0 + 1] = run; run += v1;
    if (i0 + 2 < n) out[i0 + 2] = run; run += v2;
    if (i0 + 3 < n) out[i0 + 3] = run; run += v3;
    if (bsum && t == 255) bsum[blockIdx.x] = x;
}

__global__ void k_scan_add(int* __restrict__ out, const int* __restrict__ bsum,
                           int* __restrict__ cur, int n, int total) {
    int stride = gridDim.x * blockDim.x;
    for (int i = blockIdx.x * blockDim.x + threadIdx.x; i < n; i += stride) {
        int v = out[i] + bsum[i >> 10];
        out[i] = v;
        if (cur) cur[i] = v;
    }
    if (blockIdx.x == 0 && threadIdx.x == 0) out[n] = total;
}

__global__ void k_escatter(const int* __restrict__ dst, const int* __restrict__ src,
                           const int* __restrict__ ea, int* __restrict__ cur,
                           int* __restrict__ esrc, int* __restrict__ eea, int E) {
    int stride = gridDim.x * blockDim.x;
    for (int e = blockIdx.x * blockDim.x + threadIdx.x; e < E; e += stride) {
        int p = atomicAdd(&cur[dst[e]], 1);
        esrc[p] = src[e];
        eea[p]  = ea[e];
    }
}

// ---------------- model kernels ----------------
// tblb[l][a][j] = bf16( bond_emb[a].We[l][j] + be[l][j] ), zero-padded to KP1
__global__ void k_eptable(const float* __restrict__ bond_emb,
                          const float* __restrict__ We,
                          const float* __restrict__ be,
                          bf16* __restrict__ tblb, int BV, int H, int ED, int KP1) {
    int l = blockIdx.x / BV;
    int a = blockIdx.x % BV;
    int j = threadIdx.x;
    if (j >= KP1) return;
    float s = 0.0f;
    if (j < H) {
        const float* w = We + ((size_t)l * H + j) * ED;
        const float* bb = bond_emb + (size_t)a * ED;
        s = be[(size_t)l * H + j];
        for (int k = 0; k < ED; k++) s += bb[k] * w[k];
    }
    tblb[((size_t)l * BV + a) * KP1 + j] = __float2bfloat16(s);
}

__global__ void k_encode(const int* __restrict__ x, const float* __restrict__ emb,
                         bf16* __restrict__ h, int H, int total) {
    int stride = gridDim.x * blockDim.x;
    for (int i = blockIdx.x * blockDim.x + threadIdx.x; i < total; i += stride) {
        int n = i / H, j = i - n * H;
        h[i] = __float2bfloat16(emb[(size_t)x[n] * H + j]);
    }
}

// CSR message + zmix, ONE WAVE PER NODE, packed-pair loads.
// Lane covers column pairs c = 2*lane + 128*p, p = 0..2 (covers KP1 <= 384).
// Requires H even, rows 4B-aligned (H*2 % 4 == 0).
__global__ __launch_bounds__(256)
void k_msg_csr(const int* __restrict__ eoff, const int* __restrict__ esrc,
               const int* __restrict__ eea, const bf16* __restrict__ h,
               const bf16* __restrict__ tblb, const float* __restrict__ epsp, int l,
               bf16* __restrict__ zb, int H, int KP1, int N) {
    const int wid = blockIdx.x * (blockDim.x >> 6) + (threadIdx.x >> 6);
    const int nw = gridDim.x * (blockDim.x >> 6);
    const int lane = threadIdx.x & 63;
    const float epl = 1.0f + epsp[l];
    const int c0 = 2 * lane;
    for (int n = wid; n < N; n += nw) {
        int e0 = eoff[n], e1 = eoff[n + 1];
        float a0[3] = {0.f, 0.f, 0.f}, a1[3] = {0.f, 0.f, 0.f};
        for (int e = e0; e < e1; e++) {
            int s = esrc[e], a = eea[e];
            const unsigned short* hr = (const unsigned short*)h + (size_t)s * H;
            const unsigned short* tr = (const unsigned short*)tblb + (size_t)a * KP1;
            #pragma unroll
            for (int p = 0; p < 3; p++) {
                int c = c0 + p * 128;
                if (c < H) {
                    unsigned hv = *(const unsigned*)(hr + c);
                    unsigned tv = *(const unsigned*)(tr + c);
                    float v0 = bfu_lo(hv) + bfu_lo(tv);
                    float v1 = bfu_hi(hv) + bfu_hi(tv);
                    if (v0 > 0.0f) a0[p] += v0;
                    if (v1 > 0.0f) a1[p] += v1;
                }
            }
        }
        const unsigned short* hn = (const unsigned short*)h + (size_t)n * H;
        unsigned short* zr = (unsigned short*)zb + (size_t)n * KP1;
        #pragma unroll
        for (int p = 0; p < 3; p++) {
            int c = c0 + p * 128;
            if (c < KP1) {
                float z0 = 0.f, z1 = 0.f;
                if (c < H) {
                    unsigned hv = *(const unsigned*)(hn + c);
                    z0 = epl * bfu_lo(hv) + a0[p];
                    z1 = epl * bfu_hi(hv) + a1[p];
                }
                *(unsigned*)(zr + c) = packbf(z0, z1);
            }
        }
    }
}

// CSR pooling (batch sorted), packed pairs: thread j covers cols 2j, 2j+1
__global__ __launch_bounds__(256)
void k_pool_csr(const int* __restrict__ goff, const bf16* __restrict__ h,
                float* __restrict__ hp, bf16* __restrict__ hps, int layer, int KPS,
                int H, int G) {
    int j = threadIdx.x;
    int c = 2 * j;
    if (c >= H) return;
    for (int g = blockIdx.x; g < G; g += gridDim.x) {
        float s0 = 0.0f, s1 = 0.0f;
        int n0 = goff[g], n1 = goff[g + 1];
        const unsigned short* hb = (const unsigned short*)h;
        for (int n = n0; n < n1; n++) {
            unsigned hv = *(const unsigned*)(hb + (size_t)n * H + c);
            s0 += bfu_lo(hv);
            s1 += bfu_hi(hv);
        }
        hp[(size_t)g * H + c] = s0;
        hp[(size_t)g * H + c + 1] = s1;
        *(unsigned*)((unsigned short*)hps + (size_t)g * KPS + layer * H + c) = packbf(s0, s1);
    }
}

// h[n][c..c+1] += vn[batch[n]][c..c+1]   (pair-packed)
__global__ void k_addvn(bf16* __restrict__ h, const float* __restrict__ vn,
                        const int* __restrict__ batch, int H, int total2) {
    int stride = gridDim.x * blockDim.x;
    int HP = H >> 1;
    for (int i = blockIdx.x * blockDim.x + threadIdx.x; i < total2; i += stride) {
        int n = i / HP, p = i - n * HP;
        int c = 2 * p;
        unsigned short* hr = (unsigned short*)h + (size_t)n * H + c;
        unsigned hv = *(unsigned*)hr;
        const float* vr = vn + (size_t)batch[n] * H + c;
        *(unsigned*)hr = packbf(bfu_lo(hv) + vr[0], bfu_hi(hv) + vr[1]);
    }
}

// o[g][c] = bf16( (c<H) ? hp[g][c] + vn[g][c] : 0 ), c < KP
__global__ void k_add_castpad(const float* __restrict__ hp, const float* __restrict__ vn,
                              bf16* __restrict__ o, int H, int KP, int total) {
    int stride = gridDim.x * blockDim.x;
    for (int i = blockIdx.x * blockDim.x + threadIdx.x; i < total; i += stride) {
        int g = i / KP, c = i - g * KP;
        float v = 0.0f;
        if (c < H) v = hp[(size_t)g * H + c] + vn[(size_t)g * H + c];
        o[i] = __float2bfloat16(v);
    }
}

// weight cast + zero-pad for L layers: dst[l][r][c] (L x Rp x Kp)
__global__ void k_castw_all(const float* __restrict__ W, bf16* __restrict__ Wb,
                            int L, int R, int K, int Kp, int total) {
    int stride = gridDim.x * blockDim.x;
    int perL = R * K;
    for (int i = blockIdx.x * blockDim.x + threadIdx.x; i < total; i += stride) {
        int RpKp = total / L;
        int l = i / RpKp, rem = i - l * RpKp;
        int r = rem / Kp, c = rem - r * Kp;
        float v = (r < R && c < K) ? W[(size_t)l * perL + (size_t)r * K + c] : 0.0f;
        Wb[i] = __float2bfloat16(v);
    }
}

// stacked pooling weight: Wb[r][c] (Rp x KPS), value = Wp[c/H][r][c%H]
__global__ void k_castWps(const float* __restrict__ Wp, bf16* __restrict__ Wb,
                          int L, int H, int KPS, int total) {
    int stride = gridDim.x * blockDim.x;
    for (int i = blockIdx.x * blockDim.x + threadIdx.x; i < total; i += stride) {
        int r = i / KPS, c = i - r * KPS;
        float v = 0.0f;
        if (r < H && c < L * H) {
            int li = c / H, k = c - li * H;
            v = Wp[(size_t)li * H * H + (size_t)r * H + k];
        }
        Wb[i] = __float2bfloat16(v);
    }
}

// o[j] = sum_i bp[i*H+j]
__global__ void k_sumbias(const float* __restrict__ bp, float* __restrict__ o,
                          int L, int H) {
    int j = blockIdx.x * blockDim.x + threadIdx.x;
    if (j < H) {
        float s = 0.f;
        for (int i = 0; i < L; i++) s += bp[(size_t)i * H + j];
        o[j] = s;
    }
}

// --- MFMA GEMM: out[m,n] = epi( sum_k A[m,k]*B[n,k] ), A,B bf16 k-contig.
// 512 threads / 8 waves, tile 128x128, per-wave 32x64.
// 3-buffer LDS pipeline, depth-2 prefetch: stage t+2 AFTER barrier(t) (any
// wave past barrier(t) completed its t-1 ds_reads), wait vmcnt(2) per step,
// ONE s_barrier per K-step. XOR slot swizzle both sides. XCD block swizzle.
__global__ __launch_bounds__(512)
void k_mfma_gemm(const bf16* __restrict__ A, const bf16* __restrict__ B,
                 const float* __restrict__ bias, const float* __restrict__ bn,
                 const bf16* __restrict__ resb, bf16* __restrict__ out,
                 float* __restrict__ outf,
                 int M, int Nc, int Kp, int ldA, int ldOut, int ldPad,
                 int dosilu, int ncol) {
    __shared__ short As[3 * 128 * 32];
    __shared__ short Bs[3 * 128 * 32];
    const int nwg = gridDim.x;
    const int bid = blockIdx.x;
    const int q = nwg >> 3, r = nwg & 7;
    const int xcd = bid & 7, ii = bid >> 3;
    const int wgid = (xcd < r ? xcd * (q + 1) : r * (q + 1) + (xcd - r) * q) + ii;
    const int rb = wgid / ncol, cb = wgid - rb * ncol;
    const int bm = rb * 128, bn0 = cb * 128;

    const int tid = threadIdx.x;
    const int wave = tid >> 6, lane = tid & 63;
    const int wr = wave >> 1, wc = wave & 1;
    const int l15 = lane & 15, l4 = lane >> 4;
    const int srow = wave * 16 + (lane >> 2);
    const int sslot = lane & 3;

    f32x4 acc[2][4];
    #pragma unroll
    for (int mi = 0; mi < 2; mi++)
        #pragma unroll
        for (int ni = 0; ni < 4; ni++)
            acc[mi][ni] = (f32x4){0.f, 0.f, 0.f, 0.f};

    const int sg = (sslot ^ ((srow >> 1) & 3)) << 3;

    auto STAGE = [&](int buf, int k0) {
        GLOAD16(A + (size_t)(bm + srow) * ldA + k0 + sg, As + buf * 4096 + wave * 512);
        GLOAD16(B + (size_t)(bn0 + srow) * Kp + k0 + sg, Bs + buf * 4096 + wave * 512);
    };

    const int nt = Kp >> 5;
    STAGE(0, 0);
    if (nt > 1) STAGE(1, 32);
    for (int t = 0; t < nt; ++t) {
        if (t + 1 < nt) asm volatile("s_waitcnt vmcnt(2)" ::: "memory");
        else            asm volatile("s_waitcnt vmcnt(0)" ::: "memory");
        __builtin_amdgcn_sched_barrier(0);
        __builtin_amdgcn_s_barrier();
        __builtin_amdgcn_sched_barrier(0);
        if (t + 2 < nt) STAGE((t + 2) % 3, (t + 2) << 5);
        const short* Ab = As + (t % 3) * 4096;
        const short* Bb = Bs + (t % 3) * 4096;
        bf16x8 a[2], b[4];
        #pragma unroll
        for (int mi = 0; mi < 2; mi++) {
            int row = wr * 32 + mi * 16 + l15;
            a[mi] = *(const bf16x8*)&Ab[row * 32 + ((l4 ^ ((row >> 1) & 3)) << 3)];
        }
        #pragma unroll
        for (int ni = 0; ni < 4; ni++) {
            int row = wc * 64 + ni * 16 + l15;
            b[ni] = *(const bf16x8*)&Bb[row * 32 + ((l4 ^ ((row >> 1) & 3)) << 3)];
        }
        #pragma unroll
        for (int mi = 0; mi < 2; mi++)
            #pragma unroll
            for (int ni = 0; ni < 4; ni++)
                acc[mi][ni] = __builtin_amdgcn_mfma_f32_16x16x32_bf16(
                    a[mi], b[ni], acc[mi][ni], 0, 0, 0);
        __builtin_amdgcn_sched_barrier(0);
    }

    #pragma unroll
    for (int ni = 0; ni < 4; ni++) {
        int col = bn0 + wc * 64 + ni * 16 + l15;
        if (col >= ldPad) continue;
        bool pad = (col >= Nc);
        float bi = (!pad && bias) ? bias[col] : 0.f;
        float sc = 1.f, mm = 0.f, bb = 0.f;
        if (!pad && bn) {
            sc = bn[col] * rsqrtf(bn[3 * Nc + col] + 1e-5f);
            mm = bn[2 * Nc + col];
            bb = bn[Nc + col];
        }
        #pragma unroll
        for (int mi = 0; mi < 2; mi++) {
            #pragma unroll
            for (int rr = 0; rr < 4; rr++) {
                int row = bm + wr * 32 + mi * 16 + l4 * 4 + rr;
                if (row >= M) continue;
                size_t idx = (size_t)row * ldOut + col;
                if (outf) {
                    if (pad) continue;
                    float v = acc[mi][ni][rr] + bi;
                    if (bn) v = (v - mm) * sc + bb;
                    if (dosilu) v = silu_f(v);
                    outf[idx] = v;
                } else {
                    if (pad) { out[idx] = __float2bfloat16(0.f); continue; }
                    float v = acc[mi][ni][rr] + bi;
                    if (bn) v = (v - mm) * sc + bb;
                    if (dosilu) v = silu_f(v);
                    if (resb) v += __bfloat162float(resb[idx]);
                    out[idx] = __float2bfloat16(v);
                }
            }
        }
    }
}

// --- small fp32 GEMM (readout only)
#define GBM 64
#define GBN 64
#define GBK 16
__global__ __launch_bounds__(256)
void k_gemm(const float* __restrict__ A, const float* __restrict__ B,
            const float* __restrict__ bias, const float* __restrict__ bn,
            float* __restrict__ C, int M, int Nc, int K, int flags) {
    __shared__ float As[GBK][GBM + 4];
    __shared__ float Bs[GBK][GBN + 4];
    const int bm = blockIdx.x * GBM;
    const int bnc = blockIdx.y * GBN;
    const int tid = threadIdx.x;
    const int tx = tid & 15, ty = tid >> 4;
    const int ar = tid >> 2;
    const int ak = (tid & 3) << 2;

    float acc[4][4] = {{0.f}};

    for (int k0 = 0; k0 < K; k0 += GBK) {
        {
            int gr = bm + ar, gk = k0 + ak;
            float4 v = make_float4(0.f, 0.f, 0.f, 0.f);
            if (gr < M && gk < K) {
                const float* p = A + (size_t)gr * K;
                if (gk + 3 < K) v = *(const float4*)(p + gk);
                else {
                    v.x = p[gk];
                    if (gk + 1 < K) v.y = p[gk + 1];
                    if (gk + 2 < K) v.z = p[gk + 2];
                }
            }
            As[ak][ar] = v.x; As[ak + 1][ar] = v.y; As[ak + 2][ar] = v.z; As[ak + 3][ar] = v.w;
        }
        {
            int gr = bnc + ar, gk = k0 + ak;
            float4 v = make_float4(0.f, 0.f, 0.f, 0.f);
            if (gr < Nc && gk < K) {
                const float* p = B + (size_t)gr * K;
                if (gk + 3 < K) v = *(const float4*)(p + gk);
                else {
                    v.x = p[gk];
                    if (gk + 1 < K) v.y = p[gk + 1];
                    if (gk + 2 < K) v.z = p[gk + 2];
                }
            }
            Bs[ak][ar] = v.x; Bs[ak + 1][ar] = v.y; Bs[ak + 2][ar] = v.z; Bs[ak + 3][ar] = v.w;
        }
        __syncthreads();
        #pragma unroll
        for (int kk = 0; kk < GBK; kk++) {
            float4 a = *(const float4*)&As[kk][ty * 4];
            float4 b = *(const float4*)&Bs[kk][tx * 4];
            acc[0][0] += a.x * b.x; acc[0][1] += a.x * b.y; acc[0][2] += a.x * b.z; acc[0][3] += a.x * b.w;
            acc[1][0] += a.y * b.x; acc[1][1] += a.y * b.y; acc[1][2] += a.y * b.z; acc[1][3] += a.y * b.w;
            acc[2][0] += a.z * b.x; acc[2][1] += a.z * b.y; acc[2][2] += a.z * b.z; acc[2][3] += a.z * b.w;
            acc[3][0] += a.w * b.x; acc[3][1] += a.w * b.y; acc[3][2] += a.w * b.z; acc[3][3] += a.w * b.w;
        }
        __syncthreads();
    }

    #pragma unroll
    for (int i = 0; i < 4; i++) {
        int row = bm + ty * 4 + i;
        if (row >= M) continue;
        #pragma unroll
        for (int j = 0; j < 4; j++) {
            int col = bnc + tx * 4 + j;
            if (col >= Nc) continue;
            float v = acc[i][j];
            if (bias) v += bias[col];
            if (bn) {
                float g = bn[col], bb = bn[Nc + col], mm = bn[2 * Nc + col], vv = bn[3 * Nc + col];
                v = (v - mm) * (g * rsqrtf(vv + 1e-5f)) + bb;
            }
            if (flags & 1) v = silu_f(v);
            size_t idx = (size_t)row * Nc + col;
            if (flags & 2) C[idx] += v;
            else           C[idx] = v;
        }
    }
}

// per-row LayerNorm + SiLU
__global__ __launch_bounds__(256)
void k_ln_silu(const float* __restrict__ hg, const float* __restrict__ g,
               const float* __restrict__ b, float* __restrict__ r, int H) {
    int gi = blockIdx.x;
    const float* row = hg + (size_t)gi * H;
    float s = 0.f, s2 = 0.f;
    for (int j = threadIdx.x; j < H; j += blockDim.x) {
        float v = row[j];
        s += v; s2 += v * v;
    }
    for (int off = 32; off; off >>= 1) {
        s += __shfl_down(s, off);
        s2 += __shfl_down(s2, off);
    }
    __shared__ float rs[4], rs2[4];
    int wid = threadIdx.x >> 6, lane = threadIdx.x & 63;
    if (lane == 0) { rs[wid] = s; rs2[wid] = s2; }
    __syncthreads();
    if (threadIdx.x == 0) {
        float S = 0.f, S2 = 0.f;
        for (int w = 0; w < 4; w++) { S += rs[w]; S2 += rs2[w]; }
        rs[0] = S; rs2[0] = S2;
    }
    __syncthreads();
    float mu = rs[0] / H;
    float var = rs2[0] / H - mu * mu;
    float inv = rsqrtf(var + 1e-5f);
    for (int j = threadIdx.x; j < H; j += blockDim.x) {
        float v = (row[j] - mu) * inv * g[j] + b[j];
        r[(size_t)gi * H + j] = silu_f(v);
    }
}

__global__ void k_head2(const float* __restrict__ r2, const float* __restrict__ w,
                        const float* __restrict__ b, float* __restrict__ out, int Kh) {
    int gi = blockIdx.x;
    int t = threadIdx.x;
    float s = 0.f;
    for (int k = t; k < Kh; k += 64) s += r2[(size_t)gi * Kh + k] * w[k];
    for (int off = 32; off; off >>= 1) s += __shfl_down(s, off);
    if (t == 0) out[gi] = s + b[0];
}

extern "C" void kernel_launch(void* const* d_in, const int* in_sizes, int n_in,
                              void* d_out, int out_size, void* d_ws, size_t ws_size,
                              hipStream_t stream) {
    const int*   x         = (const int*)d_in[0];
    const int*   edge_attr = (const int*)d_in[1];
    const int*   eidx      = (const int*)d_in[2];
    const int*   batch     = (const int*)d_in[3];
    const float* atom_emb  = (const float*)d_in[5];
    const float* bond_emb  = (const float*)d_in[6];
    const float* We  = (const float*)d_in[7];
    const float* be  = (const float*)d_in[8];
    const float* W1  = (const float*)d_in[9];
    const float* b1  = (const float*)d_in[10];
    const float* bn1 = (const float*)d_in[11];
    const float* W2  = (const float*)d_in[12];
    const float* b2  = (const float*)d_in[13];
    const float* bn2 = (const float*)d_in[14];
    const float* epsp= (const float*)d_in[15];
    const float* Wp  = (const float*)d_in[16];
    const float* bp  = (const float*)d_in[17];
    const float* vnW1= (const float*)d_in[18];
    const float* vnb1= (const float*)d_in[19];
    const float* vnbn= (const float*)d_in[20];
    const float* vnW2= (const float*)d_in[21];
    const float* vnb2= (const float*)d_in[22];
    const float* ln_g= (const float*)d_in[23];
    const float* ln_b= (const float*)d_in[24];
    const float* hW1 = (const float*)d_in[25];
    const float* hb1 = (const float*)d_in[26];
    const float* hW2 = (const float*)d_in[27];
    const float* hb2 = (const float*)d_in[28];
    float* out = (float*)d_out;

    const int N  = in_sizes[0];
    const int E  = in_sizes[1];
    const int G  = out_size;
    const int L  = in_sizes[15];
    const int H  = in_sizes[19];
    const int H2 = 2 * H;
    const int ED = in_sizes[7] / (L * H);
    const int BV = in_sizes[6] / ED;
    const int HH = in_sizes[26];
    (void)n_in;

    const int* src = eidx;
    const int* dst = eidx + E;

    // padded dims for MFMA path
    const int KP1 = ((H  + 31) / 32) * 32;            // 320
    const int KP2 = ((H2 + 31) / 32) * 32;            // 608
    const int KPS = ((L * H + 31) / 32) * 32;         // 1504
    const int RP1 = ((H2 + 127) / 128) * 128;         // 640
    const int RP2 = ((H  + 127) / 128) * 128;         // 384
    const int Npad = ((N + 127) / 128) * 128;
    const int GP   = ((G + 127) / 128) * 128;         // 4096

    // ---- workspace carve-up (bytes, 256B aligned), strictly within ws_size ----
    char* wsb = (char*)d_ws;
    auto alb = [](size_t v) { return (v + 255) & ~(size_t)255; };
    const size_t fN = (size_t)N * H;
    const size_t fG = (size_t)G * H;

    size_t off = 0;
    bf16*  hbf   = (bf16*) (wsb + off); off += alb(fN * 2);
    bf16*  zb    = (bf16*) (wsb + off); off += alb((size_t)Npad * KP1 * 2);
    float* hp    = (float*)(wsb + off); off += alb(fG * 4);
    float* hg    = (float*)(wsb + off); off += alb(fG * 4);
    float* vn    = (float*)(wsb + off); off += alb(fG * 4);
    float* rbuf  = (float*)(wsb + off); off += alb(fG * 4);
    float* r2    = (float*)(wsb + off); off += alb((size_t)G * HH * 4);
    bf16*  tblb  = (bf16*) (wsb + off); off += alb((size_t)L * BV * KP1 * 2);
    float* bsumf = (float*)(wsb + off); off += alb((size_t)RP2 * 4);
    bf16*  W1b   = (bf16*) (wsb + off); off += alb((size_t)L * RP1 * KP1 * 2);
    bf16*  W2b   = (bf16*) (wsb + off); off += alb((size_t)L * RP2 * KP2 * 2);
    bf16*  vnW1b = (bf16*) (wsb + off); off += alb((size_t)RP2 * KP1 * 2);
    bf16*  vnW2b = (bf16*) (wsb + off); off += alb((size_t)RP2 * KP1 * 2);
    bf16*  Wpsb  = (bf16*) (wsb + off); off += alb((size_t)RP2 * KPS * 2);
    bf16*  hps   = (bf16*) (wsb + off); off += alb((size_t)GP * KPS * 2);
    bf16*  vninb = (bf16*) (wsb + off); off += alb((size_t)GP * KP1 * 2);
    bf16*  vntb  = (bf16*) (wsb + off); off += alb((size_t)GP * KP1 * 2);
    // CSR arrays (ints)
    int* eoff = (int*)(wsb + off); off += alb((size_t)(N + 1) * 4);
    int* ecur = (int*)(wsb + off); off += alb((size_t)N * 4);
    int* esrc = (int*)(wsb + off); off += alb((size_t)E * 4);
    int* eea  = (int*)(wsb + off); off += alb((size_t)E * 4);
    int* goff = (int*)(wsb + off); off += alb((size_t)(G + 1) * 4);
    int* gcnt = (int*)(wsb + off); off += alb((size_t)G * 4);
    int* bsum = (int*)(wsb + off); off += alb(1024 * 4);

    // t1 chunk region gets the rest
    size_t left = (ws_size > off + 256) ? (ws_size - off - 256) : 0;
    long long chl = (long long)(left / ((size_t)KP2 * 2));
    int CH = (int)((chl > Npad) ? Npad : chl);
    CH = (CH / 128) * 128;
    if (CH < 128) {
        k_fill<<<64, 256, 0, stream>>>(out, 10000.0f + (float)(ws_size >> 20), G);
        return;
    }
    bf16* t1 = (bf16*)(wsb + off);

    auto gemm_f = [&](const float* A, const float* B, const float* bias, const float* bn,
                      float* C, int M, int Nc, int K, int flags) {
        dim3 grid((M + GBM - 1) / GBM, (Nc + GBN - 1) / GBN);
        k_gemm<<<grid, dim3(256), 0, stream>>>(A, B, bias, bn, C, M, Nc, K, flags);
    };
    auto mfma = [&](const bf16* A, const bf16* B, const float* bias, const float* bn,
                    const bf16* resb, bf16* outb, float* outf, int M, int Nc, int Kp,
                    int ldA, int ldOut, int ldPad, int dosilu, int ncolT) {
        int mt = (M + 127) / 128;
        k_mfma_gemm<<<dim3(mt * ncolT), dim3(512), 0, stream>>>(
            A, B, bias, bn, resb, outb, outf, M, Nc, Kp, ldA, ldOut, ldPad, dosilu, ncolT);
    };
    auto zero = [&](void* p, size_t nfloats) { k_zero<<<1024, 256, 0, stream>>>((float*)p, nfloats); };

    const int NH = N * H;

    // ---- CSR builds (dst and batch are layer-invariant) ----
    {
        int nb = (N + 1023) / 1024;
        zero(ecur, N);
        k_hist<<<1024, 256, 0, stream>>>(dst, ecur, E);
        k_scan1<<<nb, 256, 0, stream>>>(ecur, eoff, bsum, N);
        k_scan1<<<1, 256, 0, stream>>>(bsum, bsum, nullptr, nb);
        k_scan_add<<<512, 256, 0, stream>>>(eoff, bsum, ecur, N, E);
        k_escatter<<<1024, 256, 0, stream>>>(dst, src, edge_attr, ecur, esrc, eea, E);

        int nbg = (G + 1023) / 1024;
        zero(gcnt, G);
        k_hist<<<1024, 256, 0, stream>>>(batch, gcnt, N);
        k_scan1<<<nbg, 256, 0, stream>>>(gcnt, goff, bsum, G);
        k_scan1<<<1, 256, 0, stream>>>(bsum, bsum, nullptr, nbg);
        k_scan_add<<<64, 256, 0, stream>>>(goff, bsum, nullptr, G, N);
    }

    zero(vn, fG);
    zero(hps, (size_t)GP * KPS / 2);   // bf16 buffer: bytes/4 floats

    k_eptable<<<L * BV, 320, 0, stream>>>(bond_emb, We, be, tblb, BV, H, ED, KP1);
    k_encode<<<2048, 256, 0, stream>>>(x, atom_emb, hbf, H, NH);
    // weight casts (once per launch)
    k_castw_all<<<2048, 256, 0, stream>>>(W1, W1b, L, H2, H, KP1, L * RP1 * KP1);
    k_castw_all<<<2048, 256, 0, stream>>>(W2, W2b, L, H, H2, KP2, L * RP2 * KP2);
    k_castw_all<<<256, 256, 0, stream>>>(vnW1, vnW1b, 1, H, H, KP1, RP2 * KP1);
    k_castw_all<<<256, 256, 0, stream>>>(vnW2, vnW2b, 1, H, H, KP1, RP2 * KP1);
    k_castWps<<<512, 256, 0, stream>>>(Wp, Wpsb, L, H, KPS, RP2 * KPS);
    k_sumbias<<<(H + 255) / 256, 256, 0, stream>>>(bp, bsumf, L, H);

    for (int i = 0; i < L; i++) {
        if (i > 0) {
            // vn MLP on MFMA path
            k_add_castpad<<<2048, 256, 0, stream>>>(hp, vn, vninb, H, KP1, G * KP1);
            mfma(vninb, vnW1b, vnb1, vnbn, nullptr, vntb, nullptr,
                 G, H, KP1, KP1, KP1, KP1, 1, RP2 / 128);
            mfma(vntb, vnW2b, vnb2, nullptr, nullptr, nullptr, vn,
                 G, H, KP1, KP1, H, H, 0, RP2 / 128);
            k_addvn<<<2048, 256, 0, stream>>>(hbf, vn, batch, H, N * (H >> 1));
        }
        // fused message + zmix (one wave per node, packed loads)
        k_msg_csr<<<4096, 256, 0, stream>>>(eoff, esrc, eea, hbf,
                                            tblb + (size_t)i * BV * KP1, epsp, i,
                                            zb, H, KP1, N);
        // node MLP, row-chunked through t1
        for (int r0 = 0; r0 < N; r0 += CH) {
            int m = (N - r0 < CH) ? (N - r0) : CH;
            mfma(zb + (size_t)r0 * KP1, W1b + (size_t)i * RP1 * KP1,
                 b1 + (size_t)i * H2, bn1 + (size_t)i * 4 * H2,
                 nullptr, t1, nullptr, m, H2, KP1, KP1, KP2, KP2, 1, RP1 / 128);
            mfma(t1, W2b + (size_t)i * RP2 * KP2, b2 + (size_t)i * H,
                 bn2 + (size_t)i * 4 * H,
                 (i > 0) ? (hbf + (size_t)r0 * H) : nullptr, hbf + (size_t)r0 * H,
                 nullptr, m, H, KP2, KP2, H, H, 1, RP2 / 128);
        }
        // CSR pooling: hp fp32 + bf16 slice into layer-stacked hps
        k_pool_csr<<<4096, 256, 0, stream>>>(goff, hbf, hp, hps, i, KPS, H, G);
    }

    // hg = hps @ Wps^T + sum(bp)  (single stacked GEMM, fp32 out)
    mfma(hps, Wpsb, bsumf, nullptr, nullptr, nullptr, hg,
         G, H, KPS, KPS, H, H, 0, RP2 / 128);

    // readout
    k_ln_silu<<<G, 256, 0, stream>>>(hg, ln_g, ln_b, rbuf, H);
    gemm_f(rbuf, hW1, hb1, nullptr, r2, G, HH, H, 1);
    k_head2<<<G, 64, 0, stream>>>(r2, hW2, hb2, out, HH);
}